// Round 2
// baseline (20683.032 us; speedup 1.0000x reference)
//
#include <hip/hip_runtime.h>

#define SLEN 64
#define BSZ  64
#define TSL  48
#define VDIM 32000
#define NCOL 32064   // VDIM + SLEN

typedef __attribute__((ext_vector_type(8))) short bf16x8;
typedef __attribute__((ext_vector_type(4))) float f32x4;

__device__ __forceinline__ float fsig(float x){
    return 1.0f/(1.0f + __expf(-x));
}
__device__ __forceinline__ float ftanh(float x){
    float e = __expf(2.0f*x);
    return 1.0f - 2.0f/(e + 1.0f);
}
__device__ __forceinline__ unsigned short f2bf(float x){
    unsigned u = __float_as_uint(x);
    u += 0x7FFF + ((u >> 16) & 1);
    return (unsigned short)(u >> 16);
}
__device__ __forceinline__ float bf2f(unsigned short h){
    return __uint_as_float(((unsigned)h) << 16);
}
__device__ __forceinline__ float gru_fuse(float gir,float giz,float gin,
                                          float ghr,float ghz,float ghn,float h){
    float r = fsig(gir + ghr);
    float z = fsig(giz + ghz);
    float n = ftanh(gin + r*ghn);
    return (1.0f - z)*n + z*h;
}

// ---------------------------------------------------------------------------
// Tiled 64x64 fp32 GEMM:  C = A @ B^T (+bias) (opt tanh). A:(M,K) B:(N,K) row-major.
// grid = (N/64, M/64, nz); z selects pointer set.
// ---------------------------------------------------------------------------
__global__ __launch_bounds__(256) void gemm64(
    const float* A0, const float* B0, const float* bias0, float* C0, int act0,
    const float* A1, const float* B1, const float* bias1, float* C1, int act1,
    int M, int N, int K, int ldc)
{
    const float* A  = blockIdx.z ? A1 : A0;
    const float* B  = blockIdx.z ? B1 : B0;
    const float* bp = blockIdx.z ? bias1 : bias0;
    float*       C  = blockIdx.z ? C1 : C0;
    const int act   = blockIdx.z ? act1 : act0;

    __shared__ float As[32*68];
    __shared__ float Bs[32*68];

    const int n0 = blockIdx.x * 64;
    const int m0 = blockIdx.y * 64;
    const int t  = threadIdx.x;
    const int lrow = t >> 3;       // 0..31
    const int lc4  = t & 7;        // 0..7
    const int tm = (t >> 4) << 2;  // 0..60
    const int tn = (t & 15) << 2;  // 0..60

    float acc[4][4] = {};

    for (int k0 = 0; k0 < K; k0 += 32) {
        float4 a0 = *reinterpret_cast<const float4*>(A + (size_t)(m0+lrow   )*K + k0 + lc4*4);
        float4 a1 = *reinterpret_cast<const float4*>(A + (size_t)(m0+lrow+32)*K + k0 + lc4*4);
        float4 b0 = *reinterpret_cast<const float4*>(B + (size_t)(n0+lrow   )*K + k0 + lc4*4);
        float4 b1 = *reinterpret_cast<const float4*>(B + (size_t)(n0+lrow+32)*K + k0 + lc4*4);
        __syncthreads();
        const int kb = lc4*4;
        As[(kb+0)*68 + lrow]    = a0.x; As[(kb+1)*68 + lrow]    = a0.y;
        As[(kb+2)*68 + lrow]    = a0.z; As[(kb+3)*68 + lrow]    = a0.w;
        As[(kb+0)*68 + lrow+32] = a1.x; As[(kb+1)*68 + lrow+32] = a1.y;
        As[(kb+2)*68 + lrow+32] = a1.z; As[(kb+3)*68 + lrow+32] = a1.w;
        Bs[(kb+0)*68 + lrow]    = b0.x; Bs[(kb+1)*68 + lrow]    = b0.y;
        Bs[(kb+2)*68 + lrow]    = b0.z; Bs[(kb+3)*68 + lrow]    = b0.w;
        Bs[(kb+0)*68 + lrow+32] = b1.x; Bs[(kb+1)*68 + lrow+32] = b1.y;
        Bs[(kb+2)*68 + lrow+32] = b1.z; Bs[(kb+3)*68 + lrow+32] = b1.w;
        __syncthreads();
        #pragma unroll
        for (int kk = 0; kk < 32; ++kk) {
            float4 av = *reinterpret_cast<const float4*>(As + kk*68 + tm);
            float4 bv = *reinterpret_cast<const float4*>(Bs + kk*68 + tn);
            acc[0][0] += av.x*bv.x; acc[0][1] += av.x*bv.y; acc[0][2] += av.x*bv.z; acc[0][3] += av.x*bv.w;
            acc[1][0] += av.y*bv.x; acc[1][1] += av.y*bv.y; acc[1][2] += av.y*bv.z; acc[1][3] += av.y*bv.w;
            acc[2][0] += av.z*bv.x; acc[2][1] += av.z*bv.y; acc[2][2] += av.z*bv.z; acc[2][3] += av.z*bv.w;
            acc[3][0] += av.w*bv.x; acc[3][1] += av.w*bv.y; acc[3][2] += av.w*bv.z; acc[3][3] += av.w*bv.w;
        }
    }

    #pragma unroll
    for (int i = 0; i < 4; ++i) {
        float r0 = acc[i][0], r1 = acc[i][1], r2 = acc[i][2], r3 = acc[i][3];
        if (bp) { r0 += bp[n0+tn+0]; r1 += bp[n0+tn+1]; r2 += bp[n0+tn+2]; r3 += bp[n0+tn+3]; }
        if (act) { r0 = ftanh(r0); r1 = ftanh(r1); r2 = ftanh(r2); r3 = ftanh(r3); }
        float4 v = make_float4(r0, r1, r2, r3);
        *reinterpret_cast<float4*>(C + (size_t)(m0+tm+i)*ldc + (n0+tn)) = v;
    }
}

// ---------------------------------------------------------------------------
// Skinny GEMM for M=64: tile 16 rows x 64 cols. grid = (N/64, 4, nz).
// C = A @ B^T + bias.  A:(64,K)  B:(N,K).
// ---------------------------------------------------------------------------
__global__ __launch_bounds__(256) void gemm_skinny(
    const float* A0, const float* B0, const float* bias0, float* C0,
    const float* A1, const float* B1, const float* bias1, float* C1,
    int N, int K, int ldc)
{
    const float* A  = blockIdx.z ? A1 : A0;
    const float* B  = blockIdx.z ? B1 : B0;
    const float* bp = blockIdx.z ? bias1 : bias0;
    float*       C  = blockIdx.z ? C1 : C0;

    __shared__ float As[16*64];
    const int n0 = blockIdx.x * 64;
    const int m0 = blockIdx.y * 16;
    const int t  = threadIdx.x;
    const int n  = t & 63;
    const int mb = t >> 6;   // 0..3

    float acc[4] = {};

    for (int k0 = 0; k0 < K; k0 += 64) {
        __syncthreads();
        const int row = t >> 4, c4 = t & 15;
        *reinterpret_cast<float4*>(As + row*64 + c4*4) =
            *reinterpret_cast<const float4*>(A + (size_t)(m0+row)*K + k0 + c4*4);
        __syncthreads();
        const float* Bp = B + (size_t)(n0+n)*K + k0;
        #pragma unroll
        for (int q = 0; q < 16; ++q) {
            float4 bv = *reinterpret_cast<const float4*>(Bp + q*4);
            #pragma unroll
            for (int mm = 0; mm < 4; ++mm) {
                float4 av = *reinterpret_cast<const float4*>(As + (mb + 4*mm)*64 + q*4);
                acc[mm] += av.x*bv.x + av.y*bv.y + av.z*bv.z + av.w*bv.w;
            }
        }
    }
    const float bz = bp ? bp[n0+n] : 0.0f;
    #pragma unroll
    for (int mm = 0; mm < 4; ++mm)
        C[(size_t)(m0 + mb + 4*mm)*ldc + n0 + n] = acc[mm] + bz;
}

// ---------------------------------------------------------------------------
// Skinny GEMM (K=768) with GRU-gate A-provider prologue.
// blockIdx.z==0: A = gru_gate(giA,ghA,hA) rows [m0,m0+16), computed in LDS;
//                blocks with x==0 also write hnew (+ optional bf16 hi/lo).
// blockIdx.z==1: A = A1 (plain), staged whole tile into LDS.
// C = A @ B^T + bias. grid (N/64, 4, nz).
// ---------------------------------------------------------------------------
__global__ __launch_bounds__(256) void skinny_gate_k(
    const float* giA, const float* ghA, const float* hA,
    float* hnew, unsigned short* ahi, unsigned short* alo,
    const float* B0, const float* bias0, float* C0,
    const float* A1, const float* B1, const float* bias1, float* C1,
    int N, int ldc)
{
    __shared__ float Af[16*768];
    const int t  = threadIdx.x;
    const int m0 = blockIdx.y * 16;
    const int n0 = blockIdx.x * 64;

    if (blockIdx.z == 0) {
        for (int i = t; i < 16*768; i += 256) {
            int r = i / 768, j = i - r*768;
            int brow = m0 + r;
            float h = hA[(size_t)brow*768 + j];
            float v = gru_fuse(giA[(size_t)brow*2304 + j],
                               giA[(size_t)brow*2304 + j + 768],
                               giA[(size_t)brow*2304 + j + 1536],
                               ghA[(size_t)brow*2304 + j],
                               ghA[(size_t)brow*2304 + j + 768],
                               ghA[(size_t)brow*2304 + j + 1536], h);
            Af[i] = v;
            if (blockIdx.x == 0) {
                hnew[(size_t)brow*768 + j] = v;
                if (ahi) {
                    unsigned short hh = f2bf(v);
                    ahi[(size_t)brow*768 + j] = hh;
                    alo[(size_t)brow*768 + j] = f2bf(v - bf2f(hh));
                }
            }
        }
    } else {
        for (int i = t; i < 16*768; i += 256) {
            int r = i / 768, j = i - r*768;
            Af[i] = A1[(size_t)(m0 + r)*768 + j];
        }
    }
    __syncthreads();

    const float* B  = blockIdx.z ? B1 : B0;
    const float* bp = blockIdx.z ? bias1 : bias0;
    float*       C  = blockIdx.z ? C1 : C0;

    const int n  = t & 63;
    const int mb = t >> 6;
    const float* Bp = B + (size_t)(n0 + n)*768;
    float acc[4] = {};
    #pragma unroll 4
    for (int q = 0; q < 192; ++q) {
        float4 bv = *reinterpret_cast<const float4*>(Bp + q*4);
        #pragma unroll
        for (int mm = 0; mm < 4; ++mm) {
            float4 av = *reinterpret_cast<const float4*>(Af + (mb + 4*mm)*768 + q*4);
            acc[mm] += av.x*bv.x + av.y*bv.y + av.z*bv.z + av.w*bv.w;
        }
    }
    const float bz = bp ? bp[n0+n] : 0.0f;
    #pragma unroll
    for (int mm = 0; mm < 4; ++mm)
        C[(size_t)(m0 + mb + 4*mm)*ldc + n0 + n] = acc[mm] + bz;
}

// ---------------------------------------------------------------------------
// Encoder embedding gather
// ---------------------------------------------------------------------------
__global__ __launch_bounds__(256) void embed_k(const int* inp, const float* emb, float* x)
{
    int i = blockIdx.x*256 + threadIdx.x;
    if (i >= 4096*128) return;
    int row = i >> 7, c4 = i & 127;
    int tok = inp[row];
    *reinterpret_cast<float4*>(x + (size_t)row*512 + c4*4) =
        *reinterpret_cast<const float4*>(emb + (size_t)tok*512 + c4*4);
}

__global__ __launch_bounds__(256) void transpose_k(const float* W1, float* W1T)
{
    int i = blockIdx.x*256 + threadIdx.x;
    if (i >= 512*768) return;
    int n = i / 512, k = i % 512;
    W1T[i] = W1[(size_t)k*768 + n];
}

// ---------------------------------------------------------------------------
// emb_dec fp32 -> bf16 hi/lo split. grid 24000 x 256, 4 elems/thread.
// ---------------------------------------------------------------------------
__global__ __launch_bounds__(256) void convemb_k(
    const float* __restrict__ B, unsigned short* __restrict__ hi, unsigned short* __restrict__ lo)
{
    int i = blockIdx.x*256 + threadIdx.x;   // float4 index, total 6,144,000
    float4 v = reinterpret_cast<const float4*>(B)[i];
    ushort4 h, l;
    h.x = f2bf(v.x); l.x = f2bf(v.x - bf2f(h.x));
    h.y = f2bf(v.y); l.y = f2bf(v.y - bf2f(h.y));
    h.z = f2bf(v.z); l.z = f2bf(v.z - bf2f(h.z));
    h.w = f2bf(v.w); l.w = f2bf(v.w - bf2f(h.w));
    reinterpret_cast<ushort4*>(hi)[i] = h;
    reinterpret_cast<ushort4*>(lo)[i] = l;
}

// ---------------------------------------------------------------------------
// Persistent encoder layer: one block per (b, dir), loops all 64 steps.
// ---------------------------------------------------------------------------
__global__ __launch_bounds__(256) void enc_layer_k(
    const float* giF, const float* giB,
    const float* Whh, const float* bhh,
    float* yout, float* hfin)
{
    const int b = blockIdx.x, d = blockIdx.y, t = threadIdx.x;
    const float* gi_base = d ? giB : giF;
    const float* W = Whh + (size_t)d*768*256;
    const float br  = bhh[d*768 + t];
    const float bz2 = bhh[d*768 + t + 256];
    const float bn  = bhh[d*768 + t + 512];

    __shared__ float hs[256];
    hs[t] = 0.0f;
    __syncthreads();

    for (int step = 0; step < 64; ++step) {
        const int s = d ? (63 - step) : step;
        const float* gi = gi_base + (size_t)(s*64 + b)*768;
        const float gr = gi[t], gz = gi[t+256], gn = gi[t+512];
        float ar = 0.f, az = 0.f, an = 0.f;
        #pragma unroll 8
        for (int q = 0; q < 64; ++q) {
            float4 hv = *reinterpret_cast<const float4*>(hs + q*4);
            float4 wr = *reinterpret_cast<const float4*>(W + (size_t)(t      )*256 + q*4);
            float4 wz = *reinterpret_cast<const float4*>(W + (size_t)(t + 256)*256 + q*4);
            float4 wn = *reinterpret_cast<const float4*>(W + (size_t)(t + 512)*256 + q*4);
            ar += hv.x*wr.x + hv.y*wr.y + hv.z*wr.z + hv.w*wr.w;
            az += hv.x*wz.x + hv.y*wz.y + hv.z*wz.z + hv.w*wz.w;
            an += hv.x*wn.x + hv.y*wn.y + hv.z*wn.z + hv.w*wn.w;
        }
        float r  = fsig(gr + ar + br);
        float z  = fsig(gz + az + bz2);
        float n  = ftanh(gn + r*(an + bn));
        float hn2 = (1.0f - z)*n + z*hs[t];
        __syncthreads();
        hs[t] = hn2;
        yout[(size_t)(s*64 + b)*512 + d*256 + t] = hn2;
        __syncthreads();
    }
    hfin[(size_t)b*512 + d*256 + t] = hs[t];
}

// ---------------------------------------------------------------------------
// Fused attention: scores -> softmax -> context -> wgt_in (emb | Xa). grid 64.
// ---------------------------------------------------------------------------
__global__ __launch_bounds__(256) void att_fused_k(
    const float* __restrict__ w1e, const float* __restrict__ w2h,
    const float* __restrict__ Vp, const float* __restrict__ enc_out,
    const float* __restrict__ emb_dec, const int* __restrict__ y,
    int step, float* __restrict__ wgt_in)
{
    const int b = blockIdx.x, t = threadIdx.x;
    __shared__ float w2s[768];
    __shared__ float vps[768];
    __shared__ float aa[64];
    for (int i = t; i < 768; i += 256) { w2s[i] = w2h[(size_t)b*768 + i]; vps[i] = Vp[i]; }
    __syncthreads();
    const int wv = t >> 6, ln = t & 63;
    for (int ss = 0; ss < 16; ++ss) {
        const int s = wv*16 + ss;
        const float* wrow = w1e + (size_t)(s*64 + b)*768;
        float acc = 0.f;
        #pragma unroll
        for (int q = 0; q < 12; ++q) {
            int e = ln + q*64;
            acc += ftanh(wrow[e] + w2s[e]) * vps[e];
        }
        for (int off = 32; off; off >>= 1) acc += __shfl_down(acc, off);
        if (ln == 0) aa[s] = acc;
    }
    __syncthreads();
    if (t < 64) {
        float v = aa[t];
        float m = v;
        for (int off = 32; off; off >>= 1) m = fmaxf(m, __shfl_xor(m, off));
        float e = __expf(v - m);
        float ssum = e;
        for (int off = 32; off; off >>= 1) ssum += __shfl_xor(ssum, off);
        aa[t] = e / ssum;
    }
    __syncthreads();
    for (int e = t; e < 512; e += 256) {
        float acc = 0.f;
        #pragma unroll 8
        for (int s = 0; s < 64; ++s)
            acc += aa[s] * enc_out[(size_t)(s*64 + b)*512 + e];
        wgt_in[(size_t)b*1280 + 768 + e] = acc;
    }
    const int tok = (step == 0) ? 0 : y[(step-1)*64 + b];
    for (int e = t; e < 768; e += 256)
        wgt_in[(size_t)b*1280 + e] = emb_dec[(size_t)tok*768 + e];
}

// ---------------------------------------------------------------------------
// Split-bf16 MFMA vocab GEMM: C = (Ahi+Alo)@(Bhi+Blo)^T + bias (raw logits).
// A:(64,768) B:(32000,768). grid 250 blocks, 256 thr (4 waves, each 64x32).
// ---------------------------------------------------------------------------
__global__ __launch_bounds__(256) void vocab_mfma_k(
    const unsigned short* __restrict__ Ahi, const unsigned short* __restrict__ Alo,
    const unsigned short* __restrict__ Bhi, const unsigned short* __restrict__ Blo,
    const float* __restrict__ bias, float* __restrict__ Cs)
{
    __shared__ __align__(16) unsigned short As[2][64][72];
    __shared__ __align__(16) unsigned short Bs[2][128][72];
    const int t = threadIdx.x;
    const int n0 = blockIdx.x * 128;
    const int wv = t >> 6, ln = t & 63;

    f32x4 acc[4][2];
    #pragma unroll
    for (int i = 0; i < 4; ++i)
        #pragma unroll
        for (int j = 0; j < 2; ++j) acc[i][j] = (f32x4){0.f,0.f,0.f,0.f};

    const int lr = t >> 3;        // 0..31
    const int lc = (t & 7) * 8;   // 0..56

    for (int k0 = 0; k0 < 768; k0 += 64) {
        __syncthreads();
        *reinterpret_cast<uint4*>(&As[0][lr   ][lc]) = *reinterpret_cast<const uint4*>(&Ahi[(size_t)(lr   )*768 + k0 + lc]);
        *reinterpret_cast<uint4*>(&As[0][lr+32][lc]) = *reinterpret_cast<const uint4*>(&Ahi[(size_t)(lr+32)*768 + k0 + lc]);
        *reinterpret_cast<uint4*>(&As[1][lr   ][lc]) = *reinterpret_cast<const uint4*>(&Alo[(size_t)(lr   )*768 + k0 + lc]);
        *reinterpret_cast<uint4*>(&As[1][lr+32][lc]) = *reinterpret_cast<const uint4*>(&Alo[(size_t)(lr+32)*768 + k0 + lc]);
        #pragma unroll
        for (int i = 0; i < 4; ++i) {
            int r = lr + 32*i;
            *reinterpret_cast<uint4*>(&Bs[0][r][lc]) = *reinterpret_cast<const uint4*>(&Bhi[(size_t)(n0 + r)*768 + k0 + lc]);
            *reinterpret_cast<uint4*>(&Bs[1][r][lc]) = *reinterpret_cast<const uint4*>(&Blo[(size_t)(n0 + r)*768 + k0 + lc]);
        }
        __syncthreads();
        #pragma unroll
        for (int ks = 0; ks < 2; ++ks) {
            const int ko = ks*32 + (ln >> 4)*8;
            bf16x8 ah[4], al[4], bh[2], bl[2];
            #pragma unroll
            for (int m = 0; m < 4; ++m) {
                ah[m] = *reinterpret_cast<const bf16x8*>(&As[0][m*16 + (ln&15)][ko]);
                al[m] = *reinterpret_cast<const bf16x8*>(&As[1][m*16 + (ln&15)][ko]);
            }
            #pragma unroll
            for (int n = 0; n < 2; ++n) {
                bh[n] = *reinterpret_cast<const bf16x8*>(&Bs[0][wv*32 + n*16 + (ln&15)][ko]);
                bl[n] = *reinterpret_cast<const bf16x8*>(&Bs[1][wv*32 + n*16 + (ln&15)][ko]);
            }
            #pragma unroll
            for (int m = 0; m < 4; ++m)
                #pragma unroll
                for (int n = 0; n < 2; ++n) {
                    acc[m][n] = __builtin_amdgcn_mfma_f32_16x16x32_bf16(ah[m], bh[n], acc[m][n], 0,0,0);
                    acc[m][n] = __builtin_amdgcn_mfma_f32_16x16x32_bf16(ah[m], bl[n], acc[m][n], 0,0,0);
                    acc[m][n] = __builtin_amdgcn_mfma_f32_16x16x32_bf16(al[m], bh[n], acc[m][n], 0,0,0);
                }
        }
    }
    #pragma unroll
    for (int m = 0; m < 4; ++m) {
        #pragma unroll
        for (int n = 0; n < 2; ++n) {
            const int col = n0 + wv*32 + n*16 + (ln & 15);
            const float bz = bias[col];
            #pragma unroll
            for (int j = 0; j < 4; ++j) {
                const int row = m*16 + (ln >> 4)*4 + j;
                Cs[(size_t)row*VDIM + col] = acc[m][n][j] + bz;
            }
        }
    }
}

// ---------------------------------------------------------------------------
// Fused copy-score + softmax + scatter. grid 64 x 256. Writes out row once.
// ---------------------------------------------------------------------------
__global__ __launch_bounds__(256) void smax2_k(
    const float* __restrict__ scratch, const float* __restrict__ scb,
    const float* __restrict__ h1, const int* __restrict__ y, float* __restrict__ out)
{
    const int b = blockIdx.x, t = threadIdx.x;
    __shared__ float hsh[768];
    __shared__ float cps[64];
    __shared__ float red[4];
    for (int i = t; i < 768; i += 256) hsh[i] = h1[(size_t)b*768 + i];
    __syncthreads();
    const int wv = t >> 6, ln = t & 63;
    for (int ss = 0; ss < 16; ++ss) {
        const int s = wv*16 + ss;
        const float* sp = scb + (size_t)(s*64 + b)*768;
        float acc = 0.f;
        #pragma unroll
        for (int q = 0; q < 12; ++q) { int e = ln + q*64; acc += sp[e]*hsh[e]; }
        for (int off = 32; off; off >>= 1) acc += __shfl_down(acc, off);
        if (ln == 0) cps[s] = ftanh(acc);
    }
    __syncthreads();

    const float* row = scratch + (size_t)b*VDIM;
    float m = -1e30f;
    for (int i = t; i < VDIM; i += 256) m = fmaxf(m, row[i]);
    for (int off = 32; off; off >>= 1) m = fmaxf(m, __shfl_xor(m, off));
    if (ln == 0) red[wv] = m;
    __syncthreads();
    const float bm = fmaxf(fmaxf(red[0], red[1]), fmaxf(red[2], red[3]));
    __syncthreads();

    float s = 0.f;
    for (int i = t; i < VDIM; i += 256) s += __expf(row[i] - bm);
    if (t < 64) s += __expf(cps[t] - bm);
    for (int off = 32; off; off >>= 1) s += __shfl_xor(s, off);
    if (ln == 0) red[wv] = s;
    __syncthreads();
    const float inv = 1.0f / (red[0] + red[1] + red[2] + red[3]);

    float* orow = out + (size_t)b*NCOL;
    for (int i = t; i < VDIM; i += 256) orow[i] = __expf(row[i] - bm) * inv;
    if (t >= 192) orow[VDIM + (t - 192)] = 0.0f;
    __syncthreads();
    if (t < 64) atomicAdd(&orow[y[t*64 + b]], __expf(cps[t] - bm) * inv);
}

// ---------------------------------------------------------------------------
extern "C" void kernel_launch(void* const* d_in, const int* in_sizes, int n_in,
                              void* d_out, int out_size, void* d_ws, size_t ws_size,
                              hipStream_t stream)
{
    (void)in_sizes; (void)n_in; (void)out_size;
    const int*   inp       = (const int*)  d_in[0];
    const int*   y         = (const int*)  d_in[1];
    const float* emb_enc   = (const float*)d_in[2];
    const float* enc_Wih   = (const float*)d_in[3];
    const float* enc_Whh   = (const float*)d_in[4];
    const float* enc_bih   = (const float*)d_in[5];
    const float* enc_bhh   = (const float*)d_in[6];
    const float* out_enc_W = (const float*)d_in[7];
    const float* emb_dec   = (const float*)d_in[8];
    const float* dec_Wih   = (const float*)d_in[9];
    const float* dec_Whh   = (const float*)d_in[10];
    const float* dec_bih   = (const float*)d_in[11];
    const float* dec_bhh   = (const float*)d_in[12];
    const float* out_b     = (const float*)d_in[13];
    const float* W1        = (const float*)d_in[14];
    const float* l2_W      = (const float*)d_in[15];
    const float* l2_b      = (const float*)d_in[16];
    const float* l3_W      = (const float*)d_in[17];
    const float* l3_b      = (const float*)d_in[18];
    const float* Vp        = (const float*)d_in[19];
    float* out = (float*)d_out;
    float* ws  = (float*)d_ws;

    size_t off = 0;
    auto alloc = [&](size_t n) { float* p = ws + off; off += (n + 63) & ~(size_t)63; return p; };
    float* x0     = alloc(4096*512);
    float* x1     = alloc(4096*512);
    float* x2     = alloc(4096*512);   // enc_out
    float* giF    = alloc(4096*768);
    float* giB    = alloc(4096*768);
    float* w1e    = alloc(4096*768);
    float* scb    = alloc(4096*768);
    float* W1T    = alloc(768*512);
    float* hfin   = alloc(128*512);
    float* hdecA  = alloc(128*768);
    float* hdecB  = alloc(128*768);
    float* w2h    = alloc(64*768);
    float* wgt_in = alloc(64*1280);
    float* wgt    = alloc(64*768);
    float* gi0    = alloc(64*2304);
    float* gh0    = alloc(64*2304);
    float* gi1    = alloc(64*2304);
    float* gh1    = alloc(64*2304);
    float* scratch= alloc(64*VDIM);
    unsigned short* Ahi = (unsigned short*)alloc(64*768/2);
    unsigned short* Alo = (unsigned short*)alloc(64*768/2);
    // big bf16 emb_dec split arrays (24,576,000 ushorts each)
    unsigned short* Bhi = (unsigned short*)alloc((size_t)VDIM*768/2);
    unsigned short* Blo = (unsigned short*)alloc((size_t)VDIM*768/2);
    const bool use_mfma = ws_size >= off * sizeof(float);

    // ---- encoder ----
    embed_k<<<2048, 256, 0, stream>>>(inp, emb_enc, x0);
    transpose_k<<<(512*768 + 255)/256, 256, 0, stream>>>(W1, W1T);
    if (use_mfma)
        convemb_k<<<24000, 256, 0, stream>>>(emb_dec, Bhi, Blo);

    for (int l = 0; l < 2; ++l) {
        const float* xin  = l ? x1 : x0;
        float*       xout = l ? x2 : x1;
        const float* Wih = enc_Wih + (size_t)l*2*768*512;
        const float* Whh = enc_Whh + (size_t)l*2*768*256;
        const float* bih = enc_bih + (size_t)l*2*768;
        const float* bhh = enc_bhh + (size_t)l*2*768;
        gemm64<<<dim3(12, 64, 2), 256, 0, stream>>>(
            xin, Wih,           bih,       giF, 0,
            xin, Wih + 768*512, bih + 768, giB, 0,
            4096, 768, 512, 768);
        enc_layer_k<<<dim3(64, 2), 256, 0, stream>>>(
            giF, giB, Whh, bhh, xout, hfin + (size_t)l*64*512);
    }

    // decoder initial hidden: (128,512) @ out_enc_W^T -> (128,768)
    gemm64<<<dim3(12, 2, 1), 256, 0, stream>>>(
        hfin, out_enc_W, nullptr, hdecA, 0,
        hfin, out_enc_W, nullptr, hdecA, 0,
        128, 768, 512, 768);

    // w1e = enc_out @ W1 ; sc_base = tanh(enc_out @ out_enc_W^T)
    gemm64<<<dim3(12, 64, 2), 256, 0, stream>>>(
        x2, W1T,       nullptr, w1e, 0,
        x2, out_enc_W, nullptr, scb, 1,
        4096, 768, 512, 768);

    // bootstrap w2h from initial h1
    gemm_skinny<<<dim3(12, 4, 1), 256, 0, stream>>>(
        hdecA + 64*768, l2_W, l2_b, w2h,
        hdecA + 64*768, l2_W, l2_b, w2h,
        768, 768, 768);

    // ---- decoder ----
    for (int st = 0; st < TSL; ++st) {
        float* h0c = (st & 1) ? hdecB : hdecA;
        float* h0n = (st & 1) ? hdecA : hdecB;
        float* h1c = h0c + 64*768;
        float* h1n = h0n + 64*768;
        float* orow = out + (size_t)st*BSZ*NCOL;

        att_fused_k<<<64, 256, 0, stream>>>(w1e, w2h, Vp, x2, emb_dec, y, st, wgt_in);

        gemm_skinny<<<dim3(12, 4, 1), 256, 0, stream>>>(
            wgt_in, l3_W, l3_b, wgt,
            wgt_in, l3_W, l3_b, wgt,
            768, 1280, 768);

        // layer 0: gi0 = wgt @ Wih0^T ; gh0 = h0 @ Whh0^T
        gemm_skinny<<<dim3(36, 4, 2), 256, 0, stream>>>(
            wgt, dec_Wih, dec_bih, gi0,
            h0c, dec_Whh, dec_bhh, gh0,
            2304, 768, 2304);

        // gate0 -> h0n (prologue) + gi1 = h0n @ Wih1^T ; gh1 = h1 @ Whh1^T
        skinny_gate_k<<<dim3(36, 4, 2), 256, 0, stream>>>(
            gi0, gh0, h0c, h0n, nullptr, nullptr,
            dec_Wih + (size_t)2304*768, dec_bih + 2304, gi1,
            h1c, dec_Whh + (size_t)2304*768, dec_bhh + 2304, gh1,
            2304, 2304);

        // gate1 -> h1n (+bf16 hi/lo) + w2h(next) = h1n @ l2_W^T
        skinny_gate_k<<<dim3(12, 4, 1), 256, 0, stream>>>(
            gi1, gh1, h1c, h1n, Ahi, Alo,
            l2_W, l2_b, w2h,
            nullptr, nullptr, nullptr, nullptr,
            768, 768);

        // vocab logits -> scratch
        if (use_mfma)
            vocab_mfma_k<<<250, 256, 0, stream>>>(Ahi, Alo, Bhi, Blo, out_b, scratch);
        else
            gemm64<<<dim3(500, 1, 1), 256, 0, stream>>>(
                h1n, emb_dec, out_b, scratch, 0,
                h1n, emb_dec, out_b, scratch, 0,
                64, VDIM, 768, VDIM);

        smax2_k<<<64, 256, 0, stream>>>(scratch, scb, h1n, y, orow);
    }
}

// Round 3
// 13549.208 us; speedup vs baseline: 1.5265x; 1.5265x over previous
//
#include <hip/hip_runtime.h>

#define SLEN 64
#define BSZ  64
#define TSL  48
#define VDIM 32000
#define NCOL 32064   // VDIM + SLEN

typedef __attribute__((ext_vector_type(8))) _Float16 f16x8;
typedef __attribute__((ext_vector_type(4))) float f32x4;

__device__ __forceinline__ float fsig(float x){
    return 1.0f/(1.0f + __expf(-x));
}
__device__ __forceinline__ float ftanh(float x){
    float e = __expf(2.0f*x);
    return 1.0f - 2.0f/(e + 1.0f);
}
__device__ __forceinline__ unsigned short f2bf(float x){
    unsigned u = __float_as_uint(x);
    u += 0x7FFF + ((u >> 16) & 1);
    return (unsigned short)(u >> 16);
}
__device__ __forceinline__ float bf2f(unsigned short h){
    return __uint_as_float(((unsigned)h) << 16);
}
__device__ __forceinline__ unsigned short f2h(float x){
    union { _Float16 f; unsigned short u; } c; c.f = (_Float16)x; return c.u;
}
__device__ __forceinline__ unsigned short f2h_hi(float x, float& rem){
    _Float16 h = (_Float16)x;
    rem = x - (float)h;
    union { _Float16 f; unsigned short u; } c; c.f = h; return c.u;
}
__device__ __forceinline__ float gru_fuse(float gir,float giz,float gin,
                                          float ghr,float ghz,float ghn,float h){
    float r = fsig(gir + ghr);
    float z = fsig(giz + ghz);
    float n = ftanh(gin + r*ghn);
    return (1.0f - z)*n + z*h;
}

// ===========================================================================
// MFMA GEMM: C(MxN) = A(MxK) @ B(NxK)^T + bias, optional tanh.
// A fp32 (lda=K), converted to fp16 hi/lo inline while staging to LDS.
// B pre-converted fp16 (Bh) with optional lo-correction (Bl; nullptr => 2-term).
// grid = (ceil(maxN/128), M/64, nz). z selects parameter set. N%128==0, K%64==0.
// ===========================================================================
__global__ __launch_bounds__(256) void mfma_gemm(
    const float* A0, const unsigned short* Bh0, const unsigned short* Bl0,
    const float* bias0, float* C0, int N0, int ldc0, int act0,
    const float* A1, const unsigned short* Bh1, const unsigned short* Bl1,
    const float* bias1, float* C1, int N1, int ldc1, int act1,
    int K)
{
    const float* A; const unsigned short* Bh; const unsigned short* Bl;
    const float* bias; float* C; int N, ldc, act;
    if (blockIdx.z == 0) { A=A0; Bh=Bh0; Bl=Bl0; bias=bias0; C=C0; N=N0; ldc=ldc0; act=act0; }
    else                 { A=A1; Bh=Bh1; Bl=Bl1; bias=bias1; C=C1; N=N1; ldc=ldc1; act=act1; }

    const int n0 = blockIdx.x * 128;
    if (n0 >= N) return;
    const int m0 = blockIdx.y * 64;

    __shared__ __align__(16) unsigned short As[2][64][72];
    __shared__ __align__(16) unsigned short Bs[2][128][72];

    const int t  = threadIdx.x;
    const int wv = t >> 6, ln = t & 63;
    const bool has_lo = (Bl != nullptr);

    f32x4 acc[4][2];
    #pragma unroll
    for (int i = 0; i < 4; ++i)
        #pragma unroll
        for (int j = 0; j < 2; ++j) acc[i][j] = (f32x4){0.f,0.f,0.f,0.f};

    for (int k0 = 0; k0 < K; k0 += 64) {
        __syncthreads();
        // stage A: 64 rows x 64 cols fp32 -> fp16 hi/lo
        #pragma unroll
        for (int it = 0; it < 4; ++it) {
            int idx = t + it*256;           // 0..1023
            int r = idx >> 4, c4 = (idx & 15) * 4;
            float4 v = *reinterpret_cast<const float4*>(A + (size_t)(m0+r)*K + k0 + c4);
            ushort4 h, l; float rm;
            h.x = f2h_hi(v.x, rm); l.x = f2h(rm);
            h.y = f2h_hi(v.y, rm); l.y = f2h(rm);
            h.z = f2h_hi(v.z, rm); l.z = f2h(rm);
            h.w = f2h_hi(v.w, rm); l.w = f2h(rm);
            *reinterpret_cast<ushort4*>(&As[0][r][c4]) = h;
            *reinterpret_cast<ushort4*>(&As[1][r][c4]) = l;
        }
        // stage B hi: 128 rows x 64 halves
        #pragma unroll
        for (int it = 0; it < 4; ++it) {
            int idx = t + it*256;           // 0..1023
            int r = idx >> 3, c8 = (idx & 7) * 8;
            *reinterpret_cast<uint4*>(&Bs[0][r][c8]) =
                *reinterpret_cast<const uint4*>(&Bh[(size_t)(n0+r)*K + k0 + c8]);
        }
        if (has_lo) {
            #pragma unroll
            for (int it = 0; it < 4; ++it) {
                int idx = t + it*256;
                int r = idx >> 3, c8 = (idx & 7) * 8;
                *reinterpret_cast<uint4*>(&Bs[1][r][c8]) =
                    *reinterpret_cast<const uint4*>(&Bl[(size_t)(n0+r)*K + k0 + c8]);
            }
        }
        __syncthreads();
        #pragma unroll
        for (int ks = 0; ks < 2; ++ks) {
            const int ko = ks*32 + (ln >> 4)*8;
            f16x8 ah[4], al[4], bh[2], bl[2];
            #pragma unroll
            for (int m = 0; m < 4; ++m) {
                ah[m] = *reinterpret_cast<const f16x8*>(&As[0][m*16 + (ln&15)][ko]);
                al[m] = *reinterpret_cast<const f16x8*>(&As[1][m*16 + (ln&15)][ko]);
            }
            #pragma unroll
            for (int n = 0; n < 2; ++n) {
                bh[n] = *reinterpret_cast<const f16x8*>(&Bs[0][wv*32 + n*16 + (ln&15)][ko]);
                if (has_lo)
                    bl[n] = *reinterpret_cast<const f16x8*>(&Bs[1][wv*32 + n*16 + (ln&15)][ko]);
            }
            #pragma unroll
            for (int m = 0; m < 4; ++m)
                #pragma unroll
                for (int n = 0; n < 2; ++n) {
                    acc[m][n] = __builtin_amdgcn_mfma_f32_16x16x32_f16(ah[m], bh[n], acc[m][n], 0,0,0);
                    acc[m][n] = __builtin_amdgcn_mfma_f32_16x16x32_f16(al[m], bh[n], acc[m][n], 0,0,0);
                    if (has_lo)
                        acc[m][n] = __builtin_amdgcn_mfma_f32_16x16x32_f16(ah[m], bl[n], acc[m][n], 0,0,0);
                }
        }
    }
    #pragma unroll
    for (int m = 0; m < 4; ++m) {
        #pragma unroll
        for (int n = 0; n < 2; ++n) {
            const int col = n0 + wv*32 + n*16 + (ln & 15);
            const float bz = bias ? bias[col] : 0.0f;
            #pragma unroll
            for (int j = 0; j < 4; ++j) {
                const int row = m0 + m*16 + (ln >> 4)*4 + j;
                float v = acc[m][n][j] + bz;
                if (act) v = ftanh(v);
                C[(size_t)row*ldc + col] = v;
            }
        }
    }
}

// ===========================================================================
// fp32 -> fp16 hi/lo conversion (weights, one-time). n4 = elems/4.
// ===========================================================================
__global__ __launch_bounds__(256) void convhl_k(
    const float* __restrict__ W, unsigned short* __restrict__ hi,
    unsigned short* __restrict__ lo, int n4)
{
    int i = blockIdx.x*256 + threadIdx.x;
    if (i >= n4) return;
    float4 v = reinterpret_cast<const float4*>(W)[i];
    ushort4 h, l; float r;
    h.x = f2h_hi(v.x, r); l.x = f2h(r);
    h.y = f2h_hi(v.y, r); l.y = f2h(r);
    h.z = f2h_hi(v.z, r); l.z = f2h(r);
    h.w = f2h_hi(v.w, r); l.w = f2h(r);
    reinterpret_cast<ushort4*>(hi)[i] = h;
    reinterpret_cast<ushort4*>(lo)[i] = l;
}
__global__ __launch_bounds__(256) void conv16_k(
    const float* __restrict__ W, unsigned short* __restrict__ hi, int n4)
{
    int i = blockIdx.x*256 + threadIdx.x;
    if (i >= n4) return;
    float4 v = reinterpret_cast<const float4*>(W)[i];
    ushort4 h;
    h.x = f2h(v.x); h.y = f2h(v.y); h.z = f2h(v.z); h.w = f2h(v.w);
    reinterpret_cast<ushort4*>(hi)[i] = h;
}

// ===========================================================================
// fp32 fallback GEMMs (used only when ws is too small for the fp16 path)
// ===========================================================================
__global__ __launch_bounds__(256) void gemm64(
    const float* A0, const float* B0, const float* bias0, float* C0, int act0,
    const float* A1, const float* B1, const float* bias1, float* C1, int act1,
    int M, int N, int K, int ldc)
{
    const float* A  = blockIdx.z ? A1 : A0;
    const float* B  = blockIdx.z ? B1 : B0;
    const float* bp = blockIdx.z ? bias1 : bias0;
    float*       C  = blockIdx.z ? C1 : C0;
    const int act   = blockIdx.z ? act1 : act0;

    __shared__ float As[32*68];
    __shared__ float Bs[32*68];

    const int n0 = blockIdx.x * 64;
    const int m0 = blockIdx.y * 64;
    const int t  = threadIdx.x;
    const int lrow = t >> 3;
    const int lc4  = t & 7;
    const int tm = (t >> 4) << 2;
    const int tn = (t & 15) << 2;

    float acc[4][4] = {};

    for (int k0 = 0; k0 < K; k0 += 32) {
        float4 a0 = *reinterpret_cast<const float4*>(A + (size_t)(m0+lrow   )*K + k0 + lc4*4);
        float4 a1 = *reinterpret_cast<const float4*>(A + (size_t)(m0+lrow+32)*K + k0 + lc4*4);
        float4 b0 = *reinterpret_cast<const float4*>(B + (size_t)(n0+lrow   )*K + k0 + lc4*4);
        float4 b1 = *reinterpret_cast<const float4*>(B + (size_t)(n0+lrow+32)*K + k0 + lc4*4);
        __syncthreads();
        const int kb = lc4*4;
        As[(kb+0)*68 + lrow]    = a0.x; As[(kb+1)*68 + lrow]    = a0.y;
        As[(kb+2)*68 + lrow]    = a0.z; As[(kb+3)*68 + lrow]    = a0.w;
        As[(kb+0)*68 + lrow+32] = a1.x; As[(kb+1)*68 + lrow+32] = a1.y;
        As[(kb+2)*68 + lrow+32] = a1.z; As[(kb+3)*68 + lrow+32] = a1.w;
        Bs[(kb+0)*68 + lrow]    = b0.x; Bs[(kb+1)*68 + lrow]    = b0.y;
        Bs[(kb+2)*68 + lrow]    = b0.z; Bs[(kb+3)*68 + lrow]    = b0.w;
        Bs[(kb+0)*68 + lrow+32] = b1.x; Bs[(kb+1)*68 + lrow+32] = b1.y;
        Bs[(kb+2)*68 + lrow+32] = b1.z; Bs[(kb+3)*68 + lrow+32] = b1.w;
        __syncthreads();
        #pragma unroll
        for (int kk = 0; kk < 32; ++kk) {
            float4 av = *reinterpret_cast<const float4*>(As + kk*68 + tm);
            float4 bv = *reinterpret_cast<const float4*>(Bs + kk*68 + tn);
            acc[0][0] += av.x*bv.x; acc[0][1] += av.x*bv.y; acc[0][2] += av.x*bv.z; acc[0][3] += av.x*bv.w;
            acc[1][0] += av.y*bv.x; acc[1][1] += av.y*bv.y; acc[1][2] += av.y*bv.z; acc[1][3] += av.y*bv.w;
            acc[2][0] += av.z*bv.x; acc[2][1] += av.z*bv.y; acc[2][2] += av.z*bv.z; acc[2][3] += av.z*bv.w;
            acc[3][0] += av.w*bv.x; acc[3][1] += av.w*bv.y; acc[3][2] += av.w*bv.z; acc[3][3] += av.w*bv.w;
        }
    }

    #pragma unroll
    for (int i = 0; i < 4; ++i) {
        float r0 = acc[i][0], r1 = acc[i][1], r2 = acc[i][2], r3 = acc[i][3];
        if (bp) { r0 += bp[n0+tn+0]; r1 += bp[n0+tn+1]; r2 += bp[n0+tn+2]; r3 += bp[n0+tn+3]; }
        if (act) { r0 = ftanh(r0); r1 = ftanh(r1); r2 = ftanh(r2); r3 = ftanh(r3); }
        float4 v = make_float4(r0, r1, r2, r3);
        *reinterpret_cast<float4*>(C + (size_t)(m0+tm+i)*ldc + (n0+tn)) = v;
    }
}

__global__ __launch_bounds__(256) void gemm_skinny(
    const float* A0, const float* B0, const float* bias0, float* C0,
    const float* A1, const float* B1, const float* bias1, float* C1,
    int N, int K, int ldc)
{
    const float* A  = blockIdx.z ? A1 : A0;
    const float* B  = blockIdx.z ? B1 : B0;
    const float* bp = blockIdx.z ? bias1 : bias0;
    float*       C  = blockIdx.z ? C1 : C0;

    __shared__ float As[16*64];
    const int n0 = blockIdx.x * 64;
    const int m0 = blockIdx.y * 16;
    const int t  = threadIdx.x;
    const int n  = t & 63;
    const int mb = t >> 6;

    float acc[4] = {};

    for (int k0 = 0; k0 < K; k0 += 64) {
        __syncthreads();
        const int row = t >> 4, c4 = t & 15;
        *reinterpret_cast<float4*>(As + row*64 + c4*4) =
            *reinterpret_cast<const float4*>(A + (size_t)(m0+row)*K + k0 + c4*4);
        __syncthreads();
        const float* Bp = B + (size_t)(n0+n)*K + k0;
        #pragma unroll
        for (int q = 0; q < 16; ++q) {
            float4 bv = *reinterpret_cast<const float4*>(Bp + q*4);
            #pragma unroll
            for (int mm = 0; mm < 4; ++mm) {
                float4 av = *reinterpret_cast<const float4*>(As + (mb + 4*mm)*64 + q*4);
                acc[mm] += av.x*bv.x + av.y*bv.y + av.z*bv.z + av.w*bv.w;
            }
        }
    }
    const float bz = bp ? bp[n0+n] : 0.0f;
    #pragma unroll
    for (int mm = 0; mm < 4; ++mm)
        C[(size_t)(m0 + mb + 4*mm)*ldc + n0 + n] = acc[mm] + bz;
}

__global__ __launch_bounds__(256) void skinny_gate_k(
    const float* giA, const float* ghA, const float* hA,
    float* hnew, unsigned short* ahi, unsigned short* alo,
    const float* B0, const float* bias0, float* C0,
    const float* A1, const float* B1, const float* bias1, float* C1,
    int N, int ldc)
{
    __shared__ float Af[16*768];
    const int t  = threadIdx.x;
    const int m0 = blockIdx.y * 16;
    const int n0 = blockIdx.x * 64;

    if (blockIdx.z == 0) {
        for (int i = t; i < 16*768; i += 256) {
            int r = i / 768, j = i - r*768;
            int brow = m0 + r;
            float h = hA[(size_t)brow*768 + j];
            float v = gru_fuse(giA[(size_t)brow*2304 + j],
                               giA[(size_t)brow*2304 + j + 768],
                               giA[(size_t)brow*2304 + j + 1536],
                               ghA[(size_t)brow*2304 + j],
                               ghA[(size_t)brow*2304 + j + 768],
                               ghA[(size_t)brow*2304 + j + 1536], h);
            Af[i] = v;
            if (blockIdx.x == 0) {
                hnew[(size_t)brow*768 + j] = v;
                if (ahi) {
                    unsigned short hh = f2bf(v);
                    ahi[(size_t)brow*768 + j] = hh;
                    alo[(size_t)brow*768 + j] = f2bf(v - bf2f(hh));
                }
            }
        }
    } else {
        for (int i = t; i < 16*768; i += 256) {
            int r = i / 768, j = i - r*768;
            Af[i] = A1[(size_t)(m0 + r)*768 + j];
        }
    }
    __syncthreads();

    const float* B  = blockIdx.z ? B1 : B0;
    const float* bp = blockIdx.z ? bias1 : bias0;
    float*       C  = blockIdx.z ? C1 : C0;

    const int n  = t & 63;
    const int mb = t >> 6;
    const float* Bp = B + (size_t)(n0 + n)*768;
    float acc[4] = {};
    #pragma unroll 4
    for (int q = 0; q < 192; ++q) {
        float4 bv = *reinterpret_cast<const float4*>(Bp + q*4);
        #pragma unroll
        for (int mm = 0; mm < 4; ++mm) {
            float4 av = *reinterpret_cast<const float4*>(Af + (mb + 4*mm)*768 + q*4);
            acc[mm] += av.x*bv.x + av.y*bv.y + av.z*bv.z + av.w*bv.w;
        }
    }
    const float bz = bp ? bp[n0+n] : 0.0f;
    #pragma unroll
    for (int mm = 0; mm < 4; ++mm)
        C[(size_t)(m0 + mb + 4*mm)*ldc + n0 + n] = acc[mm] + bz;
}

// ===========================================================================
// misc small kernels
// ===========================================================================
__global__ __launch_bounds__(256) void embed_k(const int* inp, const float* emb, float* x)
{
    int i = blockIdx.x*256 + threadIdx.x;
    if (i >= 4096*128) return;
    int row = i >> 7, c4 = i & 127;
    int tok = inp[row];
    *reinterpret_cast<float4*>(x + (size_t)row*512 + c4*4) =
        *reinterpret_cast<const float4*>(emb + (size_t)tok*512 + c4*4);
}

__global__ __launch_bounds__(256) void transpose_k(const float* W1, float* W1T)
{
    int i = blockIdx.x*256 + threadIdx.x;
    if (i >= 512*768) return;
    int n = i / 512, k = i % 512;
    W1T[i] = W1[(size_t)k*768 + n];
}

__global__ __launch_bounds__(256) void gru_gate_k(
    const float* gi, const float* gh, const float* hold, float* hnew)
{
    int idx = blockIdx.x*256 + threadIdx.x;
    if (idx >= 64*768) return;
    int b = idx / 768, j = idx % 768;
    const float* gib = gi + (size_t)b*2304;
    const float* ghb = gh + (size_t)b*2304;
    float r = fsig(gib[j]        + ghb[j]);
    float z = fsig(gib[j + 768]  + ghb[j + 768]);
    float n = ftanh(gib[j + 1536] + r*ghb[j + 1536]);
    hnew[idx] = (1.0f - z)*n + z*hold[idx];
}

// ---------------------------------------------------------------------------
// Persistent encoder layer: one block per (b, dir), loops all 64 steps.
// ---------------------------------------------------------------------------
__global__ __launch_bounds__(256) void enc_layer_k(
    const float* giF, const float* giB,
    const float* Whh, const float* bhh,
    float* yout, float* hfin)
{
    const int b = blockIdx.x, d = blockIdx.y, t = threadIdx.x;
    const float* gi_base = d ? giB : giF;
    const float* W = Whh + (size_t)d*768*256;
    const float br  = bhh[d*768 + t];
    const float bz2 = bhh[d*768 + t + 256];
    const float bn  = bhh[d*768 + t + 512];

    __shared__ float hs[256];
    hs[t] = 0.0f;
    __syncthreads();

    for (int step = 0; step < 64; ++step) {
        const int s = d ? (63 - step) : step;
        const float* gi = gi_base + (size_t)(s*64 + b)*768;
        const float gr = gi[t], gz = gi[t+256], gn = gi[t+512];
        float ar = 0.f, az = 0.f, an = 0.f;
        #pragma unroll 8
        for (int q = 0; q < 64; ++q) {
            float4 hv = *reinterpret_cast<const float4*>(hs + q*4);
            float4 wr = *reinterpret_cast<const float4*>(W + (size_t)(t      )*256 + q*4);
            float4 wz = *reinterpret_cast<const float4*>(W + (size_t)(t + 256)*256 + q*4);
            float4 wn = *reinterpret_cast<const float4*>(W + (size_t)(t + 512)*256 + q*4);
            ar += hv.x*wr.x + hv.y*wr.y + hv.z*wr.z + hv.w*wr.w;
            az += hv.x*wz.x + hv.y*wz.y + hv.z*wz.z + hv.w*wz.w;
            an += hv.x*wn.x + hv.y*wn.y + hv.z*wn.z + hv.w*wn.w;
        }
        float r  = fsig(gr + ar + br);
        float z  = fsig(gz + az + bz2);
        float n  = ftanh(gn + r*(an + bn));
        float hn2 = (1.0f - z)*n + z*hs[t];
        __syncthreads();
        hs[t] = hn2;
        yout[(size_t)(s*64 + b)*512 + d*256 + t] = hn2;
        __syncthreads();
    }
    hfin[(size_t)b*512 + d*256 + t] = hs[t];
}

// ---------------------------------------------------------------------------
// Fused attention: scores -> softmax -> context -> wgt_in (emb | Xa). grid 64.
// ---------------------------------------------------------------------------
__global__ __launch_bounds__(256) void att_fused_k(
    const float* __restrict__ w1e, const float* __restrict__ w2h,
    const float* __restrict__ Vp, const float* __restrict__ enc_out,
    const float* __restrict__ emb_dec, const int* __restrict__ y,
    int step, float* __restrict__ wgt_in)
{
    const int b = blockIdx.x, t = threadIdx.x;
    __shared__ float w2s[768];
    __shared__ float vps[768];
    __shared__ float aa[64];
    for (int i = t; i < 768; i += 256) { w2s[i] = w2h[(size_t)b*768 + i]; vps[i] = Vp[i]; }
    __syncthreads();
    const int wv = t >> 6, ln = t & 63;
    for (int ss = 0; ss < 16; ++ss) {
        const int s = wv*16 + ss;
        const float* wrow = w1e + (size_t)(s*64 + b)*768;
        float acc = 0.f;
        #pragma unroll
        for (int q = 0; q < 12; ++q) {
            int e = ln + q*64;
            acc += ftanh(wrow[e] + w2s[e]) * vps[e];
        }
        for (int off = 32; off; off >>= 1) acc += __shfl_down(acc, off);
        if (ln == 0) aa[s] = acc;
    }
    __syncthreads();
    if (t < 64) {
        float v = aa[t];
        float m = v;
        for (int off = 32; off; off >>= 1) m = fmaxf(m, __shfl_xor(m, off));
        float e = __expf(v - m);
        float ssum = e;
        for (int off = 32; off; off >>= 1) ssum += __shfl_xor(ssum, off);
        aa[t] = e / ssum;
    }
    __syncthreads();
    for (int e = t; e < 512; e += 256) {
        float acc = 0.f;
        #pragma unroll 8
        for (int s = 0; s < 64; ++s)
            acc += aa[s] * enc_out[(size_t)(s*64 + b)*512 + e];
        wgt_in[(size_t)b*1280 + 768 + e] = acc;
    }
    const int tok = (step == 0) ? 0 : y[(step-1)*64 + b];
    for (int e = t; e < 768; e += 256)
        wgt_in[(size_t)b*1280 + e] = emb_dec[(size_t)tok*768 + e];
}

// ---------------------------------------------------------------------------
// Fused copy-score + softmax + scatter. grid 64 x 256. Writes out row once.
// ---------------------------------------------------------------------------
__global__ __launch_bounds__(256) void smax2_k(
    const float* __restrict__ scratch, const float* __restrict__ scb,
    const float* __restrict__ h1, const int* __restrict__ y, float* __restrict__ out)
{
    const int b = blockIdx.x, t = threadIdx.x;
    __shared__ float hsh[768];
    __shared__ float cps[64];
    __shared__ float red[4];
    for (int i = t; i < 768; i += 256) hsh[i] = h1[(size_t)b*768 + i];
    __syncthreads();
    const int wv = t >> 6, ln = t & 63;
    for (int ss = 0; ss < 16; ++ss) {
        const int s = wv*16 + ss;
        const float* sp = scb + (size_t)(s*64 + b)*768;
        float acc = 0.f;
        #pragma unroll
        for (int q = 0; q < 12; ++q) { int e = ln + q*64; acc += sp[e]*hsh[e]; }
        for (int off = 32; off; off >>= 1) acc += __shfl_down(acc, off);
        if (ln == 0) cps[s] = ftanh(acc);
    }
    __syncthreads();

    const float* row = scratch + (size_t)b*VDIM;
    float m = -1e30f;
    for (int i = t; i < VDIM; i += 256) m = fmaxf(m, row[i]);
    for (int off = 32; off; off >>= 1) m = fmaxf(m, __shfl_xor(m, off));
    if (ln == 0) red[wv] = m;
    __syncthreads();
    const float bm = fmaxf(fmaxf(red[0], red[1]), fmaxf(red[2], red[3]));
    __syncthreads();

    float s = 0.f;
    for (int i = t; i < VDIM; i += 256) s += __expf(row[i] - bm);
    if (t < 64) s += __expf(cps[t] - bm);
    for (int off = 32; off; off >>= 1) s += __shfl_xor(s, off);
    if (ln == 0) red[wv] = s;
    __syncthreads();
    const float inv = 1.0f / (red[0] + red[1] + red[2] + red[3]);

    float* orow = out + (size_t)b*NCOL;
    for (int i = t; i < VDIM; i += 256) orow[i] = __expf(row[i] - bm) * inv;
    if (t >= 192) orow[VDIM + (t - 192)] = 0.0f;
    __syncthreads();
    if (t < 64) atomicAdd(&orow[y[t*64 + b]], __expf(cps[t] - bm) * inv);
}

// ===========================================================================
extern "C" void kernel_launch(void* const* d_in, const int* in_sizes, int n_in,
                              void* d_out, int out_size, void* d_ws, size_t ws_size,
                              hipStream_t stream)
{
    (void)in_sizes; (void)n_in; (void)out_size;
    const int*   inp       = (const int*)  d_in[0];
    const int*   y         = (const int*)  d_in[1];
    const float* emb_enc   = (const float*)d_in[2];
    const float* enc_Wih   = (const float*)d_in[3];
    const float* enc_Whh   = (const float*)d_in[4];
    const float* enc_bih   = (const float*)d_in[5];
    const float* enc_bhh   = (const float*)d_in[6];
    const float* out_enc_W = (const float*)d_in[7];
    const float* emb_dec   = (const float*)d_in[8];
    const float* dec_Wih   = (const float*)d_in[9];
    const float* dec_Whh   = (const float*)d_in[10];
    const float* dec_bih   = (const float*)d_in[11];
    const float* dec_bhh   = (const float*)d_in[12];
    const float* out_b     = (const float*)d_in[13];
    const float* W1        = (const float*)d_in[14];
    const float* l2_W      = (const float*)d_in[15];
    const float* l2_b      = (const float*)d_in[16];
    const float* l3_W      = (const float*)d_in[17];
    const float* l3_b      = (const float*)d_in[18];
    const float* Vp        = (const float*)d_in[19];
    float* out = (float*)d_out;
    float* ws  = (float*)d_ws;

    size_t off = 0;
    auto alloc = [&](size_t n) { float* p = ws + off; off += (n + 63) & ~(size_t)63; return p; };
    // ---- fallback-safe base region (~89 MB, proven to fit in round 1) ----
    float* x0     = alloc(4096*512);
    float* x1     = alloc(4096*512);
    float* x2     = alloc(4096*512);   // enc_out
    float* giF    = alloc(4096*768);
    float* giB    = alloc(4096*768);
    float* w1e    = alloc(4096*768);
    float* scb    = alloc(4096*768);
    float* W1T    = alloc(768*512);
    float* hfin   = alloc(128*512);
    float* hdecA  = alloc(128*768);
    float* hdecB  = alloc(128*768);
    float* w2h    = alloc(64*768);
    float* wgt_in = alloc(64*1280);
    float* wgt    = alloc(64*768);
    float* gi0    = alloc(64*2304);
    float* gh0    = alloc(64*2304);
    float* gi1    = alloc(64*2304);
    float* gh1    = alloc(64*2304);
    float* scratch= alloc(64*VDIM);
    // ---- fp16 region (ushorts packed into float units) ----
    auto ualloc = [&](size_t nush) { return (unsigned short*)alloc((nush + 1) / 2); };
    unsigned short* embH    = ualloc((size_t)VDIM*768);          // fp16 single
    unsigned short* encWihH = ualloc(2*2*768*512);
    unsigned short* encWihL = ualloc(2*2*768*512);
    unsigned short* W1TH    = ualloc(768*512);
    unsigned short* W1TL    = ualloc(768*512);
    unsigned short* oeH     = ualloc(768*512);
    unsigned short* oeL     = ualloc(768*512);
    unsigned short* l2H     = ualloc(768*768);
    unsigned short* l2L     = ualloc(768*768);
    unsigned short* l3H     = ualloc(768*1280);
    unsigned short* l3L     = ualloc(768*1280);
    unsigned short* dWihH   = ualloc((size_t)2*2304*768);
    unsigned short* dWihL   = ualloc((size_t)2*2304*768);
    unsigned short* dWhhH   = ualloc((size_t)2*2304*768);
    unsigned short* dWhhL   = ualloc((size_t)2*2304*768);
    const bool use_mfma = ws_size >= off * sizeof(float);

    const size_t L1W = (size_t)2304*768;   // decoder layer-1 weight offset

    // ---- common setup ----
    embed_k<<<2048, 256, 0, stream>>>(inp, emb_enc, x0);
    transpose_k<<<(512*768 + 255)/256, 256, 0, stream>>>(W1, W1T);

    if (use_mfma) {
        convhl_k<<<1536, 256, 0, stream>>>(enc_Wih, encWihH, encWihL, 2*2*768*512/4);
        convhl_k<<<384, 256, 0, stream>>>(W1T, W1TH, W1TL, 768*512/4);
        convhl_k<<<384, 256, 0, stream>>>(out_enc_W, oeH, oeL, 768*512/4);
        convhl_k<<<576, 256, 0, stream>>>(l2_W, l2H, l2L, 768*768/4);
        convhl_k<<<960, 256, 0, stream>>>(l3_W, l3H, l3L, 768*1280/4);
        convhl_k<<<3456, 256, 0, stream>>>(dec_Wih, dWihH, dWihL, (int)(L1W*2/4));
        convhl_k<<<3456, 256, 0, stream>>>(dec_Whh, dWhhH, dWhhL, (int)(L1W*2/4));
        conv16_k<<<24000, 256, 0, stream>>>(emb_dec, embH, (int)((size_t)VDIM*768/4));

        // ---- encoder ----
        for (int l = 0; l < 2; ++l) {
            const float* xin  = l ? x1 : x0;
            float*       xout = l ? x2 : x1;
            const size_t wo = (size_t)l*2*768*512;
            mfma_gemm<<<dim3(6, 64, 2), 256, 0, stream>>>(
                xin, encWihH + wo,           encWihL + wo,           enc_bih + l*2*768,       giF, 768, 768, 0,
                xin, encWihH + wo + 768*512, encWihL + wo + 768*512, enc_bih + l*2*768 + 768, giB, 768, 768, 0,
                512);
            enc_layer_k<<<dim3(64, 2), 256, 0, stream>>>(
                giF, giB, enc_Whh + (size_t)l*2*768*256, enc_bhh + (size_t)l*2*768,
                xout, hfin + (size_t)l*64*512);
        }

        // decoder initial hidden (128,512)@out_enc_W^T
        mfma_gemm<<<dim3(6, 2, 1), 256, 0, stream>>>(
            hfin, oeH, oeL, nullptr, hdecA, 768, 768, 0,
            nullptr, nullptr, nullptr, nullptr, nullptr, 0, 0, 0,
            512);

        // w1e = enc_out @ W1 ; sc_base = tanh(enc_out @ out_enc_W^T)
        mfma_gemm<<<dim3(6, 64, 2), 256, 0, stream>>>(
            x2, W1TH, W1TL, nullptr, w1e, 768, 768, 0,
            x2, oeH,  oeL,  nullptr, scb, 768, 768, 1,
            512);

        // bootstrap w2h from initial h1
        mfma_gemm<<<dim3(6, 1, 1), 256, 0, stream>>>(
            hdecA + 64*768, l2H, l2L, l2_b, w2h, 768, 768, 0,
            nullptr, nullptr, nullptr, nullptr, nullptr, 0, 0, 0,
            768);

        // ---- decoder ----
        for (int st = 0; st < TSL; ++st) {
            float* h0c = (st & 1) ? hdecB : hdecA;
            float* h0n = (st & 1) ? hdecA : hdecB;
            float* h1c = h0c + 64*768;
            float* h1n = h0n + 64*768;
            float* orow = out + (size_t)st*BSZ*NCOL;

            att_fused_k<<<64, 256, 0, stream>>>(w1e, w2h, Vp, x2, emb_dec, y, st, wgt_in);

            mfma_gemm<<<dim3(6, 1, 1), 256, 0, stream>>>(
                wgt_in, l3H, l3L, l3_b, wgt, 768, 768, 0,
                nullptr, nullptr, nullptr, nullptr, nullptr, 0, 0, 0,
                1280);

            mfma_gemm<<<dim3(18, 1, 2), 256, 0, stream>>>(
                wgt, dWihH, dWihL, dec_bih,        gi0, 2304, 2304, 0,
                h0c, dWhhH, dWhhL, dec_bhh,        gh0, 2304, 2304, 0,
                768);
            gru_gate_k<<<192, 256, 0, stream>>>(gi0, gh0, h0c, h0n);

            mfma_gemm<<<dim3(18, 1, 2), 256, 0, stream>>>(
                h0n, dWihH + L1W, dWihL + L1W, dec_bih + 2304, gi1, 2304, 2304, 0,
                h1c, dWhhH + L1W, dWhhL + L1W, dec_bhh + 2304, gh1, 2304, 2304, 0,
                768);
            gru_gate_k<<<192, 256, 0, stream>>>(gi1, gh1, h1c, h1n);

            // vocab logits -> scratch  +  w2h(next) = h1n @ l2_W^T
            mfma_gemm<<<dim3(250, 1, 2), 256, 0, stream>>>(
                h1n, embH, nullptr, out_b, scratch, VDIM, VDIM, 0,
                h1n, l2H,  l2L,    l2_b,  w2h,     768,  768,  0,
                768);

            smax2_k<<<64, 256, 0, stream>>>(scratch, scb, h1n, y, orow);
        }
    } else {
        // ================= fp32 fallback (round-2 flow) =================
        for (int l = 0; l < 2; ++l) {
            const float* xin  = l ? x1 : x0;
            float*       xout = l ? x2 : x1;
            const float* Wih = enc_Wih + (size_t)l*2*768*512;
            const float* Whh = enc_Whh + (size_t)l*2*768*256;
            const float* bih = enc_bih + (size_t)l*2*768;
            const float* bhh = enc_bhh + (size_t)l*2*768;
            gemm64<<<dim3(12, 64, 2), 256, 0, stream>>>(
                xin, Wih,           bih,       giF, 0,
                xin, Wih + 768*512, bih + 768, giB, 0,
                4096, 768, 512, 768);
            enc_layer_k<<<dim3(64, 2), 256, 0, stream>>>(
                giF, giB, Whh, bhh, xout, hfin + (size_t)l*64*512);
        }
        gemm64<<<dim3(12, 2, 1), 256, 0, stream>>>(
            hfin, out_enc_W, nullptr, hdecA, 0,
            hfin, out_enc_W, nullptr, hdecA, 0,
            128, 768, 512, 768);
        gemm64<<<dim3(12, 64, 2), 256, 0, stream>>>(
            x2, W1T,       nullptr, w1e, 0,
            x2, out_enc_W, nullptr, scb, 1,
            4096, 768, 512, 768);
        gemm_skinny<<<dim3(12, 4, 1), 256, 0, stream>>>(
            hdecA + 64*768, l2_W, l2_b, w2h,
            hdecA + 64*768, l2_W, l2_b, w2h,
            768, 768, 768);

        for (int st = 0; st < TSL; ++st) {
            float* h0c = (st & 1) ? hdecB : hdecA;
            float* h0n = (st & 1) ? hdecA : hdecB;
            float* h1c = h0c + 64*768;
            float* h1n = h0n + 64*768;
            float* orow = out + (size_t)st*BSZ*NCOL;

            att_fused_k<<<64, 256, 0, stream>>>(w1e, w2h, Vp, x2, emb_dec, y, st, wgt_in);
            gemm_skinny<<<dim3(12, 4, 1), 256, 0, stream>>>(
                wgt_in, l3_W, l3_b, wgt,
                wgt_in, l3_W, l3_b, wgt,
                768, 1280, 768);
            gemm_skinny<<<dim3(36, 4, 2), 256, 0, stream>>>(
                wgt, dec_Wih, dec_bih, gi0,
                h0c, dec_Whh, dec_bhh, gh0,
                2304, 768, 2304);
            skinny_gate_k<<<dim3(36, 4, 2), 256, 0, stream>>>(
                gi0, gh0, h0c, h0n, nullptr, nullptr,
                dec_Wih + L1W, dec_bih + 2304, gi1,
                h1c, dec_Whh + L1W, dec_bhh + 2304, gh1,
                2304, 2304);
            skinny_gate_k<<<dim3(12, 4, 1), 256, 0, stream>>>(
                gi1, gh1, h1c, h1n, nullptr, nullptr,
                l2_W, l2_b, w2h,
                nullptr, nullptr, nullptr, nullptr,
                768, 768);
            gemm64<<<dim3(500, 1, 1), 256, 0, stream>>>(
                h1n, emb_dec, out_b, scratch, 0,
                h1n, emb_dec, out_b, scratch, 0,
                64, VDIM, 768, VDIM);
            smax2_k<<<64, 256, 0, stream>>>(scratch, scb, h1n, y, orow);
        }
    }
}

// Round 4
// 13233.376 us; speedup vs baseline: 1.5629x; 1.0239x over previous
//
#include <hip/hip_runtime.h>

#define SLEN 64
#define BSZ  64
#define TSL  48
#define VDIM 32000
#define NCOL 32064   // VDIM + SLEN

typedef __attribute__((ext_vector_type(8))) _Float16 f16x8;
typedef __attribute__((ext_vector_type(4))) _Float16 f16x4;
typedef __attribute__((ext_vector_type(4))) float f32x4;

__device__ __forceinline__ float fsig(float x){
    return 1.0f/(1.0f + __expf(-x));
}
__device__ __forceinline__ float ftanh(float x){
    float e = __expf(2.0f*x);
    return 1.0f - 2.0f/(e + 1.0f);
}
__device__ __forceinline__ unsigned short f2h(float x){
    union { _Float16 f; unsigned short u; } c; c.f = (_Float16)x; return c.u;
}
__device__ __forceinline__ unsigned short f2h_hi(float x, float& rem){
    _Float16 h = (_Float16)x;
    rem = x - (float)h;
    union { _Float16 f; unsigned short u; } c; c.f = h; return c.u;
}
__device__ __forceinline__ float gru_fuse(float gir,float giz,float gin,
                                          float ghr,float ghz,float ghn,float h){
    float r = fsig(gir + ghr);
    float z = fsig(giz + ghz);
    float n = ftanh(gin + r*ghn);
    return (1.0f - z)*n + z*h;
}

// ===========================================================================
// MFMA GEMM (2 param sets): C = A @ B^T + bias, optional tanh.
// A fp32 (lda=K) -> fp16 hi/lo inline while staging LDS. B fp16 hi(+lo).
// grid = (ceil(maxN/128), M/64, nz). N%128==0 not required (tail blocks exit).
// ===========================================================================
__global__ __launch_bounds__(256) void mfma_gemm(
    const float* A0, const unsigned short* Bh0, const unsigned short* Bl0,
    const float* bias0, float* C0, int N0, int ldc0, int act0,
    const float* A1, const unsigned short* Bh1, const unsigned short* Bl1,
    const float* bias1, float* C1, int N1, int ldc1, int act1,
    int K)
{
    const float* A; const unsigned short* Bh; const unsigned short* Bl;
    const float* bias; float* C; int N, ldc, act;
    if (blockIdx.z == 0) { A=A0; Bh=Bh0; Bl=Bl0; bias=bias0; C=C0; N=N0; ldc=ldc0; act=act0; }
    else                 { A=A1; Bh=Bh1; Bl=Bl1; bias=bias1; C=C1; N=N1; ldc=ldc1; act=act1; }

    const int n0 = blockIdx.x * 128;
    if (n0 >= N) return;
    const int m0 = blockIdx.y * 64;

    __shared__ __align__(16) unsigned short As[2][64][72];
    __shared__ __align__(16) unsigned short Bs[2][128][72];

    const int t  = threadIdx.x;
    const int wv = t >> 6, ln = t & 63;
    const bool has_lo = (Bl != nullptr);

    f32x4 acc[4][2];
    #pragma unroll
    for (int i = 0; i < 4; ++i)
        #pragma unroll
        for (int j = 0; j < 2; ++j) acc[i][j] = (f32x4){0.f,0.f,0.f,0.f};

    for (int k0 = 0; k0 < K; k0 += 64) {
        __syncthreads();
        #pragma unroll
        for (int it = 0; it < 4; ++it) {
            int idx = t + it*256;
            int r = idx >> 4, c4 = (idx & 15) * 4;
            float4 v = *reinterpret_cast<const float4*>(A + (size_t)(m0+r)*K + k0 + c4);
            ushort4 h, l; float rm;
            h.x = f2h_hi(v.x, rm); l.x = f2h(rm);
            h.y = f2h_hi(v.y, rm); l.y = f2h(rm);
            h.z = f2h_hi(v.z, rm); l.z = f2h(rm);
            h.w = f2h_hi(v.w, rm); l.w = f2h(rm);
            *reinterpret_cast<ushort4*>(&As[0][r][c4]) = h;
            *reinterpret_cast<ushort4*>(&As[1][r][c4]) = l;
        }
        #pragma unroll
        for (int it = 0; it < 4; ++it) {
            int idx = t + it*256;
            int r = idx >> 3, c8 = (idx & 7) * 8;
            *reinterpret_cast<uint4*>(&Bs[0][r][c8]) =
                *reinterpret_cast<const uint4*>(&Bh[(size_t)(n0+r)*K + k0 + c8]);
        }
        if (has_lo) {
            #pragma unroll
            for (int it = 0; it < 4; ++it) {
                int idx = t + it*256;
                int r = idx >> 3, c8 = (idx & 7) * 8;
                *reinterpret_cast<uint4*>(&Bs[1][r][c8]) =
                    *reinterpret_cast<const uint4*>(&Bl[(size_t)(n0+r)*K + k0 + c8]);
            }
        }
        __syncthreads();
        #pragma unroll
        for (int ks = 0; ks < 2; ++ks) {
            const int ko = ks*32 + (ln >> 4)*8;
            f16x8 ah[4], al[4], bh[2], bl[2];
            #pragma unroll
            for (int m = 0; m < 4; ++m) {
                ah[m] = *reinterpret_cast<const f16x8*>(&As[0][m*16 + (ln&15)][ko]);
                al[m] = *reinterpret_cast<const f16x8*>(&As[1][m*16 + (ln&15)][ko]);
            }
            #pragma unroll
            for (int n = 0; n < 2; ++n) {
                bh[n] = *reinterpret_cast<const f16x8*>(&Bs[0][wv*32 + n*16 + (ln&15)][ko]);
                if (has_lo)
                    bl[n] = *reinterpret_cast<const f16x8*>(&Bs[1][wv*32 + n*16 + (ln&15)][ko]);
            }
            #pragma unroll
            for (int m = 0; m < 4; ++m)
                #pragma unroll
                for (int n = 0; n < 2; ++n) {
                    acc[m][n] = __builtin_amdgcn_mfma_f32_16x16x32_f16(ah[m], bh[n], acc[m][n], 0,0,0);
                    acc[m][n] = __builtin_amdgcn_mfma_f32_16x16x32_f16(al[m], bh[n], acc[m][n], 0,0,0);
                    if (has_lo)
                        acc[m][n] = __builtin_amdgcn_mfma_f32_16x16x32_f16(ah[m], bl[n], acc[m][n], 0,0,0);
                }
        }
    }
    #pragma unroll
    for (int m = 0; m < 4; ++m) {
        #pragma unroll
        for (int n = 0; n < 2; ++n) {
            const int col = n0 + wv*32 + n*16 + (ln & 15);
            const float bz = bias ? bias[col] : 0.0f;
            #pragma unroll
            for (int j = 0; j < 4; ++j) {
                const int row = m0 + m*16 + (ln >> 4)*4 + j;
                float v = acc[m][n][j] + bz;
                if (act) v = ftanh(v);
                C[(size_t)row*ldc + col] = v;
            }
        }
    }
}

// ===========================================================================
// MFMA GEMM, 3 param sets (decoder K4: vocab + w2h' + gh1'). M=64 fixed.
// ===========================================================================
__global__ __launch_bounds__(256) void mfma_gemm3(
    const float* A0, const unsigned short* Bh0, const unsigned short* Bl0,
    const float* bias0, float* C0, int N0, int ldc0,
    const float* A1, const unsigned short* Bh1, const unsigned short* Bl1,
    const float* bias1, float* C1, int N1, int ldc1,
    const float* A2, const unsigned short* Bh2, const unsigned short* Bl2,
    const float* bias2, float* C2, int N2, int ldc2,
    int K)
{
    const float* A; const unsigned short* Bh; const unsigned short* Bl;
    const float* bias; float* C; int N, ldc;
    if (blockIdx.z == 0)      { A=A0; Bh=Bh0; Bl=Bl0; bias=bias0; C=C0; N=N0; ldc=ldc0; }
    else if (blockIdx.z == 1) { A=A1; Bh=Bh1; Bl=Bl1; bias=bias1; C=C1; N=N1; ldc=ldc1; }
    else                      { A=A2; Bh=Bh2; Bl=Bl2; bias=bias2; C=C2; N=N2; ldc=ldc2; }

    const int n0 = blockIdx.x * 128;
    if (n0 >= N) return;

    __shared__ __align__(16) unsigned short As[2][64][72];
    __shared__ __align__(16) unsigned short Bs[2][128][72];

    const int t  = threadIdx.x;
    const int wv = t >> 6, ln = t & 63;
    const bool has_lo = (Bl != nullptr);

    f32x4 acc[4][2];
    #pragma unroll
    for (int i = 0; i < 4; ++i)
        #pragma unroll
        for (int j = 0; j < 2; ++j) acc[i][j] = (f32x4){0.f,0.f,0.f,0.f};

    for (int k0 = 0; k0 < K; k0 += 64) {
        __syncthreads();
        #pragma unroll
        for (int it = 0; it < 4; ++it) {
            int idx = t + it*256;
            int r = idx >> 4, c4 = (idx & 15) * 4;
            float4 v = *reinterpret_cast<const float4*>(A + (size_t)r*K + k0 + c4);
            ushort4 h, l; float rm;
            h.x = f2h_hi(v.x, rm); l.x = f2h(rm);
            h.y = f2h_hi(v.y, rm); l.y = f2h(rm);
            h.z = f2h_hi(v.z, rm); l.z = f2h(rm);
            h.w = f2h_hi(v.w, rm); l.w = f2h(rm);
            *reinterpret_cast<ushort4*>(&As[0][r][c4]) = h;
            *reinterpret_cast<ushort4*>(&As[1][r][c4]) = l;
        }
        #pragma unroll
        for (int it = 0; it < 4; ++it) {
            int idx = t + it*256;
            int r = idx >> 3, c8 = (idx & 7) * 8;
            *reinterpret_cast<uint4*>(&Bs[0][r][c8]) =
                *reinterpret_cast<const uint4*>(&Bh[(size_t)(n0+r)*K + k0 + c8]);
        }
        if (has_lo) {
            #pragma unroll
            for (int it = 0; it < 4; ++it) {
                int idx = t + it*256;
                int r = idx >> 3, c8 = (idx & 7) * 8;
                *reinterpret_cast<uint4*>(&Bs[1][r][c8]) =
                    *reinterpret_cast<const uint4*>(&Bl[(size_t)(n0+r)*K + k0 + c8]);
            }
        }
        __syncthreads();
        #pragma unroll
        for (int ks = 0; ks < 2; ++ks) {
            const int ko = ks*32 + (ln >> 4)*8;
            f16x8 ah[4], al[4], bh[2], bl[2];
            #pragma unroll
            for (int m = 0; m < 4; ++m) {
                ah[m] = *reinterpret_cast<const f16x8*>(&As[0][m*16 + (ln&15)][ko]);
                al[m] = *reinterpret_cast<const f16x8*>(&As[1][m*16 + (ln&15)][ko]);
            }
            #pragma unroll
            for (int n = 0; n < 2; ++n) {
                bh[n] = *reinterpret_cast<const f16x8*>(&Bs[0][wv*32 + n*16 + (ln&15)][ko]);
                if (has_lo)
                    bl[n] = *reinterpret_cast<const f16x8*>(&Bs[1][wv*32 + n*16 + (ln&15)][ko]);
            }
            #pragma unroll
            for (int m = 0; m < 4; ++m)
                #pragma unroll
                for (int n = 0; n < 2; ++n) {
                    acc[m][n] = __builtin_amdgcn_mfma_f32_16x16x32_f16(ah[m], bh[n], acc[m][n], 0,0,0);
                    acc[m][n] = __builtin_amdgcn_mfma_f32_16x16x32_f16(al[m], bh[n], acc[m][n], 0,0,0);
                    if (has_lo)
                        acc[m][n] = __builtin_amdgcn_mfma_f32_16x16x32_f16(al[m], bl[n], acc[m][n], 0,0,0);
                }
        }
    }
    #pragma unroll
    for (int m = 0; m < 4; ++m) {
        #pragma unroll
        for (int n = 0; n < 2; ++n) {
            const int col = n0 + wv*32 + n*16 + (ln & 15);
            const float bz = bias ? bias[col] : 0.0f;
            #pragma unroll
            for (int j = 0; j < 4; ++j) {
                const int row = m*16 + (ln >> 4)*4 + j;
                C[(size_t)row*ldc + col] = acc[m][n][j] + bz;
            }
        }
    }
}

// ===========================================================================
// Barrier-free MFMA GRU-GEMM. M=64 (rows split over 4 waves), per block one
// 16-col strip of each of the 3 gates. A fp32 -> fp16 hi/lo in registers,
// B fp16 hi(+lo) direct global->reg. gate=1: fused GRU update -> hnew(64x768).
// gate=0: plain write C[row*2304 + g*768 + col] + bias. grid (48, 1, nz).
// ===========================================================================
__global__ __launch_bounds__(256) void gru_mfma_k(
    const float* A0, const unsigned short* BH0, const unsigned short* BL0,
    const float* bias0, const float* gh0, const float* hold0, float* out0,
    int gate0, int K0,
    const float* A1, const unsigned short* BH1, const unsigned short* BL1,
    const float* bias1, const float* gh1, const float* hold1, float* out1,
    int gate1, int K1)
{
    const float* A; const unsigned short* BH; const unsigned short* BL;
    const float* bias; const float* gh; const float* hold; float* outp; int gate, K;
    if (blockIdx.z == 0) { A=A0; BH=BH0; BL=BL0; bias=bias0; gh=gh0; hold=hold0; outp=out0; gate=gate0; K=K0; }
    else                 { A=A1; BH=BH1; BL=BL1; bias=bias1; gh=gh1; hold=hold1; outp=out1; gate=gate1; K=K1; }

    const int t = threadIdx.x;
    const int wv = t >> 6, ln = t & 63;
    const int colg16 = blockIdx.x * 16;          // strip base within each gate
    const int arow = wv*16 + (ln & 15);
    const int kof  = (ln >> 4) * 8;
    const bool has_lo = (BL != nullptr);

    f32x4 acc[3];
    #pragma unroll
    for (int g = 0; g < 3; ++g) acc[g] = (f32x4){0.f,0.f,0.f,0.f};

    const float* Ar = A + (size_t)arow*K + kof;
    const int brow_n = colg16 + (ln & 15);

    #pragma unroll 2
    for (int k0 = 0; k0 < K; k0 += 32) {
        float4 a0 = *reinterpret_cast<const float4*>(Ar + k0);
        float4 a1 = *reinterpret_cast<const float4*>(Ar + k0 + 4);
        f16x8 ah, al;
        {
            float av0=a0.x, av1=a0.y, av2=a0.z, av3=a0.w;
            float av4=a1.x, av5=a1.y, av6=a1.z, av7=a1.w;
            _Float16 hh;
            hh=(_Float16)av0; ah[0]=hh; al[0]=(_Float16)(av0-(float)hh);
            hh=(_Float16)av1; ah[1]=hh; al[1]=(_Float16)(av1-(float)hh);
            hh=(_Float16)av2; ah[2]=hh; al[2]=(_Float16)(av2-(float)hh);
            hh=(_Float16)av3; ah[3]=hh; al[3]=(_Float16)(av3-(float)hh);
            hh=(_Float16)av4; ah[4]=hh; al[4]=(_Float16)(av4-(float)hh);
            hh=(_Float16)av5; ah[5]=hh; al[5]=(_Float16)(av5-(float)hh);
            hh=(_Float16)av6; ah[6]=hh; al[6]=(_Float16)(av6-(float)hh);
            hh=(_Float16)av7; ah[7]=hh; al[7]=(_Float16)(av7-(float)hh);
        }
        #pragma unroll
        for (int g = 0; g < 3; ++g) {
            const size_t boff = (size_t)(g*768 + brow_n)*K + k0 + kof;
            f16x8 bh = *reinterpret_cast<const f16x8*>(&BH[boff]);
            acc[g] = __builtin_amdgcn_mfma_f32_16x16x32_f16(ah, bh, acc[g], 0,0,0);
            acc[g] = __builtin_amdgcn_mfma_f32_16x16x32_f16(al, bh, acc[g], 0,0,0);
            if (has_lo) {
                f16x8 bl = *reinterpret_cast<const f16x8*>(&BL[boff]);
                acc[g] = __builtin_amdgcn_mfma_f32_16x16x32_f16(ah, bl, acc[g], 0,0,0);
            }
        }
    }

    const int colg = colg16 + (ln & 15);
    const int rb   = wv*16 + (ln >> 4)*4;
    if (gate) {
        const float br = bias[colg], bz = bias[768+colg], bn = bias[1536+colg];
        #pragma unroll
        for (int jj = 0; jj < 4; ++jj) {
            const int row = rb + jj;
            float ghr = gh[(size_t)row*2304 + colg];
            float ghz = gh[(size_t)row*2304 + 768 + colg];
            float ghn = gh[(size_t)row*2304 + 1536 + colg];
            float h   = hold[(size_t)row*768 + colg];
            outp[(size_t)row*768 + colg] =
                gru_fuse(acc[0][jj]+br, acc[1][jj]+bz, acc[2][jj]+bn, ghr, ghz, ghn, h);
        }
    } else {
        #pragma unroll
        for (int g = 0; g < 3; ++g) {
            const float bz = bias[g*768 + colg];
            #pragma unroll
            for (int jj = 0; jj < 4; ++jj)
                outp[(size_t)(rb+jj)*2304 + g*768 + colg] = acc[g][jj] + bz;
        }
    }
}

// ===========================================================================
// conversions / transposes / small setup kernels
// ===========================================================================
__global__ __launch_bounds__(256) void convhl_k(
    const float* __restrict__ W, unsigned short* __restrict__ hi,
    unsigned short* __restrict__ lo, int n4)
{
    int i = blockIdx.x*256 + threadIdx.x;
    if (i >= n4) return;
    float4 v = reinterpret_cast<const float4*>(W)[i];
    ushort4 h, l; float r;
    h.x = f2h_hi(v.x, r); l.x = f2h(r);
    h.y = f2h_hi(v.y, r); l.y = f2h(r);
    h.z = f2h_hi(v.z, r); l.z = f2h(r);
    h.w = f2h_hi(v.w, r); l.w = f2h(r);
    reinterpret_cast<ushort4*>(hi)[i] = h;
    reinterpret_cast<ushort4*>(lo)[i] = l;
}
__global__ __launch_bounds__(256) void conv16_k(
    const float* __restrict__ W, unsigned short* __restrict__ hi, int n4)
{
    int i = blockIdx.x*256 + threadIdx.x;
    if (i >= n4) return;
    float4 v = reinterpret_cast<const float4*>(W)[i];
    ushort4 h;
    h.x = f2h(v.x); h.y = f2h(v.y); h.z = f2h(v.z); h.w = f2h(v.w);
    reinterpret_cast<ushort4*>(hi)[i] = h;
}
// D[c*R + r] = S[r*C + c]
__global__ __launch_bounds__(256) void transpose2_k(
    const float* __restrict__ S, float* __restrict__ D, int R, int C)
{
    int i = blockIdx.x*256 + threadIdx.x;
    if (i >= R*C) return;
    int r = i / C, c = i - r*C;
    D[(size_t)c*R + r] = S[i];
}
// b03[j] = dec_bih0[j] + sum_m Wih0[j][m] * l3_b[m]
__global__ __launch_bounds__(256) void b03_k(
    const float* __restrict__ Wih0, const float* __restrict__ bih0,
    const float* __restrict__ l3b, float* __restrict__ b03)
{
    int j = blockIdx.x*256 + threadIdx.x;
    if (j >= 2304) return;
    const float* wr = Wih0 + (size_t)j*768;
    float s = 0.f;
    #pragma unroll 4
    for (int m = 0; m < 768; m += 4) {
        float4 w = *reinterpret_cast<const float4*>(wr + m);
        float4 b = *reinterpret_cast<const float4*>(l3b + m);
        s += w.x*b.x + w.y*b.y + w.z*b.z + w.w*b.w;
    }
    b03[j] = bih0[j] + s;
}

__global__ __launch_bounds__(256) void embed_k(const int* inp, const float* emb, float* x)
{
    int i = blockIdx.x*256 + threadIdx.x;
    if (i >= 4096*128) return;
    int row = i >> 7, c4 = i & 127;
    int tok = inp[row];
    *reinterpret_cast<float4*>(x + (size_t)row*512 + c4*4) =
        *reinterpret_cast<const float4*>(emb + (size_t)tok*512 + c4*4);
}

// ---------------------------------------------------------------------------
// Persistent encoder layer, fp16 Whh. permute=1 writes yout[(b*64+s)...].
// ---------------------------------------------------------------------------
__global__ __launch_bounds__(256) void enc_layer_k(
    const float* giF, const float* giB,
    const unsigned short* Whh16, const float* bhh,
    float* yout, float* hfin, int permute)
{
    const int b = blockIdx.x, d = blockIdx.y, t = threadIdx.x;
    const float* gi_base = d ? giB : giF;
    const unsigned short* W = Whh16 + (size_t)d*768*256;
    const float br  = bhh[d*768 + t];
    const float bz2 = bhh[d*768 + t + 256];
    const float bn  = bhh[d*768 + t + 512];

    __shared__ float hs[256];
    hs[t] = 0.0f;
    __syncthreads();

    for (int step = 0; step < 64; ++step) {
        const int s = d ? (63 - step) : step;
        const float* gi = gi_base + (size_t)(s*64 + b)*768;
        const float gr = gi[t], gz = gi[t+256], gn = gi[t+512];
        float ar = 0.f, az = 0.f, an = 0.f;
        #pragma unroll 8
        for (int q = 0; q < 64; ++q) {
            float4 hv = *reinterpret_cast<const float4*>(hs + q*4);
            f16x4 wr = *reinterpret_cast<const f16x4*>(&W[(size_t)(t      )*256 + q*4]);
            f16x4 wz = *reinterpret_cast<const f16x4*>(&W[(size_t)(t + 256)*256 + q*4]);
            f16x4 wn = *reinterpret_cast<const f16x4*>(&W[(size_t)(t + 512)*256 + q*4]);
            ar += hv.x*(float)wr[0] + hv.y*(float)wr[1] + hv.z*(float)wr[2] + hv.w*(float)wr[3];
            az += hv.x*(float)wz[0] + hv.y*(float)wz[1] + hv.z*(float)wz[2] + hv.w*(float)wz[3];
            an += hv.x*(float)wn[0] + hv.y*(float)wn[1] + hv.z*(float)wn[2] + hv.w*(float)wn[3];
        }
        float r  = fsig(gr + ar + br);
        float z  = fsig(gz + az + bz2);
        float n  = ftanh(gn + r*(an + bn));
        float hn2 = (1.0f - z)*n + z*hs[t];
        __syncthreads();
        hs[t] = hn2;
        const int idx = permute ? (b*64 + s) : (s*64 + b);
        yout[(size_t)idx*512 + d*256 + t] = hn2;
        __syncthreads();
    }
    hfin[(size_t)b*512 + d*256 + t] = hs[t];
}

// ---------------------------------------------------------------------------
// Fused attention (permuted layouts: w1e/enc_out rows = b*64+s). grid 64.
// ---------------------------------------------------------------------------
__global__ __launch_bounds__(256) void att_fused_k(
    const float* __restrict__ w1e, const float* __restrict__ w2h,
    const float* __restrict__ Vp, const float* __restrict__ enc_out,
    const float* __restrict__ emb_dec, const int* __restrict__ y,
    int step, float* __restrict__ wgt_in)
{
    const int b = blockIdx.x, t = threadIdx.x;
    __shared__ float w2s[768];
    __shared__ float vps[768];
    __shared__ float aa[64];
    for (int i = t; i < 768; i += 256) { w2s[i] = w2h[(size_t)b*768 + i]; vps[i] = Vp[i]; }
    __syncthreads();
    const int wv = t >> 6, ln = t & 63;
    for (int ss = 0; ss < 16; ++ss) {
        const int s = wv*16 + ss;
        const float* wrow = w1e + (size_t)(b*64 + s)*768;
        float acc = 0.f;
        #pragma unroll
        for (int q = 0; q < 12; ++q) {
            int e = ln + q*64;
            acc += ftanh(wrow[e] + w2s[e]) * vps[e];
        }
        for (int off = 32; off; off >>= 1) acc += __shfl_down(acc, off);
        if (ln == 0) aa[s] = acc;
    }
    __syncthreads();
    if (t < 64) {
        float v = aa[t];
        float m = v;
        for (int off = 32; off; off >>= 1) m = fmaxf(m, __shfl_xor(m, off));
        float e = __expf(v - m);
        float ssum = e;
        for (int off = 32; off; off >>= 1) ssum += __shfl_xor(ssum, off);
        aa[t] = e / ssum;
    }
    __syncthreads();
    for (int e = t; e < 512; e += 256) {
        float acc = 0.f;
        #pragma unroll 8
        for (int s = 0; s < 64; ++s)
            acc += aa[s] * enc_out[(size_t)(b*64 + s)*512 + e];
        wgt_in[(size_t)b*1280 + 768 + e] = acc;
    }
    const int tok = (step == 0) ? 0 : y[(step-1)*64 + b];
    for (int e = t; e < 768; e += 256)
        wgt_in[(size_t)b*1280 + e] = emb_dec[(size_t)tok*768 + e];
}

// ---------------------------------------------------------------------------
// Fused copy-score + softmax + scatter (permuted scb rows b*64+s). grid 64.
// ---------------------------------------------------------------------------
__global__ __launch_bounds__(256) void smax2_k(
    const float* __restrict__ scratch, const float* __restrict__ scb,
    const float* __restrict__ h1, const int* __restrict__ y, float* __restrict__ out)
{
    const int b = blockIdx.x, t = threadIdx.x;
    __shared__ float hsh[768];
    __shared__ float cps[64];
    __shared__ float red[4];
    for (int i = t; i < 768; i += 256) hsh[i] = h1[(size_t)b*768 + i];
    __syncthreads();
    const int wv = t >> 6, ln = t & 63;
    for (int ss = 0; ss < 16; ++ss) {
        const int s = wv*16 + ss;
        const float* sp = scb + (size_t)(b*64 + s)*768;
        float acc = 0.f;
        #pragma unroll
        for (int q = 0; q < 12; ++q) { int e = ln + q*64; acc += sp[e]*hsh[e]; }
        for (int off = 32; off; off >>= 1) acc += __shfl_down(acc, off);
        if (ln == 0) cps[s] = ftanh(acc);
    }
    __syncthreads();

    const float* row = scratch + (size_t)b*VDIM;
    float m = -1e30f;
    for (int i = t; i < VDIM; i += 256) m = fmaxf(m, row[i]);
    for (int off = 32; off; off >>= 1) m = fmaxf(m, __shfl_xor(m, off));
    if (ln == 0) red[wv] = m;
    __syncthreads();
    const float bm = fmaxf(fmaxf(red[0], red[1]), fmaxf(red[2], red[3]));
    __syncthreads();

    float s = 0.f;
    for (int i = t; i < VDIM; i += 256) s += __expf(row[i] - bm);
    if (t < 64) s += __expf(cps[t] - bm);
    for (int off = 32; off; off >>= 1) s += __shfl_xor(s, off);
    if (ln == 0) red[wv] = s;
    __syncthreads();
    const float inv = 1.0f / (red[0] + red[1] + red[2] + red[3]);

    float* orow = out + (size_t)b*NCOL;
    for (int i = t; i < VDIM; i += 256) orow[i] = __expf(row[i] - bm) * inv;
    if (t >= 192) orow[VDIM + (t - 192)] = 0.0f;
    __syncthreads();
    if (t < 64) atomicAdd(&orow[y[t*64 + b]], __expf(cps[t] - bm) * inv);
}

// ===========================================================================
// fp32 fallback kernels (only if ws too small for fp16 path)
// ===========================================================================
__global__ __launch_bounds__(256) void gemm64(
    const float* A0, const float* B0, const float* bias0, float* C0, int act0,
    const float* A1, const float* B1, const float* bias1, float* C1, int act1,
    int M, int N, int K, int ldc)
{
    const float* A  = blockIdx.z ? A1 : A0;
    const float* B  = blockIdx.z ? B1 : B0;
    const float* bp = blockIdx.z ? bias1 : bias0;
    float*       C  = blockIdx.z ? C1 : C0;
    const int act   = blockIdx.z ? act1 : act0;

    __shared__ float As[32*68];
    __shared__ float Bs[32*68];

    const int n0 = blockIdx.x * 64;
    const int m0 = blockIdx.y * 64;
    const int t  = threadIdx.x;
    const int lrow = t >> 3;
    const int lc4  = t & 7;
    const int tm = (t >> 4) << 2;
    const int tn = (t & 15) << 2;

    float acc[4][4] = {};

    for (int k0 = 0; k0 < K; k0 += 32) {
        float4 a0 = *reinterpret_cast<const float4*>(A + (size_t)(m0+lrow   )*K + k0 + lc4*4);
        float4 a1 = *reinterpret_cast<const float4*>(A + (size_t)(m0+lrow+32)*K + k0 + lc4*4);
        float4 b0 = *reinterpret_cast<const float4*>(B + (size_t)(n0+lrow   )*K + k0 + lc4*4);
        float4 b1 = *reinterpret_cast<const float4*>(B + (size_t)(n0+lrow+32)*K + k0 + lc4*4);
        __syncthreads();
        const int kb = lc4*4;
        As[(kb+0)*68 + lrow]    = a0.x; As[(kb+1)*68 + lrow]    = a0.y;
        As[(kb+2)*68 + lrow]    = a0.z; As[(kb+3)*68 + lrow]    = a0.w;
        As[(kb+0)*68 + lrow+32] = a1.x; As[(kb+1)*68 + lrow+32] = a1.y;
        As[(kb+2)*68 + lrow+32] = a1.z; As[(kb+3)*68 + lrow+32] = a1.w;
        Bs[(kb+0)*68 + lrow]    = b0.x; Bs[(kb+1)*68 + lrow]    = b0.y;
        Bs[(kb+2)*68 + lrow]    = b0.z; Bs[(kb+3)*68 + lrow]    = b0.w;
        Bs[(kb+0)*68 + lrow+32] = b1.x; Bs[(kb+1)*68 + lrow+32] = b1.y;
        Bs[(kb+2)*68 + lrow+32] = b1.z; Bs[(kb+3)*68 + lrow+32] = b1.w;
        __syncthreads();
        #pragma unroll
        for (int kk = 0; kk < 32; ++kk) {
            float4 av = *reinterpret_cast<const float4*>(As + kk*68 + tm);
            float4 bv = *reinterpret_cast<const float4*>(Bs + kk*68 + tn);
            acc[0][0] += av.x*bv.x; acc[0][1] += av.x*bv.y; acc[0][2] += av.x*bv.z; acc[0][3] += av.x*bv.w;
            acc[1][0] += av.y*bv.x; acc[1][1] += av.y*bv.y; acc[1][2] += av.y*bv.z; acc[1][3] += av.y*bv.w;
            acc[2][0] += av.z*bv.x; acc[2][1] += av.z*bv.y; acc[2][2] += av.z*bv.z; acc[2][3] += av.z*bv.w;
            acc[3][0] += av.w*bv.x; acc[3][1] += av.w*bv.y; acc[3][2] += av.w*bv.z; acc[3][3] += av.w*bv.w;
        }
    }

    #pragma unroll
    for (int i = 0; i < 4; ++i) {
        float r0 = acc[i][0], r1 = acc[i][1], r2 = acc[i][2], r3 = acc[i][3];
        if (bp) { r0 += bp[n0+tn+0]; r1 += bp[n0+tn+1]; r2 += bp[n0+tn+2]; r3 += bp[n0+tn+3]; }
        if (act) { r0 = ftanh(r0); r1 = ftanh(r1); r2 = ftanh(r2); r3 = ftanh(r3); }
        float4 v = make_float4(r0, r1, r2, r3);
        *reinterpret_cast<float4*>(C + (size_t)(m0+tm+i)*ldc + (n0+tn)) = v;
    }
}

__global__ __launch_bounds__(256) void gemm_skinny(
    const float* A0, const float* B0, const float* bias0, float* C0,
    const float* A1, const float* B1, const float* bias1, float* C1,
    int N, int K, int ldc)
{
    const float* A  = blockIdx.z ? A1 : A0;
    const float* B  = blockIdx.z ? B1 : B0;
    const float* bp = blockIdx.z ? bias1 : bias0;
    float*       C  = blockIdx.z ? C1 : C0;

    __shared__ float As[16*64];
    const int n0 = blockIdx.x * 64;
    const int m0 = blockIdx.y * 16;
    const int t  = threadIdx.x;
    const int n  = t & 63;
    const int mb = t >> 6;

    float acc[4] = {};

    for (int k0 = 0; k0 < K; k0 += 64) {
        __syncthreads();
        const int row = t >> 4, c4 = t & 15;
        *reinterpret_cast<float4*>(As + row*64 + c4*4) =
            *reinterpret_cast<const float4*>(A + (size_t)(m0+row)*K + k0 + c4*4);
        __syncthreads();
        const float* Bp = B + (size_t)(n0+n)*K + k0;
        #pragma unroll
        for (int q = 0; q < 16; ++q) {
            float4 bv = *reinterpret_cast<const float4*>(Bp + q*4);
            #pragma unroll
            for (int mm = 0; mm < 4; ++mm) {
                float4 av = *reinterpret_cast<const float4*>(As + (mb + 4*mm)*64 + q*4);
                acc[mm] += av.x*bv.x + av.y*bv.y + av.z*bv.z + av.w*bv.w;
            }
        }
    }
    const float bz = bp ? bp[n0+n] : 0.0f;
    #pragma unroll
    for (int mm = 0; mm < 4; ++mm)
        C[(size_t)(m0 + mb + 4*mm)*ldc + n0 + n] = acc[mm] + bz;
}

__global__ __launch_bounds__(256) void gru_gate_k(
    const float* gi, const float* gh, const float* hold, float* hnew)
{
    int idx = blockIdx.x*256 + threadIdx.x;
    if (idx >= 64*768) return;
    int b = idx / 768, j = idx % 768;
    const float* gib = gi + (size_t)b*2304;
    const float* ghb = gh + (size_t)b*2304;
    hnew[idx] = gru_fuse(gib[j], gib[j+768], gib[j+1536],
                         ghb[j], ghb[j+768], ghb[j+1536], hold[idx]);
}

// ===========================================================================
extern "C" void kernel_launch(void* const* d_in, const int* in_sizes, int n_in,
                              void* d_out, int out_size, void* d_ws, size_t ws_size,
                              hipStream_t stream)
{
    (void)in_sizes; (void)n_in; (void)out_size;
    const int*   inp       = (const int*)  d_in[0];
    const int*   y         = (const int*)  d_in[1];
    const float* emb_enc   = (const float*)d_in[2];
    const float* enc_Wih   = (const float*)d_in[3];
    const float* enc_Whh   = (const float*)d_in[4];
    const float* enc_bih   = (const float*)d_in[5];
    const float* enc_bhh   = (const float*)d_in[6];
    const float* out_enc_W = (const float*)d_in[7];
    const float* emb_dec   = (const float*)d_in[8];
    const float* dec_Wih   = (const float*)d_in[9];
    const float* dec_Whh   = (const float*)d_in[10];
    const float* dec_bih   = (const float*)d_in[11];
    const float* dec_bhh   = (const float*)d_in[12];
    const float* out_b     = (const float*)d_in[13];
    const float* W1        = (const float*)d_in[14];
    const float* l2_W      = (const float*)d_in[15];
    const float* l2_b      = (const float*)d_in[16];
    const float* l3_W      = (const float*)d_in[17];
    const float* l3_b      = (const float*)d_in[18];
    const float* Vp        = (const float*)d_in[19];
    float* out = (float*)d_out;
    float* ws  = (float*)d_ws;

    size_t off = 0;
    auto alloc = [&](size_t n) { float* p = ws + off; off += (n + 63) & ~(size_t)63; return p; };
    // ---- base region (also serves fp32 fallback) ----
    float* x0     = alloc(4096*512);   // also W03f temp (spans into x1, both dead post-encoder)
    float* x1     = alloc(4096*512);
    float* x2     = alloc(4096*512);   // enc_out, permuted [b][s][512]
    float* giF    = alloc(4096*768);
    float* giB    = alloc(4096*768);
    float* w1e    = alloc(4096*768);   // [b][s][768]
    float* scb    = alloc(4096*768);   // [b][s][768]
    float* W1T    = alloc(768*512);
    float* hfin   = alloc(128*512);
    float* hdecA  = alloc(128*768);
    float* hdecB  = alloc(128*768);
    float* w2h    = alloc(64*768);
    float* wgt_in = alloc(64*1280);
    float* wgt    = alloc(64*768);     // fallback only
    float* gh0buf = alloc(64*2304);
    float* gh1buf = alloc(64*2304);
    float* gi0f   = alloc(64*2304);    // fallback only
    float* gi1f   = alloc(64*2304);    // fallback only
    float* b03    = alloc(2304);
    float* scratch= alloc(64*VDIM);    // also l3T temp (983040 < 2048000)
    auto ualloc = [&](size_t nush) { return (unsigned short*)alloc((nush + 1) / 2); };
    unsigned short* encWhhH = ualloc(2*2*768*256);   // fp16 single, base region
    // ---- fp16 region ----
    unsigned short* embH    = ualloc((size_t)VDIM*768);
    unsigned short* encWihH = ualloc(2*2*768*512);
    unsigned short* encWihL = ualloc(2*2*768*512);
    unsigned short* W1TH    = ualloc(768*512);
    unsigned short* W1TL    = ualloc(768*512);
    unsigned short* oeH     = ualloc(768*512);
    unsigned short* oeL     = ualloc(768*512);
    unsigned short* l2H     = ualloc(768*768);
    unsigned short* l2L     = ualloc(768*768);
    unsigned short* l3TH    = ualloc(1280*768);
    unsigned short* l3TL    = ualloc(1280*768);
    unsigned short* dWihH   = ualloc((size_t)2*2304*768);
    unsigned short* dWihL   = ualloc((size_t)2*2304*768);
    unsigned short* dWhhH   = ualloc((size_t)2*2304*768);
    unsigned short* dWhhL   = ualloc((size_t)2*2304*768);
    unsigned short* W03H    = ualloc((size_t)2304*1280);
    unsigned short* W03L    = ualloc((size_t)2304*1280);
    const bool use_mfma = ws_size >= off * sizeof(float);

    const size_t L1W = (size_t)2304*768;
    float* l3T  = scratch;   // 1280x768 temp, free until decoder
    float* W03f = x0;        // 2304x1280 temp, free post-encoder (spans x0+x1)

    // ---- common setup ----
    embed_k<<<2048, 256, 0, stream>>>(inp, emb_enc, x0);
    transpose2_k<<<(512*768 + 255)/256, 256, 0, stream>>>(W1, W1T, 512, 768);
    conv16_k<<<768, 256, 0, stream>>>(enc_Whh, encWhhH, 2*2*768*256/4);

    if (use_mfma) {
        convhl_k<<<1536, 256, 0, stream>>>(enc_Wih, encWihH, encWihL, 2*2*768*512/4);
        convhl_k<<<384, 256, 0, stream>>>(W1T, W1TH, W1TL, 768*512/4);
        convhl_k<<<384, 256, 0, stream>>>(out_enc_W, oeH, oeL, 768*512/4);
        convhl_k<<<576, 256, 0, stream>>>(l2_W, l2H, l2L, 768*768/4);
        convhl_k<<<3456, 256, 0, stream>>>(dec_Wih, dWihH, dWihL, (int)(L1W*2/4));
        convhl_k<<<3456, 256, 0, stream>>>(dec_Whh, dWhhH, dWhhL, (int)(L1W*2/4));
        conv16_k<<<24000, 256, 0, stream>>>(emb_dec, embH, (int)((size_t)VDIM*768/4));
        transpose2_k<<<(768*1280 + 255)/256, 256, 0, stream>>>(l3_W, l3T, 768, 1280);
        convhl_k<<<960, 256, 0, stream>>>(l3T, l3TH, l3TL, 1280*768/4);
        b03_k<<<9, 256, 0, stream>>>(dec_Wih, dec_bih, l3_b, b03);

        // ---- encoder ----
        for (int l = 0; l < 2; ++l) {
            const float* xin  = l ? x1 : x0;
            float*       xout = l ? x2 : x1;
            const size_t wo = (size_t)l*2*768*512;
            mfma_gemm<<<dim3(6, 64, 2), 256, 0, stream>>>(
                xin, encWihH + wo,           encWihL + wo,           enc_bih + l*2*768,       giF, 768, 768, 0,
                xin, encWihH + wo + 768*512, encWihL + wo + 768*512, enc_bih + l*2*768 + 768, giB, 768, 768, 0,
                512);
            enc_layer_k<<<dim3(64, 2), 256, 0, stream>>>(
                giF, giB, encWhhH + (size_t)l*2*768*256, enc_bhh + (size_t)l*2*768,
                xout, hfin + (size_t)l*64*512, l);   // layer 1 permuted
        }

        // W03 = Wih0 @ l3_W  (x0/x1 now dead -> W03f)
        mfma_gemm<<<dim3(10, 36, 1), 256, 0, stream>>>(
            dec_Wih, l3TH, l3TL, nullptr, W03f, 1280, 1280, 0,
            nullptr, nullptr, nullptr, nullptr, nullptr, 0, 0, 0,
            768);
        convhl_k<<<2880, 256, 0, stream>>>(W03f, W03H, W03L, 2304*1280/4);

        // decoder initial hidden (128,512)@out_enc_W^T
        mfma_gemm<<<dim3(6, 2, 1), 256, 0, stream>>>(
            hfin, oeH, oeL, nullptr, hdecA, 768, 768, 0,
            nullptr, nullptr, nullptr, nullptr, nullptr, 0, 0, 0,
            512);

        // w1e = enc_out@W1 ; scb = tanh(enc_out@out_enc_W^T)  (rows b*64+s)
        mfma_gemm<<<dim3(6, 64, 2), 256, 0, stream>>>(
            x2, W1TH, W1TL, nullptr, w1e, 768, 768, 0,
            x2, oeH,  oeL,  nullptr, scb, 768, 768, 1,
            512);

        // bootstrap: w2h = h1@l2 ; gh0 = h0@Whh0 ; gh1 = h1@Whh1
        mfma_gemm<<<dim3(6, 1, 1), 256, 0, stream>>>(
            hdecA + 64*768, l2H, l2L, l2_b, w2h, 768, 768, 0,
            nullptr, nullptr, nullptr, nullptr, nullptr, 0, 0, 0,
            768);
        gru_mfma_k<<<dim3(48, 1, 2), 256, 0, stream>>>(
            hdecA,          dWhhH,       dWhhL,       dec_bhh,        nullptr, nullptr, gh0buf, 0, 768,
            hdecA + 64*768, dWhhH + L1W, dWhhL + L1W, dec_bhh + 2304, nullptr, nullptr, gh1buf, 0, 768);

        // ---- decoder: 5 launches per step ----
        for (int st = 0; st < TSL; ++st) {
            float* h0c = (st & 1) ? hdecB : hdecA;
            float* h0n = (st & 1) ? hdecA : hdecB;
            float* h1c = h0c + 64*768;
            float* h1n = h0n + 64*768;
            float* orow = out + (size_t)st*BSZ*NCOL;

            att_fused_k<<<64, 256, 0, stream>>>(w1e, w2h, Vp, x2, emb_dec, y, st, wgt_in);

            // gi0 = wgt_in@W03^T + b03, fused gate0 -> h0n
            gru_mfma_k<<<dim3(48, 1, 1), 256, 0, stream>>>(
                wgt_in, W03H, W03L, b03, gh0buf, h0c, h0n, 1, 1280,
                wgt_in, W03H, W03L, b03, gh0buf, h0c, h0n, 1, 1280);

            // gi1 = h0n@Wih1^T, fused gate1 -> h1n  ||  gh0' = h0n@Whh0 (next step)
            gru_mfma_k<<<dim3(48, 1, 2), 256, 0, stream>>>(
                h0n, dWihH + L1W, dWihL + L1W, dec_bih + 2304, gh1buf, h1c, h1n, 1, 768,
                h0n, dWhhH,       dWhhL,       dec_bhh,        nullptr, nullptr, gh0buf, 0, 768);

            // vocab logits || w2h'(next) || gh1'(next)
            mfma_gemm3<<<dim3(250, 1, 3), 256, 0, stream>>>(
                h1n, embH,        nullptr,     out_b,          scratch, VDIM, VDIM,
                h1n, l2H,         l2L,         l2_b,           w2h,     768,  768,
                h1n, dWhhH + L1W, dWhhL + L1W, dec_bhh + 2304, gh1buf,  2304, 2304,
                768);

            smax2_k<<<64, 256, 0, stream>>>(scratch, scb, h1n, y, orow);
        }
    } else {
        // ================= fp32 fallback =================
        for (int l = 0; l < 2; ++l) {
            const float* xin  = l ? x1 : x0;
            float*       xout = l ? x2 : x1;
            const float* Wih = enc_Wih + (size_t)l*2*768*512;
            const float* bih = enc_bih + (size_t)l*2*768;
            gemm64<<<dim3(12, 64, 2), 256, 0, stream>>>(
                xin, Wih,           bih,       giF, 0,
                xin, Wih + 768*512, bih + 768, giB, 0,
                4096, 768, 512, 768);
            enc_layer_k<<<dim3(64, 2), 256, 0, stream>>>(
                giF, giB, encWhhH + (size_t)l*2*768*256, enc_bhh + (size_t)l*2*768,
                xout, hfin + (size_t)l*64*512, l);
        }
        gemm64<<<dim3(12, 2, 1), 256, 0, stream>>>(
            hfin, out_enc_W, nullptr, hdecA, 0,
            hfin, out_enc_W, nullptr, hdecA, 0,
            128, 768, 512, 768);
        gemm64<<<dim3(12, 64, 2), 256, 0, stream>>>(
            x2, W1T,       nullptr, w1e, 0,
            x2, out_enc_W, nullptr, scb, 1,
            4096, 768, 512, 768);
        gemm_skinny<<<dim3(12, 4, 1), 256, 0, stream>>>(
            hdecA + 64*768, l2_W, l2_b, w2h,
            hdecA + 64*768, l2_W, l2_b, w2h,
            768, 768, 768);

        for (int st = 0; st < TSL; ++st) {
            float* h0c = (st & 1) ? hdecB : hdecA;
            float* h0n = (st & 1) ? hdecA : hdecB;
            float* h1c = h0c + 64*768;
            float* h1n = h0n + 64*768;
            float* orow = out + (size_t)st*BSZ*NCOL;

            att_fused_k<<<64, 256, 0, stream>>>(w1e, w2h, Vp, x2, emb_dec, y, st, wgt_in);
            gemm_skinny<<<dim3(12, 4, 1), 256, 0, stream>>>(
                wgt_in, l3_W, l3_b, wgt,
                wgt_in, l3_W, l3_b, wgt,
                768, 1280, 768);
            gemm_skinny<<<dim3(36, 4, 2), 256, 0, stream>>>(
                wgt, dec_Wih, dec_bih, gi0f,
                h0c, dec_Whh, dec_bhh, gh0buf,
                2304, 768, 2304);
            gru_gate_k<<<192, 256, 0, stream>>>(gi0f, gh0buf, h0c, h0n);
            gemm_skinny<<<dim3(36, 4, 2), 256, 0, stream>>>(
                h0n, dec_Wih + L1W, dec_bih + 2304, gi1f,
                h1c, dec_Whh + L1W, dec_bhh + 2304, gh1buf,
                2304, 768, 2304);
            gru_gate_k<<<192, 256, 0, stream>>>(gi1f, gh1buf, h1c, h1n);
            gemm_skinny<<<dim3(12, 4, 1), 256, 0, stream>>>(
                h1n, l2_W, l2_b, w2h,
                h1n, l2_W, l2_b, w2h,
                768, 768, 768);
            gemm64<<<dim3(500, 1, 1), 256, 0, stream>>>(
                h1n, emb_dec, out_b, scratch, 0,
                h1n, emb_dec, out_b, scratch, 0,
                64, VDIM, 768, VDIM);
            smax2_k<<<64, 256, 0, stream>>>(scratch, scb, h1n, y, orow);
        }
    }
}

// Round 5
// 9486.722 us; speedup vs baseline: 2.1802x; 1.3949x over previous
//
#include <hip/hip_runtime.h>

#define SLEN 64
#define BSZ  64
#define TSL  48
#define VDIM 32000
#define NCOL 32064   // VDIM + SLEN

typedef __attribute__((ext_vector_type(8))) _Float16 f16x8;
typedef __attribute__((ext_vector_type(4))) _Float16 f16x4;
typedef __attribute__((ext_vector_type(4))) float f32x4;

__device__ __forceinline__ float fsig(float x){
    return 1.0f/(1.0f + __expf(-x));
}
__device__ __forceinline__ float ftanh(float x){
    float e = __expf(2.0f*x);
    return 1.0f - 2.0f/(e + 1.0f);
}
__device__ __forceinline__ unsigned short f2h(float x){
    union { _Float16 f; unsigned short u; } c; c.f = (_Float16)x; return c.u;
}
__device__ __forceinline__ float h2f(unsigned short u){
    union { _Float16 f; unsigned short u; } c; c.u = u; return (float)c.f;
}
__device__ __forceinline__ unsigned short f2h_hi(float x, float& rem){
    _Float16 h = (_Float16)x;
    rem = x - (float)h;
    union { _Float16 f; unsigned short u; } c; c.f = h; return c.u;
}
__device__ __forceinline__ float gru_fuse(float gir,float giz,float gin,
                                          float ghr,float ghz,float ghn,float h){
    float r = fsig(gir + ghr);
    float z = fsig(giz + ghz);
    float n = ftanh(gin + r*ghn);
    return (1.0f - z)*n + z*h;
}

// ===========================================================================
// MFMA GEMM (2 param sets): C = A @ B^T + bias, optional tanh.
// A fp32 (lda=K) -> fp16 hi/lo inline while staging LDS. B fp16 hi(+lo).
// grid = (ceil(maxN/128), M/64, nz).
// ===========================================================================
__global__ __launch_bounds__(256) void mfma_gemm(
    const float* A0, const unsigned short* Bh0, const unsigned short* Bl0,
    const float* bias0, float* C0, int N0, int ldc0, int act0,
    const float* A1, const unsigned short* Bh1, const unsigned short* Bl1,
    const float* bias1, float* C1, int N1, int ldc1, int act1,
    int K)
{
    const float* A; const unsigned short* Bh; const unsigned short* Bl;
    const float* bias; float* C; int N, ldc, act;
    if (blockIdx.z == 0) { A=A0; Bh=Bh0; Bl=Bl0; bias=bias0; C=C0; N=N0; ldc=ldc0; act=act0; }
    else                 { A=A1; Bh=Bh1; Bl=Bl1; bias=bias1; C=C1; N=N1; ldc=ldc1; act=act1; }

    const int n0 = blockIdx.x * 128;
    if (n0 >= N) return;
    const int m0 = blockIdx.y * 64;

    __shared__ __align__(16) unsigned short As[2][64][72];
    __shared__ __align__(16) unsigned short Bs[2][128][72];

    const int t  = threadIdx.x;
    const int wv = t >> 6, ln = t & 63;
    const bool has_lo = (Bl != nullptr);

    f32x4 acc[4][2];
    #pragma unroll
    for (int i = 0; i < 4; ++i)
        #pragma unroll
        for (int j = 0; j < 2; ++j) acc[i][j] = (f32x4){0.f,0.f,0.f,0.f};

    for (int k0 = 0; k0 < K; k0 += 64) {
        __syncthreads();
        #pragma unroll
        for (int it = 0; it < 4; ++it) {
            int idx = t + it*256;
            int r = idx >> 4, c4 = (idx & 15) * 4;
            float4 v = *reinterpret_cast<const float4*>(A + (size_t)(m0+r)*K + k0 + c4);
            ushort4 h, l; float rm;
            h.x = f2h_hi(v.x, rm); l.x = f2h(rm);
            h.y = f2h_hi(v.y, rm); l.y = f2h(rm);
            h.z = f2h_hi(v.z, rm); l.z = f2h(rm);
            h.w = f2h_hi(v.w, rm); l.w = f2h(rm);
            *reinterpret_cast<ushort4*>(&As[0][r][c4]) = h;
            *reinterpret_cast<ushort4*>(&As[1][r][c4]) = l;
        }
        #pragma unroll
        for (int it = 0; it < 4; ++it) {
            int idx = t + it*256;
            int r = idx >> 3, c8 = (idx & 7) * 8;
            *reinterpret_cast<uint4*>(&Bs[0][r][c8]) =
                *reinterpret_cast<const uint4*>(&Bh[(size_t)(n0+r)*K + k0 + c8]);
        }
        if (has_lo) {
            #pragma unroll
            for (int it = 0; it < 4; ++it) {
                int idx = t + it*256;
                int r = idx >> 3, c8 = (idx & 7) * 8;
                *reinterpret_cast<uint4*>(&Bs[1][r][c8]) =
                    *reinterpret_cast<const uint4*>(&Bl[(size_t)(n0+r)*K + k0 + c8]);
            }
        }
        __syncthreads();
        #pragma unroll
        for (int ks = 0; ks < 2; ++ks) {
            const int ko = ks*32 + (ln >> 4)*8;
            f16x8 ah[4], al[4], bh[2], bl[2];
            #pragma unroll
            for (int m = 0; m < 4; ++m) {
                ah[m] = *reinterpret_cast<const f16x8*>(&As[0][m*16 + (ln&15)][ko]);
                al[m] = *reinterpret_cast<const f16x8*>(&As[1][m*16 + (ln&15)][ko]);
            }
            #pragma unroll
            for (int n = 0; n < 2; ++n) {
                bh[n] = *reinterpret_cast<const f16x8*>(&Bs[0][wv*32 + n*16 + (ln&15)][ko]);
                if (has_lo)
                    bl[n] = *reinterpret_cast<const f16x8*>(&Bs[1][wv*32 + n*16 + (ln&15)][ko]);
            }
            #pragma unroll
            for (int m = 0; m < 4; ++m)
                #pragma unroll
                for (int n = 0; n < 2; ++n) {
                    acc[m][n] = __builtin_amdgcn_mfma_f32_16x16x32_f16(ah[m], bh[n], acc[m][n], 0,0,0);
                    acc[m][n] = __builtin_amdgcn_mfma_f32_16x16x32_f16(al[m], bh[n], acc[m][n], 0,0,0);
                    if (has_lo)
                        acc[m][n] = __builtin_amdgcn_mfma_f32_16x16x32_f16(ah[m], bl[n], acc[m][n], 0,0,0);
                }
        }
    }
    #pragma unroll
    for (int m = 0; m < 4; ++m) {
        #pragma unroll
        for (int n = 0; n < 2; ++n) {
            const int col = n0 + wv*32 + n*16 + (ln & 15);
            const float bz = bias ? bias[col] : 0.0f;
            #pragma unroll
            for (int j = 0; j < 4; ++j) {
                const int row = m0 + m*16 + (ln >> 4)*4 + j;
                float v = acc[m][n][j] + bz;
                if (act) v = ftanh(v);
                C[(size_t)row*ldc + col] = v;
            }
        }
    }
}

// ===========================================================================
// Barrier-free MFMA GRU-GEMM (as round 4; B single-fp16 when BL=nullptr).
// ===========================================================================
__global__ __launch_bounds__(256) void gru_mfma_k(
    const float* A0, const unsigned short* BH0, const unsigned short* BL0,
    const float* bias0, const float* gh0, const float* hold0, float* out0,
    int gate0, int K0,
    const float* A1, const unsigned short* BH1, const unsigned short* BL1,
    const float* bias1, const float* gh1, const float* hold1, float* out1,
    int gate1, int K1)
{
    const float* A; const unsigned short* BH; const unsigned short* BL;
    const float* bias; const float* gh; const float* hold; float* outp; int gate, K;
    if (blockIdx.z == 0) { A=A0; BH=BH0; BL=BL0; bias=bias0; gh=gh0; hold=hold0; outp=out0; gate=gate0; K=K0; }
    else                 { A=A1; BH=BH1; BL=BL1; bias=bias1; gh=gh1; hold=hold1; outp=out1; gate=gate1; K=K1; }

    const int t = threadIdx.x;
    const int wv = t >> 6, ln = t & 63;
    const int colg16 = blockIdx.x * 16;
    const int arow = wv*16 + (ln & 15);
    const int kof  = (ln >> 4) * 8;
    const bool has_lo = (BL != nullptr);

    f32x4 acc[3];
    #pragma unroll
    for (int g = 0; g < 3; ++g) acc[g] = (f32x4){0.f,0.f,0.f,0.f};

    const float* Ar = A + (size_t)arow*K + kof;
    const int brow_n = colg16 + (ln & 15);

    #pragma unroll 2
    for (int k0 = 0; k0 < K; k0 += 32) {
        float4 a0 = *reinterpret_cast<const float4*>(Ar + k0);
        float4 a1 = *reinterpret_cast<const float4*>(Ar + k0 + 4);
        f16x8 ah, al;
        {
            float av0=a0.x, av1=a0.y, av2=a0.z, av3=a0.w;
            float av4=a1.x, av5=a1.y, av6=a1.z, av7=a1.w;
            _Float16 hh;
            hh=(_Float16)av0; ah[0]=hh; al[0]=(_Float16)(av0-(float)hh);
            hh=(_Float16)av1; ah[1]=hh; al[1]=(_Float16)(av1-(float)hh);
            hh=(_Float16)av2; ah[2]=hh; al[2]=(_Float16)(av2-(float)hh);
            hh=(_Float16)av3; ah[3]=hh; al[3]=(_Float16)(av3-(float)hh);
            hh=(_Float16)av4; ah[4]=hh; al[4]=(_Float16)(av4-(float)hh);
            hh=(_Float16)av5; ah[5]=hh; al[5]=(_Float16)(av5-(float)hh);
            hh=(_Float16)av6; ah[6]=hh; al[6]=(_Float16)(av6-(float)hh);
            hh=(_Float16)av7; ah[7]=hh; al[7]=(_Float16)(av7-(float)hh);
        }
        #pragma unroll
        for (int g = 0; g < 3; ++g) {
            const size_t boff = (size_t)(g*768 + brow_n)*K + k0 + kof;
            f16x8 bh = *reinterpret_cast<const f16x8*>(&BH[boff]);
            acc[g] = __builtin_amdgcn_mfma_f32_16x16x32_f16(ah, bh, acc[g], 0,0,0);
            acc[g] = __builtin_amdgcn_mfma_f32_16x16x32_f16(al, bh, acc[g], 0,0,0);
            if (has_lo) {
                f16x8 bl = *reinterpret_cast<const f16x8*>(&BL[boff]);
                acc[g] = __builtin_amdgcn_mfma_f32_16x16x32_f16(ah, bl, acc[g], 0,0,0);
            }
        }
    }

    const int colg = colg16 + (ln & 15);
    const int rb   = wv*16 + (ln >> 4)*4;
    if (gate) {
        const float br = bias[colg], bz = bias[768+colg], bn = bias[1536+colg];
        #pragma unroll
        for (int jj = 0; jj < 4; ++jj) {
            const int row = rb + jj;
            float ghr = gh[(size_t)row*2304 + colg];
            float ghz = gh[(size_t)row*2304 + 768 + colg];
            float ghn = gh[(size_t)row*2304 + 1536 + colg];
            float h   = hold[(size_t)row*768 + colg];
            outp[(size_t)row*768 + colg] =
                gru_fuse(acc[0][jj]+br, acc[1][jj]+bz, acc[2][jj]+bn, ghr, ghz, ghn, h);
        }
    } else {
        #pragma unroll
        for (int g = 0; g < 3; ++g) {
            const float bz = bias[g*768 + colg];
            #pragma unroll
            for (int jj = 0; jj < 4; ++jj)
                outp[(size_t)(rb+jj)*2304 + g*768 + colg] = acc[g][jj] + bz;
        }
    }
}

// ===========================================================================
// Vocab (+w2h' +gh1') triple GEMM, K=768, A=h1n. z=0: exp(logit)->fp16 scratch
// + striped per-row partial sums. z=1/2: float C. B single-fp16, A hi/lo.
// grid (250, 1, 3).
// ===========================================================================
__global__ __launch_bounds__(256) void vocab3_k(
    const float* __restrict__ A,
    const unsigned short* __restrict__ B0, const float* __restrict__ bias0,
    unsigned short* __restrict__ scr16, float* __restrict__ psum,
    const unsigned short* __restrict__ B1, const float* __restrict__ bias1, float* __restrict__ C1,
    const unsigned short* __restrict__ B2, const float* __restrict__ bias2, float* __restrict__ C2)
{
    const int z = blockIdx.z;
    const unsigned short* Bh; const float* bias; int N, ldc;
    if (z == 0)      { Bh=B0; bias=bias0; N=VDIM; ldc=VDIM; }
    else if (z == 1) { Bh=B1; bias=bias1; N=768;  ldc=768; }
    else             { Bh=B2; bias=bias2; N=2304; ldc=2304; }
    const int n0 = blockIdx.x * 128;
    if (n0 >= N) return;

    __shared__ __align__(16) unsigned short As[2][64][72];
    __shared__ __align__(16) unsigned short Bs[128][72];
    __shared__ float rs[4][64];

    const int t = threadIdx.x, wv = t >> 6, ln = t & 63;

    f32x4 acc[4][2];
    #pragma unroll
    for (int i = 0; i < 4; ++i)
        #pragma unroll
        for (int j = 0; j < 2; ++j) acc[i][j] = (f32x4){0.f,0.f,0.f,0.f};

    for (int k0 = 0; k0 < 768; k0 += 64) {
        __syncthreads();
        #pragma unroll
        for (int it = 0; it < 4; ++it) {
            int idx = t + it*256;
            int r = idx >> 4, c4 = (idx & 15) * 4;
            float4 v = *reinterpret_cast<const float4*>(A + (size_t)r*768 + k0 + c4);
            ushort4 h, l; float rm;
            h.x = f2h_hi(v.x, rm); l.x = f2h(rm);
            h.y = f2h_hi(v.y, rm); l.y = f2h(rm);
            h.z = f2h_hi(v.z, rm); l.z = f2h(rm);
            h.w = f2h_hi(v.w, rm); l.w = f2h(rm);
            *reinterpret_cast<ushort4*>(&As[0][r][c4]) = h;
            *reinterpret_cast<ushort4*>(&As[1][r][c4]) = l;
        }
        #pragma unroll
        for (int it = 0; it < 4; ++it) {
            int idx = t + it*256;
            int r = idx >> 3, c8 = (idx & 7) * 8;
            *reinterpret_cast<uint4*>(&Bs[r][c8]) =
                *reinterpret_cast<const uint4*>(&Bh[(size_t)(n0+r)*768 + k0 + c8]);
        }
        __syncthreads();
        #pragma unroll
        for (int ks = 0; ks < 2; ++ks) {
            const int ko = ks*32 + (ln >> 4)*8;
            f16x8 ah[4], al[4], bh[2];
            #pragma unroll
            for (int m = 0; m < 4; ++m) {
                ah[m] = *reinterpret_cast<const f16x8*>(&As[0][m*16 + (ln&15)][ko]);
                al[m] = *reinterpret_cast<const f16x8*>(&As[1][m*16 + (ln&15)][ko]);
            }
            #pragma unroll
            for (int n = 0; n < 2; ++n)
                bh[n] = *reinterpret_cast<const f16x8*>(&Bs[wv*32 + n*16 + (ln&15)][ko]);
            #pragma unroll
            for (int m = 0; m < 4; ++m)
                #pragma unroll
                for (int n = 0; n < 2; ++n) {
                    acc[m][n] = __builtin_amdgcn_mfma_f32_16x16x32_f16(ah[m], bh[n], acc[m][n], 0,0,0);
                    acc[m][n] = __builtin_amdgcn_mfma_f32_16x16x32_f16(al[m], bh[n], acc[m][n], 0,0,0);
                }
        }
    }

    if (z == 0) {
        float sums[4][4];
        #pragma unroll
        for (int m = 0; m < 4; ++m)
            #pragma unroll
            for (int j = 0; j < 4; ++j) sums[m][j] = 0.f;
        #pragma unroll
        for (int m = 0; m < 4; ++m) {
            #pragma unroll
            for (int n = 0; n < 2; ++n) {
                const int col = n0 + wv*32 + n*16 + (ln & 15);
                const float bz = bias[col];
                #pragma unroll
                for (int j = 0; j < 4; ++j) {
                    const int row = m*16 + (ln >> 4)*4 + j;
                    float e = __expf(acc[m][n][j] + bz);
                    scr16[(size_t)row*VDIM + col] = f2h(e);
                    sums[m][j] += e;
                }
            }
        }
        #pragma unroll
        for (int m = 0; m < 4; ++m)
            #pragma unroll
            for (int j = 0; j < 4; ++j) {
                float v = sums[m][j];
                v += __shfl_xor(v, 1); v += __shfl_xor(v, 2);
                v += __shfl_xor(v, 4); v += __shfl_xor(v, 8);
                if ((ln & 15) == 0) rs[wv][m*16 + (ln >> 4)*4 + j] = v;
            }
        __syncthreads();
        if (t < 64)
            atomicAdd(&psum[t*8 + (blockIdx.x & 7)], rs[0][t]+rs[1][t]+rs[2][t]+rs[3][t]);
    } else {
        float* C = (z == 1) ? C1 : C2;
        #pragma unroll
        for (int m = 0; m < 4; ++m) {
            #pragma unroll
            for (int n = 0; n < 2; ++n) {
                const int col = n0 + wv*32 + n*16 + (ln & 15);
                const float bz = bias[col];
                #pragma unroll
                for (int j = 0; j < 4; ++j) {
                    const int row = m*16 + (ln >> 4)*4 + j;
                    C[(size_t)row*ldc + col] = acc[m][n][j] + bz;
                }
            }
        }
    }
}

// ===========================================================================
// conversions / transposes / small setup kernels
// ===========================================================================
__global__ __launch_bounds__(256) void convhl_k(
    const float* __restrict__ W, unsigned short* __restrict__ hi,
    unsigned short* __restrict__ lo, int n4)
{
    int i = blockIdx.x*256 + threadIdx.x;
    if (i >= n4) return;
    float4 v = reinterpret_cast<const float4*>(W)[i];
    ushort4 h, l; float r;
    h.x = f2h_hi(v.x, r); l.x = f2h(r);
    h.y = f2h_hi(v.y, r); l.y = f2h(r);
    h.z = f2h_hi(v.z, r); l.z = f2h(r);
    h.w = f2h_hi(v.w, r); l.w = f2h(r);
    reinterpret_cast<ushort4*>(hi)[i] = h;
    reinterpret_cast<ushort4*>(lo)[i] = l;
}
__global__ __launch_bounds__(256) void conv16_k(
    const float* __restrict__ W, unsigned short* __restrict__ hi, int n4)
{
    int i = blockIdx.x*256 + threadIdx.x;
    if (i >= n4) return;
    float4 v = reinterpret_cast<const float4*>(W)[i];
    ushort4 h;
    h.x = f2h(v.x); h.y = f2h(v.y); h.z = f2h(v.z); h.w = f2h(v.w);
    reinterpret_cast<ushort4*>(hi)[i] = h;
}
__global__ __launch_bounds__(256) void transpose2_k(
    const float* __restrict__ S, float* __restrict__ D, int R, int C)
{
    int i = blockIdx.x*256 + threadIdx.x;
    if (i >= R*C) return;
    int r = i / C, c = i - r*C;
    D[(size_t)c*R + r] = S[i];
}
__global__ __launch_bounds__(256) void b03_k(
    const float* __restrict__ Wih0, const float* __restrict__ bih0,
    const float* __restrict__ l3b, float* __restrict__ b03)
{
    int j = blockIdx.x*256 + threadIdx.x;
    if (j >= 2304) return;
    const float* wr = Wih0 + (size_t)j*768;
    float s = 0.f;
    #pragma unroll 4
    for (int m = 0; m < 768; m += 4) {
        float4 w = *reinterpret_cast<const float4*>(wr + m);
        float4 b = *reinterpret_cast<const float4*>(l3b + m);
        s += w.x*b.x + w.y*b.y + w.z*b.z + w.w*b.w;
    }
    b03[j] = bih0[j] + s;
}

__global__ __launch_bounds__(256) void embed_k(const int* inp, const float* emb, float* x)
{
    int i = blockIdx.x*256 + threadIdx.x;
    if (i >= 4096*128) return;
    int row = i >> 7, c4 = i & 127;
    int tok = inp[row];
    *reinterpret_cast<float4*>(x + (size_t)row*512 + c4*4) =
        *reinterpret_cast<const float4*>(emb + (size_t)tok*512 + c4*4);
}

// ---------------------------------------------------------------------------
// Persistent encoder layer, fp16 Whh, 4 batches per block. grid (16, 2).
// permute=1 writes yout[(b*64+s)...], else [(s*64+b)...].
// ---------------------------------------------------------------------------
__global__ __launch_bounds__(256) void enc_layer4_k(
    const float* giF, const float* giB,
    const unsigned short* Whh16, const float* bhh,
    float* yout, float* hfin, int permute)
{
    const int bg = blockIdx.x, d = blockIdx.y, t = threadIdx.x;
    const float* gi_base = d ? giB : giF;
    const unsigned short* W = Whh16 + (size_t)d*768*256;
    const float br  = bhh[d*768 + t];
    const float bz2 = bhh[d*768 + t + 256];
    const float bn  = bhh[d*768 + t + 512];

    __shared__ float hs[4][256];
    #pragma unroll
    for (int bb = 0; bb < 4; ++bb) hs[bb][t] = 0.0f;
    __syncthreads();

    for (int step = 0; step < 64; ++step) {
        const int s = d ? (63 - step) : step;
        float gr[4], gz[4], gn[4];
        #pragma unroll
        for (int bb = 0; bb < 4; ++bb) {
            const float* gi = gi_base + (size_t)(s*64 + bg*4 + bb)*768;
            gr[bb] = gi[t]; gz[bb] = gi[t+256]; gn[bb] = gi[t+512];
        }
        float ar[4] = {}, az[4] = {}, an[4] = {};
        #pragma unroll 4
        for (int q = 0; q < 32; ++q) {
            f16x8 wr = *reinterpret_cast<const f16x8*>(&W[(size_t)(t      )*256 + q*8]);
            f16x8 wz = *reinterpret_cast<const f16x8*>(&W[(size_t)(t + 256)*256 + q*8]);
            f16x8 wn = *reinterpret_cast<const f16x8*>(&W[(size_t)(t + 512)*256 + q*8]);
            #pragma unroll
            for (int bb = 0; bb < 4; ++bb) {
                float4 h0 = *reinterpret_cast<const float4*>(&hs[bb][q*8]);
                float4 h1 = *reinterpret_cast<const float4*>(&hs[bb][q*8+4]);
                ar[bb] += h0.x*(float)wr[0] + h0.y*(float)wr[1] + h0.z*(float)wr[2] + h0.w*(float)wr[3]
                        + h1.x*(float)wr[4] + h1.y*(float)wr[5] + h1.z*(float)wr[6] + h1.w*(float)wr[7];
                az[bb] += h0.x*(float)wz[0] + h0.y*(float)wz[1] + h0.z*(float)wz[2] + h0.w*(float)wz[3]
                        + h1.x*(float)wz[4] + h1.y*(float)wz[5] + h1.z*(float)wz[6] + h1.w*(float)wz[7];
                an[bb] += h0.x*(float)wn[0] + h0.y*(float)wn[1] + h0.z*(float)wn[2] + h0.w*(float)wn[3]
                        + h1.x*(float)wn[4] + h1.y*(float)wn[5] + h1.z*(float)wn[6] + h1.w*(float)wn[7];
            }
        }
        float hn2[4];
        #pragma unroll
        for (int bb = 0; bb < 4; ++bb) {
            float r = fsig(gr[bb] + ar[bb] + br);
            float z = fsig(gz[bb] + az[bb] + bz2);
            float n = ftanh(gn[bb] + r*(an[bb] + bn));
            hn2[bb] = (1.0f - z)*n + z*hs[bb][t];
        }
        __syncthreads();
        #pragma unroll
        for (int bb = 0; bb < 4; ++bb) {
            hs[bb][t] = hn2[bb];
            const int b = bg*4 + bb;
            const int idx = permute ? (b*64 + s) : (s*64 + b);
            yout[(size_t)idx*512 + d*256 + t] = hn2[bb];
        }
        __syncthreads();
    }
    #pragma unroll
    for (int bb = 0; bb < 4; ++bb)
        hfin[(size_t)(bg*4 + bb)*512 + d*256 + t] = hs[bb][t];
}

// ---------------------------------------------------------------------------
// Fused attention, fp16 inputs (w1e16/enc16 rows = b*64+s). Zeroes psum. grid 64.
// ---------------------------------------------------------------------------
__global__ __launch_bounds__(256) void att_fused16_k(
    const unsigned short* __restrict__ w1e16, const float* __restrict__ w2h,
    const float* __restrict__ Vp, const unsigned short* __restrict__ enc16,
    const float* __restrict__ emb_dec, const int* __restrict__ y,
    int step, float* __restrict__ wgt_in, float* __restrict__ psum)
{
    const int b = blockIdx.x, t = threadIdx.x;
    if (t < 8) psum[b*8 + t] = 0.0f;
    __shared__ float w2s[768];
    __shared__ float vps[768];
    __shared__ float aa[64];
    for (int i = t; i < 768; i += 256) { w2s[i] = w2h[(size_t)b*768 + i]; vps[i] = Vp[i]; }
    __syncthreads();
    const int wv = t >> 6, ln = t & 63;
    for (int ss = 0; ss < 16; ++ss) {
        const int s = wv*16 + ss;
        const unsigned short* wrow = w1e16 + (size_t)(b*64 + s)*768;
        float acc = 0.f;
        #pragma unroll
        for (int q = 0; q < 12; ++q) {
            int e = ln + q*64;
            acc += ftanh(h2f(wrow[e]) + w2s[e]) * vps[e];
        }
        for (int off = 32; off; off >>= 1) acc += __shfl_down(acc, off);
        if (ln == 0) aa[s] = acc;
    }
    __syncthreads();
    if (t < 64) {
        float v = aa[t];
        float m = v;
        for (int off = 32; off; off >>= 1) m = fmaxf(m, __shfl_xor(m, off));
        float e = __expf(v - m);
        float ssum = e;
        for (int off = 32; off; off >>= 1) ssum += __shfl_xor(ssum, off);
        aa[t] = e / ssum;
    }
    __syncthreads();
    for (int e = t; e < 512; e += 256) {
        float acc = 0.f;
        #pragma unroll 8
        for (int s = 0; s < 64; ++s)
            acc += aa[s] * h2f(enc16[(size_t)(b*64 + s)*512 + e]);
        wgt_in[(size_t)b*1280 + 768 + e] = acc;
    }
    const int tok = (step == 0) ? 0 : y[(step-1)*64 + b];
    for (int e = t; e < 768; e += 256)
        wgt_in[(size_t)b*1280 + e] = emb_dec[(size_t)tok*768 + e];
}

// ---------------------------------------------------------------------------
// Final: copy-scores + normalize fp16 exp-scratch + scatter. grid 64 x 256.
// ---------------------------------------------------------------------------
__global__ __launch_bounds__(256) void smax_lite_k(
    const unsigned short* __restrict__ scr16, const unsigned short* __restrict__ scb16,
    const float* __restrict__ h1, const int* __restrict__ y,
    const float* __restrict__ psum, float* __restrict__ out)
{
    const int b = blockIdx.x, t = threadIdx.x;
    __shared__ float hsh[768];
    __shared__ float cps[64];
    __shared__ float invS;
    for (int i = t; i < 768; i += 256) hsh[i] = h1[(size_t)b*768 + i];
    __syncthreads();
    const int wv = t >> 6, ln = t & 63;
    for (int ss = 0; ss < 16; ++ss) {
        const int s = wv*16 + ss;
        const unsigned short* sp = scb16 + (size_t)(b*64 + s)*768;
        float acc = 0.f;
        #pragma unroll
        for (int q = 0; q < 12; ++q) { int e = ln + q*64; acc += h2f(sp[e])*hsh[e]; }
        for (int off = 32; off; off >>= 1) acc += __shfl_down(acc, off);
        if (ln == 0) cps[s] = __expf(ftanh(acc));
    }
    __syncthreads();
    if (t < 64) {
        float v = cps[t];
        for (int off = 32; off; off >>= 1) v += __shfl_xor(v, off);
        if (t == 0) {
            float tot = v;
            #pragma unroll
            for (int k = 0; k < 8; ++k) tot += psum[b*8 + k];
            invS = 1.0f / tot;
        }
    }
    __syncthreads();
    const float inv = invS;
    const unsigned short* srow = scr16 + (size_t)b*VDIM;
    float* orow = out + (size_t)b*NCOL;
    for (int i = t*2; i < VDIM; i += 512) {
        unsigned u = *reinterpret_cast<const unsigned*>(&srow[i]);
        float2 o;
        o.x = h2f((unsigned short)(u & 0xffff)) * inv;
        o.y = h2f((unsigned short)(u >> 16)) * inv;
        *reinterpret_cast<float2*>(&orow[i]) = o;
    }
    if (t >= 192) orow[VDIM + (t - 192)] = 0.0f;
    __syncthreads();
    if (t < 64) atomicAdd(&orow[y[t*64 + b]], cps[t] * inv);
}

// ===========================================================================
// fp32 fallback kernels (only if ws too small for fp16 path)
// ===========================================================================
__global__ __launch_bounds__(256) void gemm64(
    const float* A0, const float* B0, const float* bias0, float* C0, int act0,
    const float* A1, const float* B1, const float* bias1, float* C1, int act1,
    int M, int N, int K, int ldc)
{
    const float* A  = blockIdx.z ? A1 : A0;
    const float* B  = blockIdx.z ? B1 : B0;
    const float* bp = blockIdx.z ? bias1 : bias0;
    float*       C  = blockIdx.z ? C1 : C0;
    const int act   = blockIdx.z ? act1 : act0;

    __shared__ float As[32*68];
    __shared__ float Bs[32*68];

    const int n0 = blockIdx.x * 64;
    const int m0 = blockIdx.y * 64;
    const int t  = threadIdx.x;
    const int lrow = t >> 3;
    const int lc4  = t & 7;
    const int tm = (t >> 4) << 2;
    const int tn = (t & 15) << 2;

    float acc[4][4] = {};

    for (int k0 = 0; k0 < K; k0 += 32) {
        float4 a0 = *reinterpret_cast<const float4*>(A + (size_t)(m0+lrow   )*K + k0 + lc4*4);
        float4 a1 = *reinterpret_cast<const float4*>(A + (size_t)(m0+lrow+32)*K + k0 + lc4*4);
        float4 b0 = *reinterpret_cast<const float4*>(B + (size_t)(n0+lrow   )*K + k0 + lc4*4);
        float4 b1 = *reinterpret_cast<const float4*>(B + (size_t)(n0+lrow+32)*K + k0 + lc4*4);
        __syncthreads();
        const int kb = lc4*4;
        As[(kb+0)*68 + lrow]    = a0.x; As[(kb+1)*68 + lrow]    = a0.y;
        As[(kb+2)*68 + lrow]    = a0.z; As[(kb+3)*68 + lrow]    = a0.w;
        As[(kb+0)*68 + lrow+32] = a1.x; As[(kb+1)*68 + lrow+32] = a1.y;
        As[(kb+2)*68 + lrow+32] = a1.z; As[(kb+3)*68 + lrow+32] = a1.w;
        Bs[(kb+0)*68 + lrow]    = b0.x; Bs[(kb+1)*68 + lrow]    = b0.y;
        Bs[(kb+2)*68 + lrow]    = b0.z; Bs[(kb+3)*68 + lrow]    = b0.w;
        Bs[(kb+0)*68 + lrow+32] = b1.x; Bs[(kb+1)*68 + lrow+32] = b1.y;
        Bs[(kb+2)*68 + lrow+32] = b1.z; Bs[(kb+3)*68 + lrow+32] = b1.w;
        __syncthreads();
        #pragma unroll
        for (int kk = 0; kk < 32; ++kk) {
            float4 av = *reinterpret_cast<const float4*>(As + kk*68 + tm);
            float4 bv = *reinterpret_cast<const float4*>(Bs + kk*68 + tn);
            acc[0][0] += av.x*bv.x; acc[0][1] += av.x*bv.y; acc[0][2] += av.x*bv.z; acc[0][3] += av.x*bv.w;
            acc[1][0] += av.y*bv.x; acc[1][1] += av.y*bv.y; acc[1][2] += av.y*bv.z; acc[1][3] += av.y*bv.w;
            acc[2][0] += av.z*bv.x; acc[2][1] += av.z*bv.y; acc[2][2] += av.z*bv.z; acc[2][3] += av.z*bv.w;
            acc[3][0] += av.w*bv.x; acc[3][1] += av.w*bv.y; acc[3][2] += av.w*bv.z; acc[3][3] += av.w*bv.w;
        }
    }

    #pragma unroll
    for (int i = 0; i < 4; ++i) {
        float r0 = acc[i][0], r1 = acc[i][1], r2 = acc[i][2], r3 = acc[i][3];
        if (bp) { r0 += bp[n0+tn+0]; r1 += bp[n0+tn+1]; r2 += bp[n0+tn+2]; r3 += bp[n0+tn+3]; }
        if (act) { r0 = ftanh(r0); r1 = ftanh(r1); r2 = ftanh(r2); r3 = ftanh(r3); }
        float4 v = make_float4(r0, r1, r2, r3);
        *reinterpret_cast<float4*>(C + (size_t)(m0+tm+i)*ldc + (n0+tn)) = v;
    }
}

__global__ __launch_bounds__(256) void gemm_skinny(
    const float* A0, const float* B0, const float* bias0, float* C0,
    const float* A1, const float* B1, const float* bias1, float* C1,
    int N, int K, int ldc)
{
    const float* A  = blockIdx.z ? A1 : A0;
    const float* B  = blockIdx.z ? B1 : B0;
    const float* bp = blockIdx.z ? bias1 : bias0;
    float*       C  = blockIdx.z ? C1 : C0;

    __shared__ float As[16*64];
    const int n0 = blockIdx.x * 64;
    const int m0 = blockIdx.y * 16;
    const int t  = threadIdx.x;
    const int n  = t & 63;
    const int mb = t >> 6;

    float acc[4] = {};

    for (int k0 = 0; k0 < K; k0 += 64) {
        __syncthreads();
        const int row = t >> 4, c4 = t & 15;
        *reinterpret_cast<float4*>(As + row*64 + c4*4) =
            *reinterpret_cast<const float4*>(A + (size_t)(m0+row)*K + k0 + c4*4);
        __syncthreads();
        const float* Bp = B + (size_t)(n0+n)*K + k0;
        #pragma unroll
        for (int q = 0; q < 16; ++q) {
            float4 bv = *reinterpret_cast<const float4*>(Bp + q*4);
            #pragma unroll
            for (int mm = 0; mm < 4; ++mm) {
                float4 av = *reinterpret_cast<const float4*>(As + (mb + 4*mm)*64 + q*4);
                acc[mm] += av.x*bv.x + av.y*bv.y + av.z*bv.z + av.w*bv.w;
            }
        }
    }
    const float bz = bp ? bp[n0+n] : 0.0f;
    #pragma unroll
    for (int mm = 0; mm < 4; ++mm)
        C[(size_t)(m0 + mb + 4*mm)*ldc + n0 + n] = acc[mm] + bz;
}

__global__ __launch_bounds__(256) void gru_gate_k(
    const float* gi, const float* gh, const float* hold, float* hnew)
{
    int idx = blockIdx.x*256 + threadIdx.x;
    if (idx >= 64*768) return;
    int b = idx / 768, j = idx % 768;
    const float* gib = gi + (size_t)b*2304;
    const float* ghb = gh + (size_t)b*2304;
    hnew[idx] = gru_fuse(gib[j], gib[j+768], gib[j+1536],
                         ghb[j], ghb[j+768], ghb[j+1536], hold[idx]);
}

__global__ __launch_bounds__(256) void att_fused_k(
    const float* __restrict__ w1e, const float* __restrict__ w2h,
    const float* __restrict__ Vp, const float* __restrict__ enc_out,
    const float* __restrict__ emb_dec, const int* __restrict__ y,
    int step, float* __restrict__ wgt_in)
{
    const int b = blockIdx.x, t = threadIdx.x;
    __shared__ float w2s[768];
    __shared__ float vps[768];
    __shared__ float aa[64];
    for (int i = t; i < 768; i += 256) { w2s[i] = w2h[(size_t)b*768 + i]; vps[i] = Vp[i]; }
    __syncthreads();
    const int wv = t >> 6, ln = t & 63;
    for (int ss = 0; ss < 16; ++ss) {
        const int s = wv*16 + ss;
        const float* wrow = w1e + (size_t)(b*64 + s)*768;
        float acc = 0.f;
        #pragma unroll
        for (int q = 0; q < 12; ++q) {
            int e = ln + q*64;
            acc += ftanh(wrow[e] + w2s[e]) * vps[e];
        }
        for (int off = 32; off; off >>= 1) acc += __shfl_down(acc, off);
        if (ln == 0) aa[s] = acc;
    }
    __syncthreads();
    if (t < 64) {
        float v = aa[t];
        float m = v;
        for (int off = 32; off; off >>= 1) m = fmaxf(m, __shfl_xor(m, off));
        float e = __expf(v - m);
        float ssum = e;
        for (int off = 32; off; off >>= 1) ssum += __shfl_xor(ssum, off);
        aa[t] = e / ssum;
    }
    __syncthreads();
    for (int e = t; e < 512; e += 256) {
        float acc = 0.f;
        #pragma unroll 8
        for (int s = 0; s < 64; ++s)
            acc += aa[s] * enc_out[(size_t)(b*64 + s)*512 + e];
        wgt_in[(size_t)b*1280 + 768 + e] = acc;
    }
    const int tok = (step == 0) ? 0 : y[(step-1)*64 + b];
    for (int e = t; e < 768; e += 256)
        wgt_in[(size_t)b*1280 + e] = emb_dec[(size_t)tok*768 + e];
}

__global__ __launch_bounds__(256) void smax2_k(
    const float* __restrict__ scratch, const float* __restrict__ scb,
    const float* __restrict__ h1, const int* __restrict__ y, float* __restrict__ out)
{
    const int b = blockIdx.x, t = threadIdx.x;
    __shared__ float hsh[768];
    __shared__ float cps[64];
    __shared__ float red[4];
    for (int i = t; i < 768; i += 256) hsh[i] = h1[(size_t)b*768 + i];
    __syncthreads();
    const int wv = t >> 6, ln = t & 63;
    for (int ss = 0; ss < 16; ++ss) {
        const int s = wv*16 + ss;
        const float* sp = scb + (size_t)(b*64 + s)*768;
        float acc = 0.f;
        #pragma unroll
        for (int q = 0; q < 12; ++q) { int e = ln + q*64; acc += sp[e]*hsh[e]; }
        for (int off = 32; off; off >>= 1) acc += __shfl_down(acc, off);
        if (ln == 0) cps[s] = ftanh(acc);
    }
    __syncthreads();

    const float* row = scratch + (size_t)b*VDIM;
    float m = -1e30f;
    for (int i = t; i < VDIM; i += 256) m = fmaxf(m, row[i]);
    for (int off = 32; off; off >>= 1) m = fmaxf(m, __shfl_xor(m, off));
    if (ln == 0) red[wv] = m;
    __syncthreads();
    const float bm = fmaxf(fmaxf(red[0], red[1]), fmaxf(red[2], red[3]));
    __syncthreads();

    float s = 0.f;
    for (int i = t; i < VDIM; i += 256) s += __expf(row[i] - bm);
    if (t < 64) s += __expf(cps[t] - bm);
    for (int off = 32; off; off >>= 1) s += __shfl_xor(s, off);
    if (ln == 0) red[wv] = s;
    __syncthreads();
    const float inv = 1.0f / (red[0] + red[1] + red[2] + red[3]);

    float* orow = out + (size_t)b*NCOL;
    for (int i = t; i < VDIM; i += 256) orow[i] = __expf(row[i] - bm) * inv;
    if (t >= 192) orow[VDIM + (t - 192)] = 0.0f;
    __syncthreads();
    if (t < 64) atomicAdd(&orow[y[t*64 + b]], __expf(cps[t] - bm) * inv);
}

// ===========================================================================
extern "C" void kernel_launch(void* const* d_in, const int* in_sizes, int n_in,
                              void* d_out, int out_size, void* d_ws, size_t ws_size,
                              hipStream_t stream)
{
    (void)in_sizes; (void)n_in; (void)out_size;
    const int*   inp       = (const int*)  d_in[0];
    const int*   y         = (const int*)  d_in[1];
    const float* emb_enc   = (const float*)d_in[2];
    const float* enc_Wih   = (const float*)d_in[3];
    const float* enc_Whh   = (const float*)d_in[4];
    const float* enc_bih   = (const float*)d_in[5];
    const float* enc_bhh   = (const float*)d_in[6];
    const float* out_enc_W = (const float*)d_in[7];
    const float* emb_dec   = (const float*)d_in[8];
    const float* dec_Wih   = (const float*)d_in[9];
    const float* dec_Whh   = (const float*)d_in[10];
    const float* dec_bih   = (const float*)d_in[11];
    const float* dec_bhh   = (const float*)d_in[12];
    const float* out_b     = (const float*)d_in[13];
    const float* W1        = (const float*)d_in[14];
    const float* l2_W      = (const float*)d_in[15];
    const float* l2_b      = (const float*)d_in[16];
    const float* l3_W      = (const float*)d_in[17];
    const float* l3_b      = (const float*)d_in[18];
    const float* Vp        = (const float*)d_in[19];
    float* out = (float*)d_out;
    float* ws  = (float*)d_ws;

    size_t off = 0;
    auto alloc = [&](size_t n) { float* p = ws + off; off += (n + 63) & ~(size_t)63; return p; };
    // ---- base region (also serves fp32 fallback) ----
    float* x0     = alloc(4096*512);   // also W03f temp (spans x0+x1 post-encoder)
    float* x1     = alloc(4096*512);
    float* x2     = alloc(4096*512);   // enc_out fp32, rows b*64+s
    float* giF    = alloc(4096*768);   // post-encoder: w1e16 + enc16 (ushort)
    float* giB    = alloc(4096*768);   // post-encoder: scb16 (ushort)
    float* w1e    = alloc(4096*768);
    float* scb    = alloc(4096*768);
    float* W1T    = alloc(768*512);
    float* hfin   = alloc(128*512);
    float* hdecA  = alloc(128*768);
    float* hdecB  = alloc(128*768);
    float* w2h    = alloc(64*768);
    float* wgt_in = alloc(64*1280);
    float* wgt    = alloc(64*768);     // fallback only
    float* gh0buf = alloc(64*2304);
    float* gh1buf = alloc(64*2304);
    float* gi0f   = alloc(64*2304);    // fallback only
    float* gi1f   = alloc(64*2304);    // fallback only
    float* b03    = alloc(2304);
    float* psum   = alloc(512);        // 64 rows x 8 slots
    float* scratch= alloc(64*VDIM);    // fp32 (fallback) / ushort scr16 (fp16 path) / l3T temp
    auto ualloc = [&](size_t nush) { return (unsigned short*)alloc((nush + 1) / 2); };
    unsigned short* encWhhH = ualloc(2*2*768*256);
    // ---- fp16 region ----
    unsigned short* embH    = ualloc((size_t)VDIM*768);
    unsigned short* encWihH = ualloc(2*2*768*512);
    unsigned short* encWihL = ualloc(2*2*768*512);
    unsigned short* W1TH    = ualloc(768*512);
    unsigned short* W1TL    = ualloc(768*512);
    unsigned short* oeH     = ualloc(768*512);
    unsigned short* oeL     = ualloc(768*512);
    unsigned short* l2H     = ualloc(768*768);
    unsigned short* l3TH    = ualloc(1280*768);
    unsigned short* l3TL    = ualloc(1280*768);
    unsigned short* dWihH   = ualloc((size_t)2*2304*768);
    unsigned short* dWhhH   = ualloc((size_t)2*2304*768);
    unsigned short* W03H    = ualloc((size_t)2304*1280);
    const bool use_mfma = ws_size >= off * sizeof(float);

    const size_t L1W = (size_t)2304*768;
    float* l3T  = scratch;             // 1280x768 temp (pre-decoder)
    float* W03f = x0;                  // 2304x1280 temp (post-encoder)
    unsigned short* scr16 = (unsigned short*)scratch;
    unsigned short* w1e16 = (unsigned short*)giF;                  // 3.146M ush
    unsigned short* enc16 = (unsigned short*)(giF + 1600*1024);    // 2.097M ush
    unsigned short* scb16 = (unsigned short*)giB;                  // 3.146M ush

    // ---- common setup ----
    embed_k<<<2048, 256, 0, stream>>>(inp, emb_enc, x0);
    transpose2_k<<<(512*768 + 255)/256, 256, 0, stream>>>(W1, W1T, 512, 768);
    conv16_k<<<768, 256, 0, stream>>>(enc_Whh, encWhhH, 2*2*768*256/4);

    if (use_mfma) {
        convhl_k<<<1536, 256, 0, stream>>>(enc_Wih, encWihH, encWihL, 2*2*768*512/4);
        convhl_k<<<384, 256, 0, stream>>>(W1T, W1TH, W1TL, 768*512/4);
        convhl_k<<<384, 256, 0, stream>>>(out_enc_W, oeH, oeL, 768*512/4);
        conv16_k<<<576, 256, 0, stream>>>(l2_W, l2H, 768*768/4);
        conv16_k<<<3456, 256, 0, stream>>>(dec_Wih, dWihH, (int)(L1W*2/4));
        conv16_k<<<3456, 256, 0, stream>>>(dec_Whh, dWhhH, (int)(L1W*2/4));
        conv16_k<<<24000, 256, 0, stream>>>(emb_dec, embH, (int)((size_t)VDIM*768/4));
        transpose2_k<<<(768*1280 + 255)/256, 256, 0, stream>>>(l3_W, l3T, 768, 1280);
        convhl_k<<<960, 256, 0, stream>>>(l3T, l3TH, l3TL, 1280*768/4);
        b03_k<<<9, 256, 0, stream>>>(dec_Wih, dec_bih, l3_b, b03);

        // ---- encoder ----
        for (int l = 0; l < 2; ++l) {
            const float* xin  = l ? x1 : x0;
            float*       xout = l ? x2 : x1;
            const size_t wo = (size_t)l*2*768*512;
            mfma_gemm<<<dim3(6, 64, 2), 256, 0, stream>>>(
                xin, encWihH + wo,           encWihL + wo,           enc_bih + l*2*768,       giF, 768, 768, 0,
                xin, encWihH + wo + 768*512, encWihL + wo + 768*512, enc_bih + l*2*768 + 768, giB, 768, 768, 0,
                512);
            enc_layer4_k<<<dim3(16, 2), 256, 0, stream>>>(
                giF, giB, encWhhH + (size_t)l*2*768*256, enc_bhh + (size_t)l*2*768,
                xout, hfin + (size_t)l*64*512, l);
        }

        // W03 = Wih0 @ l3_W
        mfma_gemm<<<dim3(10, 36, 1), 256, 0, stream>>>(
            dec_Wih, l3TH, l3TL, nullptr, W03f, 1280, 1280, 0,
            nullptr, nullptr, nullptr, nullptr, nullptr, 0, 0, 0,
            768);
        conv16_k<<<2880, 256, 0, stream>>>(W03f, W03H, 2304*1280/4);

        // decoder initial hidden (128,512)@out_enc_W^T
        mfma_gemm<<<dim3(6, 2, 1), 256, 0, stream>>>(
            hfin, oeH, oeL, nullptr, hdecA, 768, 768, 0,
            nullptr, nullptr, nullptr, nullptr, nullptr, 0, 0, 0,
            512);

        // w1e = enc_out@W1 ; scb = tanh(enc_out@out_enc_W^T)
        mfma_gemm<<<dim3(6, 64, 2), 256, 0, stream>>>(
            x2, W1TH, W1TL, nullptr, w1e, 768, 768, 0,
            x2, oeH,  oeL,  nullptr, scb, 768, 768, 1,
            512);

        // fp16 caches: w1e16, scb16, enc16 (giF/giB now free)
        conv16_k<<<3072, 256, 0, stream>>>(w1e, w1e16, 4096*768/4);
        conv16_k<<<3072, 256, 0, stream>>>(scb, scb16, 4096*768/4);
        conv16_k<<<2048, 256, 0, stream>>>(x2, enc16, 4096*512/4);

        // bootstrap: w2h = h1@l2 ; gh0 = h0@Whh0 ; gh1 = h1@Whh1
        mfma_gemm<<<dim3(6, 1, 1), 256, 0, stream>>>(
            hdecA + 64*768, l2H, nullptr, l2_b, w2h, 768, 768, 0,
            nullptr, nullptr, nullptr, nullptr, nullptr, 0, 0, 0,
            768);
        gru_mfma_k<<<dim3(48, 1, 2), 256, 0, stream>>>(
            hdecA,          dWhhH,       nullptr, dec_bhh,        nullptr, nullptr, gh0buf, 0, 768,
            hdecA + 64*768, dWhhH + L1W, nullptr, dec_bhh + 2304, nullptr, nullptr, gh1buf, 0, 768);

        // ---- decoder: 5 launches per step ----
        for (int st = 0; st < TSL; ++st) {
            float* h0c = (st & 1) ? hdecB : hdecA;
            float* h0n = (st & 1) ? hdecA : hdecB;
            float* h1c = h0c + 64*768;
            float* h1n = h0n + 64*768;
            float* orow = out + (size_t)st*BSZ*NCOL;

            att_fused16_k<<<64, 256, 0, stream>>>(
                w1e16, w2h, Vp, enc16, emb_dec, y, st, wgt_in, psum);

            // gi0 = wgt_in@W03^T + b03, fused gate0 -> h0n
            gru_mfma_k<<<dim3(48, 1, 1), 256, 0, stream>>>(
                wgt_in, W03H, nullptr, b03, gh0buf, h0c, h0n, 1, 1280,
                wgt_in, W03H, nullptr, b03, gh0buf, h0c, h0n, 1, 1280);

            // gi1+gate1 -> h1n  ||  gh0' = h0n@Whh0 (next step)
            gru_mfma_k<<<dim3(48, 1, 2), 256, 0, stream>>>(
                h0n, dWihH + L1W, nullptr, dec_bih + 2304, gh1buf, h1c, h1n, 1, 768,
                h0n, dWhhH,       nullptr, dec_bhh,        nullptr, nullptr, gh0buf, 0, 768);

            // vocab exp-logits -> scr16 + psum  ||  w2h'(next)  ||  gh1'(next)
            vocab3_k<<<dim3(250, 1, 3), 256, 0, stream>>>(
                h1n,
                embH, out_b, scr16, psum,
                l2H, l2_b, w2h,
                dWhhH + L1W, dec_bhh + 2304, gh1buf);

            smax_lite_k<<<64, 256, 0, stream>>>(scr16, scb16, h1n, y, psum, orow);
        }
    } else {
        // ================= fp32 fallback =================
        for (int l = 0; l < 2; ++l) {
            const float* xin  = l ? x1 : x0;
            float*       xout = l ? x2 : x1;
            const float* Wih = enc_Wih + (size_t)l*2*768*512;
            const float* bih = enc_bih + (size_t)l*2*768;
            gemm64<<<dim3(12, 64, 2), 256, 0, stream>>>(
                xin, Wih,           bih,       giF, 0,
                xin, Wih + 768*512, bih + 768, giB, 0,
                4096, 768, 512, 768);
            enc_layer4_k<<<dim3(16, 2), 256, 0, stream>>>(
                giF, giB, encWhhH + (size_t)l*2*768*256, enc_bhh + (size_t)l*2*768,
                xout, hfin + (size_t)l*64*512, l);
        }
        gemm64<<<dim3(12, 2, 1), 256, 0, stream>>>(
            hfin, out_enc_W, nullptr, hdecA, 0,
            hfin, out_enc_W, nullptr, hdecA, 0,
            128, 768, 512, 768);
        gemm64<<<dim3(12, 64, 2), 256, 0, stream>>>(
            x2, W1T,       nullptr, w1e, 0,
            x2, out_enc_W, nullptr, scb, 1,
            4096, 768, 512, 768);
        gemm_skinny<<<dim3(12, 4, 1), 256, 0, stream>>>(
            hdecA + 64*768, l2_W, l2_b, w2h,
            hdecA + 64*768, l2_W, l2_b, w2h,
            768, 768, 768);

        for (int st = 0; st < TSL; ++st) {
            float* h0c = (st & 1) ? hdecB : hdecA;
            float* h0n = (st & 1) ? hdecA : hdecB;
            float* h1c = h0c + 64*768;
            float* h1n = h0n + 64*768;
            float* orow = out + (size_t)st*BSZ*NCOL;

            att_fused_k<<<64, 256, 0, stream>>>(w1e, w2h, Vp, x2, emb_dec, y, st, wgt_in);
            gemm_skinny<<<dim3(12, 4, 1), 256, 0, stream>>>(
                wgt_in, l3_W, l3_b, wgt,
                wgt_in, l3_W, l3_b, wgt,
                768, 1280, 768);
            gemm_skinny<<<dim3(36, 4, 2), 256, 0, stream>>>(
                wgt, dec_Wih, dec_bih, gi0f,
                h0c, dec_Whh, dec_bhh, gh0buf,
                2304, 768, 2304);
            gru_gate_k<<<192, 256, 0, stream>>>(gi0f, gh0buf, h0c, h0n);
            gemm_skinny<<<dim3(36, 4, 2), 256, 0, stream>>>(
                h0n, dec_Wih + L1W, dec_bih + 2304, gi1f,
                h1c, dec_Whh + L1W, dec_bhh + 2304, gh1buf,
                2304, 768, 2304);
            gru_gate_k<<<192, 256, 0, stream>>>(gi1f, gh1buf, h1c, h1n);
            gemm_skinny<<<dim3(12, 4, 1), 256, 0, stream>>>(
                h1n, l2_W, l2_b, w2h,
                h1n, l2_W, l2_b, w2h,
                768, 768, 768);
            gemm64<<<dim3(500, 1, 1), 256, 0, stream>>>(
                h1n, emb_dec, out_b, scratch, 0,
                h1n, emb_dec, out_b, scratch, 0,
                64, VDIM, 768, VDIM);
            smax2_k<<<64, 256, 0, stream>>>(scratch, scb, h1n, y, orow);
        }
    }
}

// Round 6
// 7943.069 us; speedup vs baseline: 2.6039x; 1.1943x over previous
//
#include <hip/hip_runtime.h>

#define SLEN 64
#define BSZ  64
#define TSL  48
#define VDIM 32000
#define NCOL 32064   // VDIM + SLEN

typedef __attribute__((ext_vector_type(8))) _Float16 f16x8;
typedef __attribute__((ext_vector_type(4))) _Float16 f16x4;
typedef __attribute__((ext_vector_type(4))) float f32x4;

__device__ __forceinline__ float fsig(float x){
    return 1.0f/(1.0f + __expf(-x));
}
__device__ __forceinline__ float ftanh(float x){
    float e = __expf(2.0f*x);
    return 1.0f - 2.0f/(e + 1.0f);
}
__device__ __forceinline__ unsigned short f2h(float x){
    union { _Float16 f; unsigned short u; } c; c.f = (_Float16)x; return c.u;
}
__device__ __forceinline__ float h2f(unsigned short u){
    union { _Float16 f; unsigned short u; } c; c.u = u; return (float)c.f;
}
__device__ __forceinline__ unsigned short f2h_hi(float x, float& rem){
    _Float16 h = (_Float16)x;
    rem = x - (float)h;
    union { _Float16 f; unsigned short u; } c; c.f = h; return c.u;
}
__device__ __forceinline__ float gru_fuse(float gir,float giz,float gin,
                                          float ghr,float ghz,float ghn,float h){
    float r = fsig(gir + ghr);
    float z = fsig(giz + ghz);
    float n = ftanh(gin + r*ghn);
    return (1.0f - z)*n + z*h;
}

// ===========================================================================
// MFMA GEMM (2 param sets): C = A @ B^T + bias, optional tanh.
// A fp32 (lda=K) -> fp16 hi/lo inline while staging LDS. B fp16 hi(+lo).
// grid = (ceil(maxN/128), M/64, nz).
// ===========================================================================
__global__ __launch_bounds__(256) void mfma_gemm(
    const float* A0, const unsigned short* Bh0, const unsigned short* Bl0,
    const float* bias0, float* C0, int N0, int ldc0, int act0,
    const float* A1, const unsigned short* Bh1, const unsigned short* Bl1,
    const float* bias1, float* C1, int N1, int ldc1, int act1,
    int K)
{
    const float* A; const unsigned short* Bh; const unsigned short* Bl;
    const float* bias; float* C; int N, ldc, act;
    if (blockIdx.z == 0) { A=A0; Bh=Bh0; Bl=Bl0; bias=bias0; C=C0; N=N0; ldc=ldc0; act=act0; }
    else                 { A=A1; Bh=Bh1; Bl=Bl1; bias=bias1; C=C1; N=N1; ldc=ldc1; act=act1; }

    const int n0 = blockIdx.x * 128;
    if (n0 >= N) return;
    const int m0 = blockIdx.y * 64;

    __shared__ __align__(16) unsigned short As[2][64][72];
    __shared__ __align__(16) unsigned short Bs[2][128][72];

    const int t  = threadIdx.x;
    const int wv = t >> 6, ln = t & 63;
    const bool has_lo = (Bl != nullptr);

    f32x4 acc[4][2];
    #pragma unroll
    for (int i = 0; i < 4; ++i)
        #pragma unroll
        for (int j = 0; j < 2; ++j) acc[i][j] = (f32x4){0.f,0.f,0.f,0.f};

    for (int k0 = 0; k0 < K; k0 += 64) {
        __syncthreads();
        #pragma unroll
        for (int it = 0; it < 4; ++it) {
            int idx = t + it*256;
            int r = idx >> 4, c4 = (idx & 15) * 4;
            float4 v = *reinterpret_cast<const float4*>(A + (size_t)(m0+r)*K + k0 + c4);
            ushort4 h, l; float rm;
            h.x = f2h_hi(v.x, rm); l.x = f2h(rm);
            h.y = f2h_hi(v.y, rm); l.y = f2h(rm);
            h.z = f2h_hi(v.z, rm); l.z = f2h(rm);
            h.w = f2h_hi(v.w, rm); l.w = f2h(rm);
            *reinterpret_cast<ushort4*>(&As[0][r][c4]) = h;
            *reinterpret_cast<ushort4*>(&As[1][r][c4]) = l;
        }
        #pragma unroll
        for (int it = 0; it < 4; ++it) {
            int idx = t + it*256;
            int r = idx >> 3, c8 = (idx & 7) * 8;
            *reinterpret_cast<uint4*>(&Bs[0][r][c8]) =
                *reinterpret_cast<const uint4*>(&Bh[(size_t)(n0+r)*K + k0 + c8]);
        }
        if (has_lo) {
            #pragma unroll
            for (int it = 0; it < 4; ++it) {
                int idx = t + it*256;
                int r = idx >> 3, c8 = (idx & 7) * 8;
                *reinterpret_cast<uint4*>(&Bs[1][r][c8]) =
                    *reinterpret_cast<const uint4*>(&Bl[(size_t)(n0+r)*K + k0 + c8]);
            }
        }
        __syncthreads();
        #pragma unroll
        for (int ks = 0; ks < 2; ++ks) {
            const int ko = ks*32 + (ln >> 4)*8;
            f16x8 ah[4], al[4], bh[2], bl[2];
            #pragma unroll
            for (int m = 0; m < 4; ++m) {
                ah[m] = *reinterpret_cast<const f16x8*>(&As[0][m*16 + (ln&15)][ko]);
                al[m] = *reinterpret_cast<const f16x8*>(&As[1][m*16 + (ln&15)][ko]);
            }
            #pragma unroll
            for (int n = 0; n < 2; ++n) {
                bh[n] = *reinterpret_cast<const f16x8*>(&Bs[0][wv*32 + n*16 + (ln&15)][ko]);
                if (has_lo)
                    bl[n] = *reinterpret_cast<const f16x8*>(&Bs[1][wv*32 + n*16 + (ln&15)][ko]);
            }
            #pragma unroll
            for (int m = 0; m < 4; ++m)
                #pragma unroll
                for (int n = 0; n < 2; ++n) {
                    acc[m][n] = __builtin_amdgcn_mfma_f32_16x16x32_f16(ah[m], bh[n], acc[m][n], 0,0,0);
                    acc[m][n] = __builtin_amdgcn_mfma_f32_16x16x32_f16(al[m], bh[n], acc[m][n], 0,0,0);
                    if (has_lo)
                        acc[m][n] = __builtin_amdgcn_mfma_f32_16x16x32_f16(ah[m], bl[n], acc[m][n], 0,0,0);
                }
        }
    }
    #pragma unroll
    for (int m = 0; m < 4; ++m) {
        #pragma unroll
        for (int n = 0; n < 2; ++n) {
            const int col = n0 + wv*32 + n*16 + (ln & 15);
            const float bz = bias ? bias[col] : 0.0f;
            #pragma unroll
            for (int j = 0; j < 4; ++j) {
                const int row = m0 + m*16 + (ln >> 4)*4 + j;
                float v = acc[m][n][j] + bz;
                if (act) v = ftanh(v);
                C[(size_t)row*ldc + col] = v;
            }
        }
    }
}

// ===========================================================================
// Barrier-free MFMA GRU-GEMM. psz!=nullptr: block (z==0,x==0) zeroes psum[512].
// ===========================================================================
__global__ __launch_bounds__(256) void gru_mfma_k(
    const float* A0, const unsigned short* BH0, const unsigned short* BL0,
    const float* bias0, const float* gh0, const float* hold0, float* out0,
    int gate0, int K0,
    const float* A1, const unsigned short* BH1, const unsigned short* BL1,
    const float* bias1, const float* gh1, const float* hold1, float* out1,
    int gate1, int K1, float* psz)
{
    const float* A; const unsigned short* BH; const unsigned short* BL;
    const float* bias; const float* gh; const float* hold; float* outp; int gate, K;
    if (blockIdx.z == 0) { A=A0; BH=BH0; BL=BL0; bias=bias0; gh=gh0; hold=hold0; outp=out0; gate=gate0; K=K0; }
    else                 { A=A1; BH=BH1; BL=BL1; bias=bias1; gh=gh1; hold=hold1; outp=out1; gate=gate1; K=K1; }

    const int t = threadIdx.x;
    if (psz && blockIdx.z == 0 && blockIdx.x == 0) { psz[t] = 0.f; psz[t+256] = 0.f; }
    const int wv = t >> 6, ln = t & 63;
    const int colg16 = blockIdx.x * 16;
    const int arow = wv*16 + (ln & 15);
    const int kof  = (ln >> 4) * 8;
    const bool has_lo = (BL != nullptr);

    f32x4 acc[3];
    #pragma unroll
    for (int g = 0; g < 3; ++g) acc[g] = (f32x4){0.f,0.f,0.f,0.f};

    const float* Ar = A + (size_t)arow*K + kof;
    const int brow_n = colg16 + (ln & 15);

    #pragma unroll 2
    for (int k0 = 0; k0 < K; k0 += 32) {
        float4 a0 = *reinterpret_cast<const float4*>(Ar + k0);
        float4 a1 = *reinterpret_cast<const float4*>(Ar + k0 + 4);
        f16x8 ah, al;
        {
            float av0=a0.x, av1=a0.y, av2=a0.z, av3=a0.w;
            float av4=a1.x, av5=a1.y, av6=a1.z, av7=a1.w;
            _Float16 hh;
            hh=(_Float16)av0; ah[0]=hh; al[0]=(_Float16)(av0-(float)hh);
            hh=(_Float16)av1; ah[1]=hh; al[1]=(_Float16)(av1-(float)hh);
            hh=(_Float16)av2; ah[2]=hh; al[2]=(_Float16)(av2-(float)hh);
            hh=(_Float16)av3; ah[3]=hh; al[3]=(_Float16)(av3-(float)hh);
            hh=(_Float16)av4; ah[4]=hh; al[4]=(_Float16)(av4-(float)hh);
            hh=(_Float16)av5; ah[5]=hh; al[5]=(_Float16)(av5-(float)hh);
            hh=(_Float16)av6; ah[6]=hh; al[6]=(_Float16)(av6-(float)hh);
            hh=(_Float16)av7; ah[7]=hh; al[7]=(_Float16)(av7-(float)hh);
        }
        #pragma unroll
        for (int g = 0; g < 3; ++g) {
            const size_t boff = (size_t)(g*768 + brow_n)*K + k0 + kof;
            f16x8 bh = *reinterpret_cast<const f16x8*>(&BH[boff]);
            acc[g] = __builtin_amdgcn_mfma_f32_16x16x32_f16(ah, bh, acc[g], 0,0,0);
            acc[g] = __builtin_amdgcn_mfma_f32_16x16x32_f16(al, bh, acc[g], 0,0,0);
            if (has_lo) {
                f16x8 bl = *reinterpret_cast<const f16x8*>(&BL[boff]);
                acc[g] = __builtin_amdgcn_mfma_f32_16x16x32_f16(ah, bl, acc[g], 0,0,0);
            }
        }
    }

    const int colg = colg16 + (ln & 15);
    const int rb   = wv*16 + (ln >> 4)*4;
    if (gate) {
        const float br = bias[colg], bz = bias[768+colg], bn = bias[1536+colg];
        #pragma unroll
        for (int jj = 0; jj < 4; ++jj) {
            const int row = rb + jj;
            float ghr = gh[(size_t)row*2304 + colg];
            float ghz = gh[(size_t)row*2304 + 768 + colg];
            float ghn = gh[(size_t)row*2304 + 1536 + colg];
            float h   = hold[(size_t)row*768 + colg];
            outp[(size_t)row*768 + colg] =
                gru_fuse(acc[0][jj]+br, acc[1][jj]+bz, acc[2][jj]+bn, ghr, ghz, ghn, h);
        }
    } else {
        #pragma unroll
        for (int g = 0; g < 3; ++g) {
            const float bz = bias[g*768 + colg];
            #pragma unroll
            for (int jj = 0; jj < 4; ++jj)
                outp[(size_t)(rb+jj)*2304 + g*768 + colg] = acc[g][jj] + bz;
        }
    }
}

// ===========================================================================
// Vocab quad launch, K=768, A=h1n. grid (250, 1, 4).
// z=0: exp(logit)->fp16 scratch (LDS-staged coalesced write) + striped psum.
// z=1: w2h' (x<6). z=2: gh1' (x<18).
// z=3 (x<64): copy-score dots cpt[b][s] = tanh(scb16[b,s,:]·h1n[b,:]).
// ===========================================================================
__global__ __launch_bounds__(256) void vocab4_k(
    const float* __restrict__ A,
    const unsigned short* __restrict__ B0, const float* __restrict__ bias0,
    unsigned short* __restrict__ scr16, float* __restrict__ psum,
    const unsigned short* __restrict__ B1, const float* __restrict__ bias1, float* __restrict__ C1,
    const unsigned short* __restrict__ B2, const float* __restrict__ bias2, float* __restrict__ C2,
    const unsigned short* __restrict__ scb16, float* __restrict__ cpt)
{
    const int z = blockIdx.z;
    const int t = threadIdx.x, wv = t >> 6, ln = t & 63;

    if (z == 3) {
        const int b = blockIdx.x;
        if (b >= 64) return;
        __shared__ float hsh[768];
        for (int i = t; i < 768; i += 256) hsh[i] = A[(size_t)b*768 + i];
        __syncthreads();
        for (int ss = 0; ss < 16; ++ss) {
            const int s = wv*16 + ss;
            const unsigned short* sp = scb16 + (size_t)(b*64 + s)*768;
            float acc = 0.f;
            #pragma unroll
            for (int q = 0; q < 6; ++q) {
                int e = ln*2 + q*128;
                unsigned u = *reinterpret_cast<const unsigned*>(&sp[e]);
                acc += h2f((unsigned short)(u & 0xffff))*hsh[e]
                     + h2f((unsigned short)(u >> 16))*hsh[e+1];
            }
            for (int off = 32; off; off >>= 1) acc += __shfl_down(acc, off);
            if (ln == 0) cpt[b*64 + s] = ftanh(acc);
        }
        return;
    }

    const unsigned short* Bh; const float* bias; int N, ldc;
    if (z == 0)      { Bh=B0; bias=bias0; N=VDIM; ldc=VDIM; }
    else if (z == 1) { Bh=B1; bias=bias1; N=768;  ldc=768; }
    else             { Bh=B2; bias=bias2; N=2304; ldc=2304; }
    const int n0 = blockIdx.x * 128;
    if (n0 >= N) return;

    __shared__ __align__(16) unsigned short As[2][64][72];
    __shared__ __align__(16) unsigned short Bs[128][72];
    __shared__ float rs[4][64];

    f32x4 acc[4][2];
    #pragma unroll
    for (int i = 0; i < 4; ++i)
        #pragma unroll
        for (int j = 0; j < 2; ++j) acc[i][j] = (f32x4){0.f,0.f,0.f,0.f};

    for (int k0 = 0; k0 < 768; k0 += 64) {
        __syncthreads();
        #pragma unroll
        for (int it = 0; it < 4; ++it) {
            int idx = t + it*256;
            int r = idx >> 4, c4 = (idx & 15) * 4;
            float4 v = *reinterpret_cast<const float4*>(A + (size_t)r*768 + k0 + c4);
            ushort4 h, l; float rm;
            h.x = f2h_hi(v.x, rm); l.x = f2h(rm);
            h.y = f2h_hi(v.y, rm); l.y = f2h(rm);
            h.z = f2h_hi(v.z, rm); l.z = f2h(rm);
            h.w = f2h_hi(v.w, rm); l.w = f2h(rm);
            *reinterpret_cast<ushort4*>(&As[0][r][c4]) = h;
            *reinterpret_cast<ushort4*>(&As[1][r][c4]) = l;
        }
        #pragma unroll
        for (int it = 0; it < 4; ++it) {
            int idx = t + it*256;
            int r = idx >> 3, c8 = (idx & 7) * 8;
            *reinterpret_cast<uint4*>(&Bs[r][c8]) =
                *reinterpret_cast<const uint4*>(&Bh[(size_t)(n0+r)*768 + k0 + c8]);
        }
        __syncthreads();
        #pragma unroll
        for (int ks = 0; ks < 2; ++ks) {
            const int ko = ks*32 + (ln >> 4)*8;
            f16x8 ah[4], al[4], bh[2];
            #pragma unroll
            for (int m = 0; m < 4; ++m) {
                ah[m] = *reinterpret_cast<const f16x8*>(&As[0][m*16 + (ln&15)][ko]);
                al[m] = *reinterpret_cast<const f16x8*>(&As[1][m*16 + (ln&15)][ko]);
            }
            #pragma unroll
            for (int n = 0; n < 2; ++n)
                bh[n] = *reinterpret_cast<const f16x8*>(&Bs[wv*32 + n*16 + (ln&15)][ko]);
            #pragma unroll
            for (int m = 0; m < 4; ++m)
                #pragma unroll
                for (int n = 0; n < 2; ++n) {
                    acc[m][n] = __builtin_amdgcn_mfma_f32_16x16x32_f16(ah[m], bh[n], acc[m][n], 0,0,0);
                    acc[m][n] = __builtin_amdgcn_mfma_f32_16x16x32_f16(al[m], bh[n], acc[m][n], 0,0,0);
                }
        }
    }

    if (z == 0) {
        // stage exp values in LDS (aliasing As), coalesced store after barrier
        __syncthreads();
        unsigned short (*Cs)[128] = reinterpret_cast<unsigned short(*)[128]>(&As[0][0][0]);
        float sums[4][4];
        #pragma unroll
        for (int m = 0; m < 4; ++m)
            #pragma unroll
            for (int j = 0; j < 4; ++j) sums[m][j] = 0.f;
        #pragma unroll
        for (int m = 0; m < 4; ++m) {
            #pragma unroll
            for (int n = 0; n < 2; ++n) {
                const int cl = wv*32 + n*16 + (ln & 15);
                const float bz = bias[n0 + cl];
                #pragma unroll
                for (int j = 0; j < 4; ++j) {
                    const int row = m*16 + (ln >> 4)*4 + j;
                    float e = __expf(acc[m][n][j] + bz);
                    Cs[row][cl] = f2h(e);
                    sums[m][j] += e;
                }
            }
        }
        #pragma unroll
        for (int m = 0; m < 4; ++m)
            #pragma unroll
            for (int j = 0; j < 4; ++j) {
                float v = sums[m][j];
                v += __shfl_xor(v, 1); v += __shfl_xor(v, 2);
                v += __shfl_xor(v, 4); v += __shfl_xor(v, 8);
                if ((ln & 15) == 0) rs[wv][m*16 + (ln >> 4)*4 + j] = v;
            }
        __syncthreads();
        #pragma unroll
        for (int it = 0; it < 4; ++it) {
            int jj = t + it*256;             // 1024 uint4s = 64 rows x 16
            int row = jj >> 4, c8 = (jj & 15) * 8;
            *reinterpret_cast<uint4*>(&scr16[(size_t)row*VDIM + n0 + c8]) =
                *reinterpret_cast<const uint4*>(&Cs[row][c8]);
        }
        if (t < 64)
            atomicAdd(&psum[t*8 + (blockIdx.x & 7)], rs[0][t]+rs[1][t]+rs[2][t]+rs[3][t]);
    } else {
        float* C = (z == 1) ? C1 : C2;
        #pragma unroll
        for (int m = 0; m < 4; ++m) {
            #pragma unroll
            for (int n = 0; n < 2; ++n) {
                const int col = n0 + wv*32 + n*16 + (ln & 15);
                const float bz = bias[col];
                #pragma unroll
                for (int j = 0; j < 4; ++j) {
                    const int row = m*16 + (ln >> 4)*4 + j;
                    C[(size_t)row*ldc + col] = acc[m][n][j] + bz;
                }
            }
        }
    }
}

// ===========================================================================
// Merged attention(step) [y=0] + softmax-finalize(step-1) [y=1]. grid (64,2).
// ===========================================================================
__global__ __launch_bounds__(256) void attsm_k(
    const unsigned short* __restrict__ w1e16, const float* __restrict__ w2h,
    const float* __restrict__ Vp, const unsigned short* __restrict__ enc16,
    const float* __restrict__ emb_dec, const int* __restrict__ y,
    int step, int do_att, int do_sm,
    float* __restrict__ wgt_in,
    const unsigned short* __restrict__ scr16, const float* __restrict__ cpt,
    const float* __restrict__ psum, float* __restrict__ outprev)
{
    const int b = blockIdx.x, t = threadIdx.x;
    const int wv = t >> 6, ln = t & 63;
    if (blockIdx.y == 0) {
        if (!do_att) return;
        __shared__ float w2s[768];
        __shared__ float vps[768];
        __shared__ float aa[64];
        for (int i = t; i < 768; i += 256) { w2s[i] = w2h[(size_t)b*768 + i]; vps[i] = Vp[i]; }
        __syncthreads();
        for (int ss = 0; ss < 16; ++ss) {
            const int s = wv*16 + ss;
            const unsigned short* wrow = w1e16 + (size_t)(b*64 + s)*768;
            float acc = 0.f;
            #pragma unroll
            for (int q = 0; q < 6; ++q) {
                int e = ln*2 + q*128;
                unsigned u = *reinterpret_cast<const unsigned*>(&wrow[e]);
                acc += ftanh(h2f((unsigned short)(u & 0xffff)) + w2s[e])*vps[e]
                     + ftanh(h2f((unsigned short)(u >> 16))   + w2s[e+1])*vps[e+1];
            }
            for (int off = 32; off; off >>= 1) acc += __shfl_down(acc, off);
            if (ln == 0) aa[s] = acc;
        }
        __syncthreads();
        if (t < 64) {
            float v = aa[t];
            float m = v;
            for (int off = 32; off; off >>= 1) m = fmaxf(m, __shfl_xor(m, off));
            float e = __expf(v - m);
            float ssum = e;
            for (int off = 32; off; off >>= 1) ssum += __shfl_xor(ssum, off);
            aa[t] = e / ssum;
        }
        __syncthreads();
        {
            float a0 = 0.f, a1 = 0.f;
            const unsigned short* ebase = enc16 + (size_t)(b*64)*512 + t*2;
            #pragma unroll 8
            for (int s = 0; s < 64; ++s) {
                unsigned u = *reinterpret_cast<const unsigned*>(ebase + (size_t)s*512);
                float a = aa[s];
                a0 += a * h2f((unsigned short)(u & 0xffff));
                a1 += a * h2f((unsigned short)(u >> 16));
            }
            wgt_in[(size_t)b*1280 + 768 + t*2]     = a0;
            wgt_in[(size_t)b*1280 + 768 + t*2 + 1] = a1;
        }
        const int tok = (step == 0) ? 0 : y[(step-1)*64 + b];
        for (int e = t; e < 768; e += 256)
            wgt_in[(size_t)b*1280 + e] = emb_dec[(size_t)tok*768 + e];
    } else {
        if (!do_sm) return;
        __shared__ float cps[64];
        __shared__ float invS;
        if (t < 64) cps[t] = __expf(cpt[b*64 + t]);
        __syncthreads();
        if (t < 64) {
            float v = cps[t];
            for (int off = 32; off; off >>= 1) v += __shfl_xor(v, off);
            if (t == 0) {
                float tot = v;
                #pragma unroll
                for (int k = 0; k < 8; ++k) tot += psum[b*8 + k];
                invS = 1.0f / tot;
            }
        }
        __syncthreads();
        const float inv = invS;
        const unsigned short* srow = scr16 + (size_t)b*VDIM;
        float* orow = outprev + (size_t)b*NCOL;
        for (int i = t*8; i < VDIM; i += 2048) {
            uint4 u = *reinterpret_cast<const uint4*>(&srow[i]);
            float4 o0, o1;
            o0.x = h2f((unsigned short)(u.x & 0xffff))*inv; o0.y = h2f((unsigned short)(u.x >> 16))*inv;
            o0.z = h2f((unsigned short)(u.y & 0xffff))*inv; o0.w = h2f((unsigned short)(u.y >> 16))*inv;
            o1.x = h2f((unsigned short)(u.z & 0xffff))*inv; o1.y = h2f((unsigned short)(u.z >> 16))*inv;
            o1.z = h2f((unsigned short)(u.w & 0xffff))*inv; o1.w = h2f((unsigned short)(u.w >> 16))*inv;
            *reinterpret_cast<float4*>(&orow[i])     = o0;
            *reinterpret_cast<float4*>(&orow[i + 4]) = o1;
        }
        if (t >= 192) orow[VDIM + (t - 192)] = 0.0f;
        __syncthreads();
        if (t < 64) atomicAdd(&orow[y[t*64 + b]], cps[t] * inv);
    }
}

// ===========================================================================
// conversions / transposes / small setup kernels
// ===========================================================================
__global__ __launch_bounds__(256) void convhl_k(
    const float* __restrict__ W, unsigned short* __restrict__ hi,
    unsigned short* __restrict__ lo, int n4)
{
    int i = blockIdx.x*256 + threadIdx.x;
    if (i >= n4) return;
    float4 v = reinterpret_cast<const float4*>(W)[i];
    ushort4 h, l; float r;
    h.x = f2h_hi(v.x, r); l.x = f2h(r);
    h.y = f2h_hi(v.y, r); l.y = f2h(r);
    h.z = f2h_hi(v.z, r); l.z = f2h(r);
    h.w = f2h_hi(v.w, r); l.w = f2h(r);
    reinterpret_cast<ushort4*>(hi)[i] = h;
    reinterpret_cast<ushort4*>(lo)[i] = l;
}
__global__ __launch_bounds__(256) void conv16_k(
    const float* __restrict__ W, unsigned short* __restrict__ hi, int n4)
{
    int i = blockIdx.x*256 + threadIdx.x;
    if (i >= n4) return;
    float4 v = reinterpret_cast<const float4*>(W)[i];
    ushort4 h;
    h.x = f2h(v.x); h.y = f2h(v.y); h.z = f2h(v.z); h.w = f2h(v.w);
    reinterpret_cast<ushort4*>(hi)[i] = h;
}
__global__ __launch_bounds__(256) void transpose2_k(
    const float* __restrict__ S, float* __restrict__ D, int R, int C)
{
    int i = blockIdx.x*256 + threadIdx.x;
    if (i >= R*C) return;
    int r = i / C, c = i - r*C;
    D[(size_t)c*R + r] = S[i];
}
__global__ __launch_bounds__(256) void b03_k(
    const float* __restrict__ Wih0, const float* __restrict__ bih0,
    const float* __restrict__ l3b, float* __restrict__ b03)
{
    int j = blockIdx.x*256 + threadIdx.x;
    if (j >= 2304) return;
    const float* wr = Wih0 + (size_t)j*768;
    float s = 0.f;
    #pragma unroll 4
    for (int m = 0; m < 768; m += 4) {
        float4 w = *reinterpret_cast<const float4*>(wr + m);
        float4 b = *reinterpret_cast<const float4*>(l3b + m);
        s += w.x*b.x + w.y*b.y + w.z*b.z + w.w*b.w;
    }
    b03[j] = bih0[j] + s;
}

__global__ __launch_bounds__(256) void embed_k(const int* inp, const float* emb, float* x)
{
    int i = blockIdx.x*256 + threadIdx.x;
    if (i >= 4096*128) return;
    int row = i >> 7, c4 = i & 127;
    int tok = inp[row];
    *reinterpret_cast<float4*>(x + (size_t)row*512 + c4*4) =
        *reinterpret_cast<const float4*>(emb + (size_t)tok*512 + c4*4);
}

// ---------------------------------------------------------------------------
// Persistent encoder layer, fp16 Whh, 4 batches per block. grid (16, 2).
// ---------------------------------------------------------------------------
__global__ __launch_bounds__(256) void enc_layer4_k(
    const float* giF, const float* giB,
    const unsigned short* Whh16, const float* bhh,
    float* yout, float* hfin, int permute)
{
    const int bg = blockIdx.x, d = blockIdx.y, t = threadIdx.x;
    const float* gi_base = d ? giB : giF;
    const unsigned short* W = Whh16 + (size_t)d*768*256;
    const float br  = bhh[d*768 + t];
    const float bz2 = bhh[d*768 + t + 256];
    const float bn  = bhh[d*768 + t + 512];

    __shared__ float hs[4][256];
    #pragma unroll
    for (int bb = 0; bb < 4; ++bb) hs[bb][t] = 0.0f;
    __syncthreads();

    for (int step = 0; step < 64; ++step) {
        const int s = d ? (63 - step) : step;
        float gr[4], gz[4], gn[4];
        #pragma unroll
        for (int bb = 0; bb < 4; ++bb) {
            const float* gi = gi_base + (size_t)(s*64 + bg*4 + bb)*768;
            gr[bb] = gi[t]; gz[bb] = gi[t+256]; gn[bb] = gi[t+512];
        }
        float ar[4] = {}, az[4] = {}, an[4] = {};
        #pragma unroll 4
        for (int q = 0; q < 32; ++q) {
            f16x8 wr = *reinterpret_cast<const f16x8*>(&W[(size_t)(t      )*256 + q*8]);
            f16x8 wz = *reinterpret_cast<const f16x8*>(&W[(size_t)(t + 256)*256 + q*8]);
            f16x8 wn = *reinterpret_cast<const f16x8*>(&W[(size_t)(t + 512)*256 + q*8]);
            #pragma unroll
            for (int bb = 0; bb < 4; ++bb) {
                float4 h0 = *reinterpret_cast<const float4*>(&hs[bb][q*8]);
                float4 h1 = *reinterpret_cast<const float4*>(&hs[bb][q*8+4]);
                ar[bb] += h0.x*(float)wr[0] + h0.y*(float)wr[1] + h0.z*(float)wr[2] + h0.w*(float)wr[3]
                        + h1.x*(float)wr[4] + h1.y*(float)wr[5] + h1.z*(float)wr[6] + h1.w*(float)wr[7];
                az[bb] += h0.x*(float)wz[0] + h0.y*(float)wz[1] + h0.z*(float)wz[2] + h0.w*(float)wz[3]
                        + h1.x*(float)wz[4] + h1.y*(float)wz[5] + h1.z*(float)wz[6] + h1.w*(float)wz[7];
                an[bb] += h0.x*(float)wn[0] + h0.y*(float)wn[1] + h0.z*(float)wn[2] + h0.w*(float)wn[3]
                        + h1.x*(float)wn[4] + h1.y*(float)wn[5] + h1.z*(float)wn[6] + h1.w*(float)wn[7];
            }
        }
        float hn2[4];
        #pragma unroll
        for (int bb = 0; bb < 4; ++bb) {
            float r = fsig(gr[bb] + ar[bb] + br);
            float z = fsig(gz[bb] + az[bb] + bz2);
            float n = ftanh(gn[bb] + r*(an[bb] + bn));
            hn2[bb] = (1.0f - z)*n + z*hs[bb][t];
        }
        __syncthreads();
        #pragma unroll
        for (int bb = 0; bb < 4; ++bb) {
            hs[bb][t] = hn2[bb];
            const int b = bg*4 + bb;
            const int idx = permute ? (b*64 + s) : (s*64 + b);
            yout[(size_t)idx*512 + d*256 + t] = hn2[bb];
        }
        __syncthreads();
    }
    #pragma unroll
    for (int bb = 0; bb < 4; ++bb)
        hfin[(size_t)(bg*4 + bb)*512 + d*256 + t] = hs[bb][t];
}

// ===========================================================================
// fp32 fallback kernels (only if ws too small for fp16 path)
// ===========================================================================
__global__ __launch_bounds__(256) void gemm64(
    const float* A0, const float* B0, const float* bias0, float* C0, int act0,
    const float* A1, const float* B1, const float* bias1, float* C1, int act1,
    int M, int N, int K, int ldc)
{
    const float* A  = blockIdx.z ? A1 : A0;
    const float* B  = blockIdx.z ? B1 : B0;
    const float* bp = blockIdx.z ? bias1 : bias0;
    float*       C  = blockIdx.z ? C1 : C0;
    const int act   = blockIdx.z ? act1 : act0;

    __shared__ float As[32*68];
    __shared__ float Bs[32*68];

    const int n0 = blockIdx.x * 64;
    const int m0 = blockIdx.y * 64;
    const int t  = threadIdx.x;
    const int lrow = t >> 3;
    const int lc4  = t & 7;
    const int tm = (t >> 4) << 2;
    const int tn = (t & 15) << 2;

    float acc[4][4] = {};

    for (int k0 = 0; k0 < K; k0 += 32) {
        float4 a0 = *reinterpret_cast<const float4*>(A + (size_t)(m0+lrow   )*K + k0 + lc4*4);
        float4 a1 = *reinterpret_cast<const float4*>(A + (size_t)(m0+lrow+32)*K + k0 + lc4*4);
        float4 b0 = *reinterpret_cast<const float4*>(B + (size_t)(n0+lrow   )*K + k0 + lc4*4);
        float4 b1 = *reinterpret_cast<const float4*>(B + (size_t)(n0+lrow+32)*K + k0 + lc4*4);
        __syncthreads();
        const int kb = lc4*4;
        As[(kb+0)*68 + lrow]    = a0.x; As[(kb+1)*68 + lrow]    = a0.y;
        As[(kb+2)*68 + lrow]    = a0.z; As[(kb+3)*68 + lrow]    = a0.w;
        As[(kb+0)*68 + lrow+32] = a1.x; As[(kb+1)*68 + lrow+32] = a1.y;
        As[(kb+2)*68 + lrow+32] = a1.z; As[(kb+3)*68 + lrow+32] = a1.w;
        Bs[(kb+0)*68 + lrow]    = b0.x; Bs[(kb+1)*68 + lrow]    = b0.y;
        Bs[(kb+2)*68 + lrow]    = b0.z; Bs[(kb+3)*68 + lrow]    = b0.w;
        Bs[(kb+0)*68 + lrow+32] = b1.x; Bs[(kb+1)*68 + lrow+32] = b1.y;
        Bs[(kb+2)*68 + lrow+32] = b1.z; Bs[(kb+3)*68 + lrow+32] = b1.w;
        __syncthreads();
        #pragma unroll
        for (int kk = 0; kk < 32; ++kk) {
            float4 av = *reinterpret_cast<const float4*>(As + kk*68 + tm);
            float4 bv = *reinterpret_cast<const float4*>(Bs + kk*68 + tn);
            acc[0][0] += av.x*bv.x; acc[0][1] += av.x*bv.y; acc[0][2] += av.x*bv.z; acc[0][3] += av.x*bv.w;
            acc[1][0] += av.y*bv.x; acc[1][1] += av.y*bv.y; acc[1][2] += av.y*bv.z; acc[1][3] += av.y*bv.w;
            acc[2][0] += av.z*bv.x; acc[2][1] += av.z*bv.y; acc[2][2] += av.z*bv.z; acc[2][3] += av.z*bv.w;
            acc[3][0] += av.w*bv.x; acc[3][1] += av.w*bv.y; acc[3][2] += av.w*bv.z; acc[3][3] += av.w*bv.w;
        }
    }

    #pragma unroll
    for (int i = 0; i < 4; ++i) {
        float r0 = acc[i][0], r1 = acc[i][1], r2 = acc[i][2], r3 = acc[i][3];
        if (bp) { r0 += bp[n0+tn+0]; r1 += bp[n0+tn+1]; r2 += bp[n0+tn+2]; r3 += bp[n0+tn+3]; }
        if (act) { r0 = ftanh(r0); r1 = ftanh(r1); r2 = ftanh(r2); r3 = ftanh(r3); }
        float4 v = make_float4(r0, r1, r2, r3);
        *reinterpret_cast<float4*>(C + (size_t)(m0+tm+i)*ldc + (n0+tn)) = v;
    }
}

__global__ __launch_bounds__(256) void gemm_skinny(
    const float* A0, const float* B0, const float* bias0, float* C0,
    const float* A1, const float* B1, const float* bias1, float* C1,
    int N, int K, int ldc)
{
    const float* A  = blockIdx.z ? A1 : A0;
    const float* B  = blockIdx.z ? B1 : B0;
    const float* bp = blockIdx.z ? bias1 : bias0;
    float*       C  = blockIdx.z ? C1 : C0;

    __shared__ float As[16*64];
    const int n0 = blockIdx.x * 64;
    const int m0 = blockIdx.y * 16;
    const int t  = threadIdx.x;
    const int n  = t & 63;
    const int mb = t >> 6;

    float acc[4] = {};

    for (int k0 = 0; k0 < K; k0 += 64) {
        __syncthreads();
        const int row = t >> 4, c4 = t & 15;
        *reinterpret_cast<float4*>(As + row*64 + c4*4) =
            *reinterpret_cast<const float4*>(A + (size_t)(m0+row)*K + k0 + c4*4);
        __syncthreads();
        const float* Bp = B + (size_t)(n0+n)*K + k0;
        #pragma unroll
        for (int q = 0; q < 16; ++q) {
            float4 bv = *reinterpret_cast<const float4*>(Bp + q*4);
            #pragma unroll
            for (int mm = 0; mm < 4; ++mm) {
                float4 av = *reinterpret_cast<const float4*>(As + (mb + 4*mm)*64 + q*4);
                acc[mm] += av.x*bv.x + av.y*bv.y + av.z*bv.z + av.w*bv.w;
            }
        }
    }
    const float bz = bp ? bp[n0+n] : 0.0f;
    #pragma unroll
    for (int mm = 0; mm < 4; ++mm)
        C[(size_t)(m0 + mb + 4*mm)*ldc + n0 + n] = acc[mm] + bz;
}

__global__ __launch_bounds__(256) void gru_gate_k(
    const float* gi, const float* gh, const float* hold, float* hnew)
{
    int idx = blockIdx.x*256 + threadIdx.x;
    if (idx >= 64*768) return;
    int b = idx / 768, j = idx % 768;
    const float* gib = gi + (size_t)b*2304;
    const float* ghb = gh + (size_t)b*2304;
    hnew[idx] = gru_fuse(gib[j], gib[j+768], gib[j+1536],
                         ghb[j], ghb[j+768], ghb[j+1536], hold[idx]);
}

__global__ __launch_bounds__(256) void att_fused_k(
    const float* __restrict__ w1e, const float* __restrict__ w2h,
    const float* __restrict__ Vp, const float* __restrict__ enc_out,
    const float* __restrict__ emb_dec, const int* __restrict__ y,
    int step, float* __restrict__ wgt_in)
{
    const int b = blockIdx.x, t = threadIdx.x;
    __shared__ float w2s[768];
    __shared__ float vps[768];
    __shared__ float aa[64];
    for (int i = t; i < 768; i += 256) { w2s[i] = w2h[(size_t)b*768 + i]; vps[i] = Vp[i]; }
    __syncthreads();
    const int wv = t >> 6, ln = t & 63;
    for (int ss = 0; ss < 16; ++ss) {
        const int s = wv*16 + ss;
        const float* wrow = w1e + (size_t)(b*64 + s)*768;
        float acc = 0.f;
        #pragma unroll
        for (int q = 0; q < 12; ++q) {
            int e = ln + q*64;
            acc += ftanh(wrow[e] + w2s[e]) * vps[e];
        }
        for (int off = 32; off; off >>= 1) acc += __shfl_down(acc, off);
        if (ln == 0) aa[s] = acc;
    }
    __syncthreads();
    if (t < 64) {
        float v = aa[t];
        float m = v;
        for (int off = 32; off; off >>= 1) m = fmaxf(m, __shfl_xor(m, off));
        float e = __expf(v - m);
        float ssum = e;
        for (int off = 32; off; off >>= 1) ssum += __shfl_xor(ssum, off);
        aa[t] = e / ssum;
    }
    __syncthreads();
    for (int e = t; e < 512; e += 256) {
        float acc = 0.f;
        #pragma unroll 8
        for (int s = 0; s < 64; ++s)
            acc += aa[s] * enc_out[(size_t)(b*64 + s)*512 + e];
        wgt_in[(size_t)b*1280 + 768 + e] = acc;
    }
    const int tok = (step == 0) ? 0 : y[(step-1)*64 + b];
    for (int e = t; e < 768; e += 256)
        wgt_in[(size_t)b*1280 + e] = emb_dec[(size_t)tok*768 + e];
}

__global__ __launch_bounds__(256) void smax2_k(
    const float* __restrict__ scratch, const float* __restrict__ scb,
    const float* __restrict__ h1, const int* __restrict__ y, float* __restrict__ out)
{
    const int b = blockIdx.x, t = threadIdx.x;
    __shared__ float hsh[768];
    __shared__ float cps[64];
    __shared__ float red[4];
    for (int i = t; i < 768; i += 256) hsh[i] = h1[(size_t)b*768 + i];
    __syncthreads();
    const int wv = t >> 6, ln = t & 63;
    for (int ss = 0; ss < 16; ++ss) {
        const int s = wv*16 + ss;
        const float* sp = scb + (size_t)(b*64 + s)*768;
        float acc = 0.f;
        #pragma unroll
        for (int q = 0; q < 12; ++q) { int e = ln + q*64; acc += sp[e]*hsh[e]; }
        for (int off = 32; off; off >>= 1) acc += __shfl_down(acc, off);
        if (ln == 0) cps[s] = ftanh(acc);
    }
    __syncthreads();

    const float* row = scratch + (size_t)b*VDIM;
    float m = -1e30f;
    for (int i = t; i < VDIM; i += 256) m = fmaxf(m, row[i]);
    for (int off = 32; off; off >>= 1) m = fmaxf(m, __shfl_xor(m, off));
    if (ln == 0) red[wv] = m;
    __syncthreads();
    const float bm = fmaxf(fmaxf(red[0], red[1]), fmaxf(red[2], red[3]));
    __syncthreads();

    float s = 0.f;
    for (int i = t; i < VDIM; i += 256) s += __expf(row[i] - bm);
    if (t < 64) s += __expf(cps[t] - bm);
    for (int off = 32; off; off >>= 1) s += __shfl_xor(s, off);
    if (ln == 0) red[wv] = s;
    __syncthreads();
    const float inv = 1.0f / (red[0] + red[1] + red[2] + red[3]);

    float* orow = out + (size_t)b*NCOL;
    for (int i = t; i < VDIM; i += 256) orow[i] = __expf(row[i] - bm) * inv;
    if (t >= 192) orow[VDIM + (t - 192)] = 0.0f;
    __syncthreads();
    if (t < 64) atomicAdd(&orow[y[t*64 + b]], __expf(cps[t] - bm) * inv);
}

// ===========================================================================
extern "C" void kernel_launch(void* const* d_in, const int* in_sizes, int n_in,
                              void* d_out, int out_size, void* d_ws, size_t ws_size,
                              hipStream_t stream)
{
    (void)in_sizes; (void)n_in; (void)out_size;
    const int*   inp       = (const int*)  d_in[0];
    const int*   y         = (const int*)  d_in[1];
    const float* emb_enc   = (const float*)d_in[2];
    const float* enc_Wih   = (const float*)d_in[3];
    const float* enc_Whh   = (const float*)d_in[4];
    const float* enc_bih   = (const float*)d_in[5];
    const float* enc_bhh   = (const float*)d_in[6];
    const float* out_enc_W = (const float*)d_in[7];
    const float* emb_dec   = (const float*)d_in[8];
    const float* dec_Wih   = (const float*)d_in[9];
    const float* dec_Whh   = (const float*)d_in[10];
    const float* dec_bih   = (const float*)d_in[11];
    const float* dec_bhh   = (const float*)d_in[12];
    const float* out_b     = (const float*)d_in[13];
    const float* W1        = (const float*)d_in[14];
    const float* l2_W      = (const float*)d_in[15];
    const float* l2_b      = (const float*)d_in[16];
    const float* l3_W      = (const float*)d_in[17];
    const float* l3_b      = (const float*)d_in[18];
    const float* Vp        = (const float*)d_in[19];
    float* out = (float*)d_out;
    float* ws  = (float*)d_ws;

    size_t off = 0;
    auto alloc = [&](size_t n) { float* p = ws + off; off += (n + 63) & ~(size_t)63; return p; };
    // ---- base region (also serves fp32 fallback) ----
    float* x0     = alloc(4096*512);   // also W03f temp (spans x0+x1 post-encoder)
    float* x1     = alloc(4096*512);
    float* x2     = alloc(4096*512);   // enc_out fp32, rows b*64+s
    float* giF    = alloc(4096*768);   // post-encoder: w1e16 + enc16 (ushort)
    float* giB    = alloc(4096*768);   // post-encoder: scb16 (ushort)
    float* w1e    = alloc(4096*768);
    float* scb    = alloc(4096*768);
    float* W1T    = alloc(768*512);
    float* hfin   = alloc(128*512);
    float* hdecA  = alloc(128*768);
    float* hdecB  = alloc(128*768);
    float* w2h    = alloc(64*768);
    float* wgt_in = alloc(64*1280);
    float* wgt    = alloc(64*768);     // fallback only
    float* gh0buf = alloc(64*2304);
    float* gh1buf = alloc(64*2304);
    float* gi0f   = alloc(64*2304);    // fallback only
    float* gi1f   = alloc(64*2304);    // fallback only
    float* b03    = alloc(2304);
    float* psum   = alloc(512);        // 64 rows x 8 slots
    float* cpt    = alloc(64*64);      // copy-score tanh dots
    float* scratch= alloc(64*VDIM);    // fp32 (fallback) / ushort scr16 / l3T temp
    auto ualloc = [&](size_t nush) { return (unsigned short*)alloc((nush + 1) / 2); };
    unsigned short* encWhhH = ualloc(2*2*768*256);
    // ---- fp16 region ----
    unsigned short* embH    = ualloc((size_t)VDIM*768);
    unsigned short* encWihH = ualloc(2*2*768*512);
    unsigned short* encWihL = ualloc(2*2*768*512);
    unsigned short* W1TH    = ualloc(768*512);
    unsigned short* W1TL    = ualloc(768*512);
    unsigned short* oeH     = ualloc(768*512);
    unsigned short* oeL     = ualloc(768*512);
    unsigned short* l2H     = ualloc(768*768);
    unsigned short* l3TH    = ualloc(1280*768);
    unsigned short* l3TL    = ualloc(1280*768);
    unsigned short* dWihH   = ualloc((size_t)2*2304*768);
    unsigned short* dWhhH   = ualloc((size_t)2*2304*768);
    unsigned short* W03H    = ualloc((size_t)2304*1280);
    const bool use_mfma = ws_size >= off * sizeof(float);

    const size_t L1W = (size_t)2304*768;
    float* l3T  = scratch;             // 1280x768 temp (pre-decoder)
    float* W03f = x0;                  // 2304x1280 temp (post-encoder)
    unsigned short* scr16 = (unsigned short*)scratch;
    unsigned short* w1e16 = (unsigned short*)giF;                  // 3.146M ush
    unsigned short* enc16 = (unsigned short*)(giF + 1600*1024);    // 2.097M ush
    unsigned short* scb16 = (unsigned short*)giB;                  // 3.146M ush

    // ---- common setup ----
    embed_k<<<2048, 256, 0, stream>>>(inp, emb_enc, x0);
    transpose2_k<<<(512*768 + 255)/256, 256, 0, stream>>>(W1, W1T, 512, 768);
    conv16_k<<<768, 256, 0, stream>>>(enc_Whh, encWhhH, 2*2*768*256/4);

    if (use_mfma) {
        convhl_k<<<1536, 256, 0, stream>>>(enc_Wih, encWihH, encWihL, 2*2*768*512/4);
        convhl_k<<<384, 256, 0, stream>>>(W1T, W1TH, W1TL, 768*512/4);
        convhl_k<<<384, 256, 0, stream>>>(out_enc_W, oeH, oeL, 768*512/4);
        conv16_k<<<576, 256, 0, stream>>>(l2_W, l2H, 768*768/4);
        conv16_k<<<3456, 256, 0, stream>>>(dec_Wih, dWihH, (int)(L1W*2/4));
        conv16_k<<<3456, 256, 0, stream>>>(dec_Whh, dWhhH, (int)(L1W*2/4));
        conv16_k<<<24000, 256, 0, stream>>>(emb_dec, embH, (int)((size_t)VDIM*768/4));
        transpose2_k<<<(768*1280 + 255)/256, 256, 0, stream>>>(l3_W, l3T, 768, 1280);
        convhl_k<<<960, 256, 0, stream>>>(l3T, l3TH, l3TL, 1280*768/4);
        b03_k<<<9, 256, 0, stream>>>(dec_Wih, dec_bih, l3_b, b03);

        // ---- encoder ----
        for (int l = 0; l < 2; ++l) {
            const float* xin  = l ? x1 : x0;
            float*       xout = l ? x2 : x1;
            const size_t wo = (size_t)l*2*768*512;
            mfma_gemm<<<dim3(6, 64, 2), 256, 0, stream>>>(
                xin, encWihH + wo,           encWihL + wo,           enc_bih + l*2*768,       giF, 768, 768, 0,
                xin, encWihH + wo + 768*512, encWihL + wo + 768*512, enc_bih + l*2*768 + 768, giB, 768, 768, 0,
                512);
            enc_layer4_k<<<dim3(16, 2), 256, 0, stream>>>(
                giF, giB, encWhhH + (size_t)l*2*768*256, enc_bhh + (size_t)l*2*768,
                xout, hfin + (size_t)l*64*512, l);
        }

        // W03 = Wih0 @ l3_W
        mfma_gemm<<<dim3(10, 36, 1), 256, 0, stream>>>(
            dec_Wih, l3TH, l3TL, nullptr, W03f, 1280, 1280, 0,
            nullptr, nullptr, nullptr, nullptr, nullptr, 0, 0, 0,
            768);
        conv16_k<<<2880, 256, 0, stream>>>(W03f, W03H, 2304*1280/4);

        // decoder initial hidden (128,512)@out_enc_W^T
        mfma_gemm<<<dim3(6, 2, 1), 256, 0, stream>>>(
            hfin, oeH, oeL, nullptr, hdecA, 768, 768, 0,
            nullptr, nullptr, nullptr, nullptr, nullptr, 0, 0, 0,
            512);

        // w1e = enc_out@W1 ; scb = tanh(enc_out@out_enc_W^T)
        mfma_gemm<<<dim3(6, 64, 2), 256, 0, stream>>>(
            x2, W1TH, W1TL, nullptr, w1e, 768, 768, 0,
            x2, oeH,  oeL,  nullptr, scb, 768, 768, 1,
            512);

        // fp16 caches: w1e16, scb16, enc16 (giF/giB now free)
        conv16_k<<<3072, 256, 0, stream>>>(w1e, w1e16, 4096*768/4);
        conv16_k<<<3072, 256, 0, stream>>>(scb, scb16, 4096*768/4);
        conv16_k<<<2048, 256, 0, stream>>>(x2, enc16, 4096*512/4);

        // bootstrap: w2h = h1@l2 ; gh0 = h0@Whh0 ; gh1 = h1@Whh1
        mfma_gemm<<<dim3(6, 1, 1), 256, 0, stream>>>(
            hdecA + 64*768, l2H, nullptr, l2_b, w2h, 768, 768, 0,
            nullptr, nullptr, nullptr, nullptr, nullptr, 0, 0, 0,
            768);
        gru_mfma_k<<<dim3(48, 1, 2), 256, 0, stream>>>(
            hdecA,          dWhhH,       nullptr, dec_bhh,        nullptr, nullptr, gh0buf, 0, 768,
            hdecA + 64*768, dWhhH + L1W, nullptr, dec_bhh + 2304, nullptr, nullptr, gh1buf, 0, 768,
            nullptr);

        // ---- decoder: 4 launches per step (smax(t-1) merged into att(t)) ----
        for (int st = 0; st < TSL; ++st) {
            float* h0c = (st & 1) ? hdecB : hdecA;
            float* h0n = (st & 1) ? hdecA : hdecB;
            float* h1c = h0c + 64*768;
            float* h1n = h0n + 64*768;
            float* oprev = out + (size_t)(st > 0 ? st - 1 : 0)*BSZ*NCOL;

            attsm_k<<<dim3(64, 2), 256, 0, stream>>>(
                w1e16, w2h, Vp, enc16, emb_dec, y, st, 1, (st > 0) ? 1 : 0,
                wgt_in, scr16, cpt, psum, oprev);

            // gi0 = wgt_in@W03^T + b03, fused gate0 -> h0n (zeroes psum)
            gru_mfma_k<<<dim3(48, 1, 1), 256, 0, stream>>>(
                wgt_in, W03H, nullptr, b03, gh0buf, h0c, h0n, 1, 1280,
                wgt_in, W03H, nullptr, b03, gh0buf, h0c, h0n, 1, 1280,
                psum);

            // gi1+gate1 -> h1n  ||  gh0' = h0n@Whh0 (next step)
            gru_mfma_k<<<dim3(48, 1, 2), 256, 0, stream>>>(
                h0n, dWihH + L1W, nullptr, dec_bih + 2304, gh1buf, h1c, h1n, 1, 768,
                h0n, dWhhH,       nullptr, dec_bhh,        nullptr, nullptr, gh0buf, 0, 768,
                nullptr);

            // vocab exp->scr16+psum || w2h' || gh1' || copy-scores cpt
            vocab4_k<<<dim3(250, 1, 4), 256, 0, stream>>>(
                h1n,
                embH, out_b, scr16, psum,
                l2H, l2_b, w2h,
                dWhhH + L1W, dec_bhh + 2304, gh1buf,
                scb16, cpt);
        }
        // final softmax for step 47
        attsm_k<<<dim3(64, 2), 256, 0, stream>>>(
            w1e16, w2h, Vp, enc16, emb_dec, y, TSL, 0, 1,
            wgt_in, scr16, cpt, psum, out + (size_t)(TSL-1)*BSZ*NCOL);
    } else {
        // ================= fp32 fallback =================
        for (int l = 0; l < 2; ++l) {
            const float* xin  = l ? x1 : x0;
            float*       xout = l ? x2 : x1;
            const float* Wih = enc_Wih + (size_t)l*2*768*512;
            const float* bih = enc_bih + (size_t)l*2*768;
            gemm64<<<dim3(12, 64, 2), 256, 0, stream>>>(
                xin, Wih,           bih,       giF, 0,
                xin, Wih + 768*512, bih + 768, giB, 0,
                4096, 768, 512, 768);
            enc_layer4_k<<<dim3(16, 2), 256, 0, stream>>>(
                giF, giB, encWhhH + (size_t)l*2*768*256, enc_bhh + (size_t)l*2*768,
                xout, hfin + (size_t)l*64*512, l);
        }
        gemm64<<<dim3(12, 2, 1), 256, 0, stream>>>(
            hfin, out_enc_W, nullptr, hdecA, 0,
            hfin, out_enc_W, nullptr, hdecA, 0,
            128, 768, 512, 768);
        gemm64<<<dim3(12, 64, 2), 256, 0, stream>>>(
            x2, W1T,       nullptr, w1e, 0,
            x2, out_enc_W, nullptr, scb, 1,
            4096, 768, 512, 768);
        gemm_skinny<<<dim3(12, 4, 1), 256, 0, stream>>>(
            hdecA + 64*768, l2_W, l2_b, w2h,
            hdecA + 64*768, l2_W, l2_b, w2h,
            768, 768, 768);

        for (int st = 0; st < TSL; ++st) {
            float* h0c = (st & 1) ? hdecB : hdecA;
            float* h0n = (st & 1) ? hdecA : hdecB;
            float* h1c = h0c + 64*768;
            float* h1n = h0n + 64*768;
            float* orow = out + (size_t)st*BSZ*NCOL;

            att_fused_k<<<64, 256, 0, stream>>>(w1e, w2h, Vp, x2, emb_dec, y, st, wgt_in);
            gemm_skinny<<<dim3(12, 4, 1), 256, 0, stream>>>(
                wgt_in, l3_W, l3_b, wgt,
                wgt_in, l3_W, l3_b, wgt,
                768, 1280, 768);
            gemm_skinny<<<dim3(36, 4, 2), 256, 0, stream>>>(
                wgt, dec_Wih, dec_bih, gi0f,
                h0c, dec_Whh, dec_bhh, gh0buf,
                2304, 768, 2304);
            gru_gate_k<<<192, 256, 0, stream>>>(gi0f, gh0buf, h0c, h0n);
            gemm_skinny<<<dim3(36, 4, 2), 256, 0, stream>>>(
                h0n, dec_Wih + L1W, dec_bih + 2304, gi1f,
                h1c, dec_Whh + L1W, dec_bhh + 2304, gh1buf,
                2304, 768, 2304);
            gru_gate_k<<<192, 256, 0, stream>>>(gi1f, gh1buf, h1c, h1n);
            gemm_skinny<<<dim3(12, 4, 1), 256, 0, stream>>>(
                h1n, l2_W, l2_b, w2h,
                h1n, l2_W, l2_b, w2h,
                768, 768, 768);
            gemm64<<<dim3(500, 1, 1), 256, 0, stream>>>(
                h1n, emb_dec, out_b, scratch, 0,
                h1n, emb_dec, out_b, scratch, 0,
                64, VDIM, 768, VDIM);
            smax2_k<<<64, 256, 0, stream>>>(scratch, scb, h1n, y, orow);
        }
    }
}